// Round 1
// baseline (2046.300 us; speedup 1.0000x reference)
//
#include <hip/hip_runtime.h>
#include <hip/hip_bf16.h>

#define NEGV -1e10f
#define NEG_INF -3.402823466e38f

__device__ inline float bf2f(unsigned short u) {
    union { unsigned int i; float f; } c; c.i = ((unsigned int)u) << 16; return c.f;
}

// ---------------- K0: zero-init ts, a, b (ws is poisoned 0xAA) ----------------
__global__ void k0_init(float* ts, float* a, float* b) {
    int i = blockIdx.x * blockDim.x + threadIdx.x;
    if (i < 16384) ts[i] = 0.f;
    if (i < 131072) { a[i] = 0.f; b[i] = 0.f; }
}

// ---------------- K1: span head-attention scores ----------------
// scores[nm,t] = relu(cont[nm,t,:] @ aw1 + ab1) @ aw2 + ab2   (h never materialized)
__global__ __launch_bounds__(256) void k1_span_scores(
    const float* __restrict__ cont, const float* __restrict__ aw1,
    const float* __restrict__ ab1, const float* __restrict__ aw2,
    const float* __restrict__ ab2, float* __restrict__ scores) {
    __shared__ float cont_sh[10][768];
    __shared__ float red[4][10];
    int nm = blockIdx.x;
    int tid = threadIdx.x;
    const float* cbase = cont + (size_t)nm * 7680;
    for (int idx = tid; idx < 7680; idx += 256) cont_sh[idx / 768][idx % 768] = cbase[idx];
    __syncthreads();
    int c0 = tid * 4;
    float acc[10][4];
#pragma unroll
    for (int t = 0; t < 10; ++t)
#pragma unroll
        for (int j = 0; j < 4; ++j) acc[t][j] = 0.f;
    for (int k = 0; k < 768; ++k) {
        float4 w = *(const float4*)&aw1[(size_t)k * 1024 + c0];
#pragma unroll
        for (int t = 0; t < 10; ++t) {
            float cv = cont_sh[t][k];
            acc[t][0] = fmaf(cv, w.x, acc[t][0]);
            acc[t][1] = fmaf(cv, w.y, acc[t][1]);
            acc[t][2] = fmaf(cv, w.z, acc[t][2]);
            acc[t][3] = fmaf(cv, w.w, acc[t][3]);
        }
    }
    float4 b1 = *(const float4*)&ab1[c0];
    float4 w2 = *(const float4*)&aw2[c0];
    int lane = tid & 63, wave = tid >> 6;
#pragma unroll
    for (int t = 0; t < 10; ++t) {
        float s = fmaxf(acc[t][0] + b1.x, 0.f) * w2.x
                + fmaxf(acc[t][1] + b1.y, 0.f) * w2.y
                + fmaxf(acc[t][2] + b1.z, 0.f) * w2.z
                + fmaxf(acc[t][3] + b1.w, 0.f) * w2.w;
        for (int off = 32; off > 0; off >>= 1) s += __shfl_down(s, off);
        if (lane == 0) red[wave][t] = s;
    }
    __syncthreads();
    if (tid < 10)
        scores[nm * 10 + tid] = red[0][tid] + red[1][tid] + red[2][tid] + red[3][tid] + ab2[0];
}

// ---------------- K2: softmax over span tokens, assemble span embeddings ----------------
__global__ __launch_bounds__(256) void k2_assemble(
    const float* __restrict__ se, const float* __restrict__ cont,
    const int* __restrict__ width, const float* __restrict__ scores,
    const float* __restrict__ wemb, float* __restrict__ spans) {
    int nm = blockIdx.x, tid = threadIdx.x;
    int wd = width[nm];
    float sc[10];
    float m = NEG_INF;
#pragma unroll
    for (int t = 0; t < 10; ++t) {
        float s = scores[nm * 10 + t];
        sc[t] = (t < wd) ? s : NEGV;
        m = fmaxf(m, sc[t]);
    }
    float sum = 0.f;
#pragma unroll
    for (int t = 0; t < 10; ++t) { sc[t] = expf(sc[t] - m); sum += sc[t]; }
    float inv = 1.f / sum;
#pragma unroll
    for (int t = 0; t < 10; ++t) sc[t] *= inv;
    const float* cbase = cont + (size_t)nm * 7680;
    float* srow = spans + (size_t)nm * 2324;
    for (int d = tid; d < 768; d += 256) {
        float acc = 0.f;
#pragma unroll
        for (int t = 0; t < 10; ++t) acc = fmaf(sc[t], cbase[t * 768 + d], acc);
        srow[1536 + d] = acc;
    }
    for (int idx = tid; idx < 1536; idx += 256) srow[idx] = se[(size_t)nm * 1536 + idx];
    if (tid < 20) srow[2304 + tid] = wemb[min(wd, 4) * 20 + tid];
}

// ---------------- K3: grounding S_g, one block per (s,v) ----------------
__global__ __launch_bounds__(256) void k3_grounding(
    const float* __restrict__ doc, const float* __restrict__ img,
    const float* __restrict__ tm, const float* __restrict__ im,
    float* __restrict__ Sg) {
    __shared__ float dsh[64][65];
    __shared__ float ish[36][65];
    __shared__ float att[64][37];
    __shared__ float tmv[64], imv[36];
    __shared__ float s1sh;
    int b = blockIdx.x;
    int s = b >> 3, v = b & 7;
    int tid = threadIdx.x;
    if (tid < 64) tmv[tid] = tm[s * 64 + tid];
    if (tid >= 64 && tid < 100) imv[tid - 64] = im[v * 36 + (tid - 64)];
    float accv[9];
#pragma unroll
    for (int r = 0; r < 9; ++r) accv[r] = 0.f;
    for (int kc = 0; kc < 16; ++kc) {
        int k0 = kc * 64;
        __syncthreads();
#pragma unroll
        for (int l = 0; l < 16; ++l) {
            int idx = tid + 256 * l;
            dsh[idx >> 6][idx & 63] = doc[(size_t)(s * 64 + (idx >> 6)) * 1024 + k0 + (idx & 63)];
        }
#pragma unroll
        for (int l = 0; l < 9; ++l) {
            int idx = tid + 256 * l;
            ish[idx >> 6][idx & 63] = img[(size_t)(v * 36 + (idx >> 6)) * 1024 + k0 + (idx & 63)];
        }
        __syncthreads();
#pragma unroll
        for (int r = 0; r < 9; ++r) {
            int e = tid + 256 * r;
            int i = e / 36, j = e - i * 36;
            float a = 0.f;
            for (int k = 0; k < 64; ++k) a = fmaf(dsh[i][k], ish[j][k], a);
            accv[r] += a;
        }
    }
    __syncthreads();
#pragma unroll
    for (int r = 0; r < 9; ++r) {
        int e = tid + 256 * r;
        int i = e / 36, j = e - i * 36;
        float x = accv[r] * tmv[i] * imv[j];
        att[i][j] = (x != 0.f) ? x : NEGV;
    }
    __syncthreads();
    // s1: softmax over j of (att * imv), times mask, dotted with att
    float part = 0.f;
    if (tid < 64) {
        int i = tid;
        float mx = NEG_INF;
        for (int j = 0; j < 36; ++j) mx = fmaxf(mx, att[i][j] * imv[j]);
        float sum = 0.f;
        for (int j = 0; j < 36; ++j) sum += expf(att[i][j] * imv[j] - mx);
        float invs = 1.f / sum;
        for (int j = 0; j < 36; ++j) {
            float aw = expf(att[i][j] * imv[j] - mx) * invs * (tmv[i] * imv[j]);
            part += aw * att[i][j];
        }
        for (int off = 32; off > 0; off >>= 1) part += __shfl_down(part, off);
        if (tid == 0) s1sh = part;
    }
    __syncthreads();
    // s2: softmax over i (frame axis) of att, times mask, dotted with att
    if (tid < 64) {
        float part2 = 0.f;
        if (tid < 36) {
            int j = tid;
            float mx = NEG_INF;
            for (int i = 0; i < 64; ++i) mx = fmaxf(mx, att[i][j]);
            float sum = 0.f;
            for (int i = 0; i < 64; ++i) sum += expf(att[i][j] - mx);
            float invs = 1.f / sum;
            for (int i = 0; i < 64; ++i) {
                float aw = expf(att[i][j] - mx) * invs * (tmv[i] * imv[j]);
                part2 += aw * att[i][j];
            }
        }
        for (int off = 32; off > 0; off >>= 1) part2 += __shfl_down(part2, off);
        if (tid == 0) Sg[s * 8 + v] = s1sh + part2;
    }
}

// ---------------- K4: a = spans@w1[:SD], b = spans@w1[SD:2SD]  (K-split, atomic) ----------------
__global__ __launch_bounds__(256) void k4_ab(
    const float* __restrict__ spans, const float* __restrict__ w1,
    float* __restrict__ aout, float* __restrict__ bout) {
    __shared__ __align__(16) float As[4][128];
    __shared__ __align__(16) float Ws[4][64];
    int tid = threadIdx.x;
    int tx = tid & 15, ty = tid >> 4;
    int col0 = blockIdx.x * 64;
    int half = blockIdx.y;
    int kz = blockIdx.z;
    const float* wbase = w1 + (size_t)half * 2324 * 1024;
    float* outp = half ? bout : aout;
    float acc[8][4];
#pragma unroll
    for (int r = 0; r < 8; ++r)
#pragma unroll
        for (int j = 0; j < 4; ++j) acc[r][j] = 0.f;
    for (int k0 = kz * 4; k0 < 2324; k0 += 16) {
#pragma unroll
        for (int l = 0; l < 2; ++l) {
            int idx = tid * 2 + l;
            int mm = idx >> 2, kk = idx & 3;
            As[kk][mm] = spans[(size_t)mm * 2324 + k0 + kk];
        }
        {
            int kk = tid >> 6, c = tid & 63;
            Ws[kk][c] = wbase[(size_t)(k0 + kk) * 1024 + col0 + c];
        }
        __syncthreads();
#pragma unroll
        for (int kk = 0; kk < 4; ++kk) {
            float4 w = *(const float4*)&Ws[kk][tx * 4];
            float4 x0 = *(const float4*)&As[kk][ty * 8];
            float4 x1 = *(const float4*)&As[kk][ty * 8 + 4];
            float ar[8] = {x0.x, x0.y, x0.z, x0.w, x1.x, x1.y, x1.z, x1.w};
            float wr[4] = {w.x, w.y, w.z, w.w};
#pragma unroll
            for (int r = 0; r < 8; ++r)
#pragma unroll
                for (int j = 0; j < 4; ++j) acc[r][j] = fmaf(ar[r], wr[j], acc[r][j]);
        }
        __syncthreads();
    }
#pragma unroll
    for (int r = 0; r < 8; ++r)
#pragma unroll
        for (int j = 0; j < 4; ++j)
            atomicAdd(&outp[(size_t)(ty * 8 + r) * 1024 + col0 + tx * 4 + j], acc[r][j]);
}

// ---------------- K5: h[u,w,:] = relu(a[u]+b[w]+(spans[u]*spans[w])@w1c + b1), bf16 store ----
__global__ __launch_bounds__(256) void k5_h(
    const float* __restrict__ spans, const float* __restrict__ w1,
    const float* __restrict__ a, const float* __restrict__ b,
    const float* __restrict__ b1, __hip_bfloat16* __restrict__ h) {
    __shared__ __align__(16) float As[4][128];
    __shared__ __align__(16) float Ws[4][64];
    int tid = threadIdx.x;
    int tx = tid & 15, ty = tid >> 4;
    int col0 = blockIdx.x * 64;
    int u = blockIdx.y;
    const float* wbase = w1 + (size_t)2 * 2324 * 1024;
    const float* su = spans + (size_t)u * 2324;
    float acc[8][4];
#pragma unroll
    for (int r = 0; r < 8; ++r)
#pragma unroll
        for (int j = 0; j < 4; ++j) acc[r][j] = 0.f;
    for (int k0 = 0; k0 < 2324; k0 += 4) {
#pragma unroll
        for (int l = 0; l < 2; ++l) {
            int idx = tid * 2 + l;
            int mm = idx >> 2, kk = idx & 3;
            As[kk][mm] = spans[(size_t)mm * 2324 + k0 + kk] * su[k0 + kk];
        }
        {
            int kk = tid >> 6, c = tid & 63;
            Ws[kk][c] = wbase[(size_t)(k0 + kk) * 1024 + col0 + c];
        }
        __syncthreads();
#pragma unroll
        for (int kk = 0; kk < 4; ++kk) {
            float4 w = *(const float4*)&Ws[kk][tx * 4];
            float4 x0 = *(const float4*)&As[kk][ty * 8];
            float4 x1 = *(const float4*)&As[kk][ty * 8 + 4];
            float ar[8] = {x0.x, x0.y, x0.z, x0.w, x1.x, x1.y, x1.z, x1.w};
            float wr[4] = {w.x, w.y, w.z, w.w};
#pragma unroll
            for (int r = 0; r < 8; ++r)
#pragma unroll
                for (int j = 0; j < 4; ++j) acc[r][j] = fmaf(ar[r], wr[j], acc[r][j]);
        }
        __syncthreads();
    }
#pragma unroll
    for (int r = 0; r < 8; ++r) {
        int ww = ty * 8 + r;
#pragma unroll
        for (int j = 0; j < 4; ++j) {
            int c = col0 + tx * 4 + j;
            float val = acc[r][j] + a[u * 1024 + c] + b[ww * 1024 + c] + b1[c];
            val = fmaxf(val, 0.f);
            h[((size_t)u * 128 + ww) * 1024 + c] = __float2bfloat16(val);
        }
    }
}

// ---------------- K6: ts[p] = relu(h[p]@w2 + b2) @ w3  (b3 added in K7) ----------------
__global__ __launch_bounds__(256) void k6_ts(
    const __hip_bfloat16* __restrict__ h, const float* __restrict__ w2,
    const float* __restrict__ b2, const float* __restrict__ w3,
    float* __restrict__ ts) {
    __shared__ __align__(16) float As[8][128];
    __shared__ __align__(16) float Ws[8][64];
    int tid = threadIdx.x;
    int tx = tid & 15, ty = tid >> 4;
    int col0 = blockIdx.x * 64;
    int m0 = blockIdx.y * 128;
    const unsigned short* hp = (const unsigned short*)h;
    float acc[8][4];
#pragma unroll
    for (int r = 0; r < 8; ++r)
#pragma unroll
        for (int j = 0; j < 4; ++j) acc[r][j] = 0.f;
    for (int k0 = 0; k0 < 1024; k0 += 8) {
        {
            int idx = tid * 4;
            int mm = idx >> 3, kk = idx & 7;
            ushort4 rawv = *(const ushort4*)&hp[(size_t)(m0 + mm) * 1024 + k0 + kk];
            As[kk + 0][mm] = bf2f(rawv.x);
            As[kk + 1][mm] = bf2f(rawv.y);
            As[kk + 2][mm] = bf2f(rawv.z);
            As[kk + 3][mm] = bf2f(rawv.w);
        }
#pragma unroll
        for (int l = 0; l < 2; ++l) {
            int idx = tid + 256 * l;
            int kk = idx >> 6, c = idx & 63;
            Ws[kk][c] = w2[(size_t)(k0 + kk) * 1024 + col0 + c];
        }
        __syncthreads();
#pragma unroll
        for (int kk = 0; kk < 8; ++kk) {
            float4 w = *(const float4*)&Ws[kk][tx * 4];
            float4 x0 = *(const float4*)&As[kk][ty * 8];
            float4 x1 = *(const float4*)&As[kk][ty * 8 + 4];
            float ar[8] = {x0.x, x0.y, x0.z, x0.w, x1.x, x1.y, x1.z, x1.w};
            float wr[4] = {w.x, w.y, w.z, w.w};
#pragma unroll
            for (int r = 0; r < 8; ++r)
#pragma unroll
                for (int j = 0; j < 4; ++j) acc[r][j] = fmaf(ar[r], wr[j], acc[r][j]);
        }
        __syncthreads();
    }
#pragma unroll
    for (int r = 0; r < 8; ++r) {
        float sum = 0.f;
#pragma unroll
        for (int j = 0; j < 4; ++j) {
            int c = col0 + tx * 4 + j;
            float val = fmaxf(acc[r][j] + b2[c], 0.f);
            sum = fmaf(val, w3[c], sum);
        }
#pragma unroll
        for (int off = 8; off > 0; off >>= 1) sum += __shfl_down(sum, off, 16);
        if (tx == 0) atomicAdd(&ts[m0 + ty * 8 + r], sum);
    }
}

// ---------------- K7: adaptive S_c + final loss ----------------
__global__ void k7_final(const float* __restrict__ ts, const float* __restrict__ Sg,
                         const float* __restrict__ m1, const float* __restrict__ b3,
                         float* __restrict__ out) {
    __shared__ float Sc[64];
    __shared__ float mg[8][8], mgT[8][8], mc[8][8];
    int tid = threadIdx.x;
    float b3v = b3[0];
    if (tid < 64) {
        int s = tid >> 3, v = tid & 7;
        float cs = 0.f, cv = 0.f;
        for (int k = 0; k < 16; ++k) { cs += m1[s * 16 + k]; cv += m1[v * 16 + k]; }
        float max1 = NEG_INF;
        for (int i = 0; i < 16; ++i) {
            float rm = 0.f;
            for (int j = 0; j < 16; ++j)
                rm += (ts[(size_t)(s * 16 + i) * 128 + v * 16 + j] + b3v) * m1[v * 16 + j];
            rm /= cv;
            if (m1[s * 16 + i] > 0.f) max1 = fmaxf(max1, rm);
        }
        float max2 = NEG_INF;
        for (int j = 0; j < 16; ++j) {
            float cm = 0.f;
            for (int i = 0; i < 16; ++i)
                cm += (ts[(size_t)(s * 16 + i) * 128 + v * 16 + j] + b3v) * m1[s * 16 + i];
            cm /= cs;
            if (m1[v * 16 + j] > 0.f) max2 = fmaxf(max2, cm);
        }
        Sc[tid] = 0.5f * (max1 + max2);
    }
    __syncthreads();
    if (tid < 8) {
        int r = tid;
        float mx = NEG_INF;
        for (int v = 0; v < 8; ++v) mx = fmaxf(mx, Sg[r * 8 + v]);
        float sm = 0.f;
        for (int v = 0; v < 8; ++v) sm += expf(Sg[r * 8 + v] - mx);
        for (int v = 0; v < 8; ++v) mg[r][v] = expf(Sg[r * 8 + v] - mx) / sm;

        mx = NEG_INF;
        for (int v = 0; v < 8; ++v) mx = fmaxf(mx, Sc[r * 8 + v]);
        sm = 0.f;
        for (int v = 0; v < 8; ++v) sm += expf(Sc[r * 8 + v] - mx);
        for (int v = 0; v < 8; ++v) mc[r][v] = expf(Sc[r * 8 + v] - mx) / sm;

        mx = NEG_INF;
        for (int s2 = 0; s2 < 8; ++s2) mx = fmaxf(mx, Sg[s2 * 8 + r]);
        sm = 0.f;
        for (int s2 = 0; s2 < 8; ++s2) sm += expf(Sg[s2 * 8 + r] - mx);
        for (int s2 = 0; s2 < 8; ++s2) mgT[r][s2] = expf(Sg[s2 * 8 + r] - mx) / sm;
    }
    __syncthreads();
    if (tid == 0) {
        float loss = 0.f;
        for (int r = 0; r < 8; ++r) {
            float d1 = 0.f, d2 = 0.f;
            for (int v = 0; v < 8; ++v) {
                d1 += mg[r][v] * mc[r][v];
                d2 += mgT[r][v] * mc[r][v];
            }
            loss -= logf(d1) + logf(d2);
        }
        out[0] = loss / 8.f;
    }
}

extern "C" void kernel_launch(void* const* d_in, const int* in_sizes, int n_in,
                              void* d_out, int out_size, void* d_ws, size_t ws_size,
                              hipStream_t stream) {
    const float* doc   = (const float*)d_in[0];
    const float* img   = (const float*)d_in[1];
    const float* tm    = (const float*)d_in[2];
    const float* im    = (const float*)d_in[3];
    const float* se    = (const float*)d_in[4];
    const float* cont  = (const float*)d_in[5];
    const int*   width = (const int*)d_in[6];
    const float* m1    = (const float*)d_in[7];
    const float* aw1   = (const float*)d_in[8];
    const float* ab1   = (const float*)d_in[9];
    const float* aw2   = (const float*)d_in[10];
    const float* ab2   = (const float*)d_in[11];
    const float* wemb  = (const float*)d_in[12];
    const float* pw_w1 = (const float*)d_in[13];
    const float* pw_b1 = (const float*)d_in[14];
    const float* pw_w2 = (const float*)d_in[15];
    const float* pw_b2 = (const float*)d_in[16];
    const float* pw_w3 = (const float*)d_in[17];
    const float* pw_b3 = (const float*)d_in[18];
    float* out = (float*)d_out;

    char* ws = (char*)d_ws;
    float* spans  = (float*)(ws + 0);           // 297472 f
    float* scores = (float*)(ws + 1189888);     // 1280 f
    float* a      = (float*)(ws + 1195008);     // 131072 f
    float* b      = (float*)(ws + 1719296);     // 131072 f
    float* Sg     = (float*)(ws + 2243584);     // 64 f
    float* ts     = (float*)(ws + 2243840);     // 16384 f
    __hip_bfloat16* h = (__hip_bfloat16*)(ws + 2309376); // 16777216 bf16 = 33.5 MB

    k0_init<<<512, 256, 0, stream>>>(ts, a, b);
    k1_span_scores<<<128, 256, 0, stream>>>(cont, aw1, ab1, aw2, ab2, scores);
    k2_assemble<<<128, 256, 0, stream>>>(se, cont, width, scores, wemb, spans);
    k3_grounding<<<64, 256, 0, stream>>>(doc, img, tm, im, Sg);
    k4_ab<<<dim3(16, 2, 4), 256, 0, stream>>>(spans, pw_w1, a, b);
    k5_h<<<dim3(16, 128), 256, 0, stream>>>(spans, pw_w1, a, b, pw_b1, h);
    k6_ts<<<dim3(16, 128), 256, 0, stream>>>(h, pw_w2, pw_b2, pw_w3, ts);
    k7_final<<<1, 64, 0, stream>>>(ts, Sg, m1, pw_b3, out);
}

// Round 2
// 729.905 us; speedup vs baseline: 2.8035x; 2.8035x over previous
//
#include <hip/hip_runtime.h>
#include <hip/hip_bf16.h>

#define NEGV -1e10f
#define NEG_INF -3.402823466e38f

typedef __attribute__((ext_vector_type(8))) short short8;
typedef __attribute__((ext_vector_type(4))) float floatx4;

__device__ inline float bf2f(unsigned short u) {
    union { unsigned int i; float f; } c; c.i = ((unsigned int)u) << 16; return c.f;
}
__device__ inline unsigned short f2b(float f) {
    __hip_bfloat16 h = __float2bfloat16(f);
    return *reinterpret_cast<unsigned short*>(&h);
}
// product of two packed bf16 pairs -> packed bf16 pair (RNE)
__device__ inline unsigned int mul2bf(unsigned int x, unsigned int y) {
    union { unsigned int i; float f; } xl, xh, yl, yh;
    xl.i = x << 16; xh.i = x & 0xffff0000u;
    yl.i = y << 16; yh.i = y & 0xffff0000u;
    unsigned int lo = f2b(xl.f * yl.f);
    unsigned int hi = f2b(xh.f * yh.f);
    return lo | (hi << 16);
}

// ---------------- K0: zero-init ts, a, b ----------------
__global__ void k0_init(float* ts, float* a, float* b) {
    int i = blockIdx.x * blockDim.x + threadIdx.x;
    if (i < 16384) ts[i] = 0.f;
    if (i < 131072) { a[i] = 0.f; b[i] = 0.f; }
}

// ---------------- KT: transpose fp32 [K][N] -> bf16 [N][Kpad] (zero-pad K) ----------------
__global__ __launch_bounds__(256) void kT_transpose(
    const float* __restrict__ in, int ldin, int krows,
    unsigned short* __restrict__ out, int ldout) {
    __shared__ unsigned short L[64][66];
    int t = threadIdx.x;
    int kt = blockIdx.x * 64, nt = blockIdx.y * 64;
    int nl = t & 63, g = t >> 6;
#pragma unroll
    for (int i = 0; i < 16; ++i) {
        int kl = g * 16 + i;
        int k = kt + kl;
        float v = (k < krows) ? in[(size_t)k * ldin + nt + nl] : 0.f;
        L[kl][nl] = f2b(v);
    }
    __syncthreads();
    int kl2 = t & 63;
#pragma unroll
    for (int i = 0; i < 16; ++i) {
        int nl2 = g * 16 + i;
        out[(size_t)(nt + nl2) * ldout + kt + kl2] = L[kl2][nl2];
    }
}

// ---------------- KP: spans fp32 [128][2324] -> bf16 [128][2368] zero-padded ----------------
__global__ void kP_spansbf(const float* __restrict__ spans, unsigned short* __restrict__ sb) {
    int i = blockIdx.x * 256 + threadIdx.x;
    if (i >= 128 * 2368) return;
    int r = i / 2368, k = i - r * 2368;
    float v = (k < 2324) ? spans[r * 2324 + k] : 0.f;
    sb[i] = f2b(v);
}

// ---------------- K1: span head-attention scores (fp32) ----------------
__global__ __launch_bounds__(256) void k1_span_scores(
    const float* __restrict__ cont, const float* __restrict__ aw1,
    const float* __restrict__ ab1, const float* __restrict__ aw2,
    const float* __restrict__ ab2, float* __restrict__ scores) {
    __shared__ float cont_sh[10][768];
    __shared__ float red[4][10];
    int nm = blockIdx.x;
    int tid = threadIdx.x;
    const float* cbase = cont + (size_t)nm * 7680;
    for (int idx = tid; idx < 7680; idx += 256) cont_sh[idx / 768][idx % 768] = cbase[idx];
    __syncthreads();
    int c0 = tid * 4;
    float acc[10][4];
#pragma unroll
    for (int t = 0; t < 10; ++t)
#pragma unroll
        for (int j = 0; j < 4; ++j) acc[t][j] = 0.f;
    for (int k = 0; k < 768; ++k) {
        float4 w = *(const float4*)&aw1[(size_t)k * 1024 + c0];
#pragma unroll
        for (int t = 0; t < 10; ++t) {
            float cv = cont_sh[t][k];
            acc[t][0] = fmaf(cv, w.x, acc[t][0]);
            acc[t][1] = fmaf(cv, w.y, acc[t][1]);
            acc[t][2] = fmaf(cv, w.z, acc[t][2]);
            acc[t][3] = fmaf(cv, w.w, acc[t][3]);
        }
    }
    float4 b1 = *(const float4*)&ab1[c0];
    float4 w2 = *(const float4*)&aw2[c0];
    int lane = tid & 63, wave = tid >> 6;
#pragma unroll
    for (int t = 0; t < 10; ++t) {
        float s = fmaxf(acc[t][0] + b1.x, 0.f) * w2.x
                + fmaxf(acc[t][1] + b1.y, 0.f) * w2.y
                + fmaxf(acc[t][2] + b1.z, 0.f) * w2.z
                + fmaxf(acc[t][3] + b1.w, 0.f) * w2.w;
        for (int off = 32; off > 0; off >>= 1) s += __shfl_down(s, off);
        if (lane == 0) red[wave][t] = s;
    }
    __syncthreads();
    if (tid < 10)
        scores[nm * 10 + tid] = red[0][tid] + red[1][tid] + red[2][tid] + red[3][tid] + ab2[0];
}

// ---------------- K2: softmax over span tokens, assemble span embeddings ----------------
__global__ __launch_bounds__(256) void k2_assemble(
    const float* __restrict__ se, const float* __restrict__ cont,
    const int* __restrict__ width, const float* __restrict__ scores,
    const float* __restrict__ wemb, float* __restrict__ spans) {
    int nm = blockIdx.x, tid = threadIdx.x;
    int wd = width[nm];
    float sc[10];
    float m = NEG_INF;
#pragma unroll
    for (int t = 0; t < 10; ++t) {
        float s = scores[nm * 10 + t];
        sc[t] = (t < wd) ? s : NEGV;
        m = fmaxf(m, sc[t]);
    }
    float sum = 0.f;
#pragma unroll
    for (int t = 0; t < 10; ++t) { sc[t] = expf(sc[t] - m); sum += sc[t]; }
    float inv = 1.f / sum;
#pragma unroll
    for (int t = 0; t < 10; ++t) sc[t] *= inv;
    const float* cbase = cont + (size_t)nm * 7680;
    float* srow = spans + (size_t)nm * 2324;
    for (int d = tid; d < 768; d += 256) {
        float acc = 0.f;
#pragma unroll
        for (int t = 0; t < 10; ++t) acc = fmaf(sc[t], cbase[t * 768 + d], acc);
        srow[1536 + d] = acc;
    }
    for (int idx = tid; idx < 1536; idx += 256) srow[idx] = se[(size_t)nm * 1536 + idx];
    if (tid < 20) srow[2304 + tid] = wemb[min(wd, 4) * 20 + tid];
}

// ---------------- K3: grounding S_g, one block per (s,v) ----------------
__global__ __launch_bounds__(256) void k3_grounding(
    const float* __restrict__ doc, const float* __restrict__ img,
    const float* __restrict__ tm, const float* __restrict__ im,
    float* __restrict__ Sg) {
    __shared__ float dsh[64][65];
    __shared__ float ish[36][65];
    __shared__ float att[64][37];
    __shared__ float tmv[64], imv[36];
    __shared__ float s1sh;
    int b = blockIdx.x;
    int s = b >> 3, v = b & 7;
    int tid = threadIdx.x;
    if (tid < 64) tmv[tid] = tm[s * 64 + tid];
    if (tid >= 64 && tid < 100) imv[tid - 64] = im[v * 36 + (tid - 64)];
    float accv[9];
#pragma unroll
    for (int r = 0; r < 9; ++r) accv[r] = 0.f;
    for (int kc = 0; kc < 16; ++kc) {
        int k0 = kc * 64;
        __syncthreads();
#pragma unroll
        for (int l = 0; l < 16; ++l) {
            int idx = tid + 256 * l;
            dsh[idx >> 6][idx & 63] = doc[(size_t)(s * 64 + (idx >> 6)) * 1024 + k0 + (idx & 63)];
        }
#pragma unroll
        for (int l = 0; l < 9; ++l) {
            int idx = tid + 256 * l;
            ish[idx >> 6][idx & 63] = img[(size_t)(v * 36 + (idx >> 6)) * 1024 + k0 + (idx & 63)];
        }
        __syncthreads();
#pragma unroll
        for (int r = 0; r < 9; ++r) {
            int e = tid + 256 * r;
            int i = e / 36, j = e - i * 36;
            float a = 0.f;
            for (int k = 0; k < 64; ++k) a = fmaf(dsh[i][k], ish[j][k], a);
            accv[r] += a;
        }
    }
    __syncthreads();
#pragma unroll
    for (int r = 0; r < 9; ++r) {
        int e = tid + 256 * r;
        int i = e / 36, j = e - i * 36;
        float x = accv[r] * tmv[i] * imv[j];
        att[i][j] = (x != 0.f) ? x : NEGV;
    }
    __syncthreads();
    float part = 0.f;
    if (tid < 64) {
        int i = tid;
        float mx = NEG_INF;
        for (int j = 0; j < 36; ++j) mx = fmaxf(mx, att[i][j] * imv[j]);
        float sum = 0.f;
        for (int j = 0; j < 36; ++j) sum += expf(att[i][j] * imv[j] - mx);
        float invs = 1.f / sum;
        for (int j = 0; j < 36; ++j) {
            float aw = expf(att[i][j] * imv[j] - mx) * invs * (tmv[i] * imv[j]);
            part += aw * att[i][j];
        }
        for (int off = 32; off > 0; off >>= 1) part += __shfl_down(part, off);
        if (tid == 0) s1sh = part;
    }
    __syncthreads();
    if (tid < 64) {
        float part2 = 0.f;
        if (tid < 36) {
            int j = tid;
            float mx = NEG_INF;
            for (int i = 0; i < 64; ++i) mx = fmaxf(mx, att[i][j]);
            float sum = 0.f;
            for (int i = 0; i < 64; ++i) sum += expf(att[i][j] - mx);
            float invs = 1.f / sum;
            for (int i = 0; i < 64; ++i) {
                float aw = expf(att[i][j] - mx) * invs * (tmv[i] * imv[j]);
                part2 += aw * att[i][j];
            }
        }
        for (int off = 32; off > 0; off >>= 1) part2 += __shfl_down(part2, off);
        if (tid == 0) Sg[s * 8 + v] = s1sh + part2;
    }
}

// ---------------- K4: a = spans@w1[:SD], b = spans@w1[SD:2SD]  (fp32, K-split, atomic) ----
__global__ __launch_bounds__(256) void k4_ab(
    const float* __restrict__ spans, const float* __restrict__ w1,
    float* __restrict__ aout, float* __restrict__ bout) {
    __shared__ __align__(16) float As[4][128];
    __shared__ __align__(16) float Ws[4][64];
    int tid = threadIdx.x;
    int tx = tid & 15, ty = tid >> 4;
    int col0 = blockIdx.x * 64;
    int half = blockIdx.y;
    int kz = blockIdx.z;
    const float* wbase = w1 + (size_t)half * 2324 * 1024;
    float* outp = half ? bout : aout;
    float acc[8][4];
#pragma unroll
    for (int r = 0; r < 8; ++r)
#pragma unroll
        for (int j = 0; j < 4; ++j) acc[r][j] = 0.f;
    for (int k0 = kz * 4; k0 < 2324; k0 += 16) {
#pragma unroll
        for (int l = 0; l < 2; ++l) {
            int idx = tid * 2 + l;
            int mm = idx >> 2, kk = idx & 3;
            As[kk][mm] = spans[(size_t)mm * 2324 + k0 + kk];
        }
        {
            int kk = tid >> 6, c = tid & 63;
            Ws[kk][c] = wbase[(size_t)(k0 + kk) * 1024 + col0 + c];
        }
        __syncthreads();
#pragma unroll
        for (int kk = 0; kk < 4; ++kk) {
            float4 w = *(const float4*)&Ws[kk][tx * 4];
            float4 x0 = *(const float4*)&As[kk][ty * 8];
            float4 x1 = *(const float4*)&As[kk][ty * 8 + 4];
            float ar[8] = {x0.x, x0.y, x0.z, x0.w, x1.x, x1.y, x1.z, x1.w};
            float wr[4] = {w.x, w.y, w.z, w.w};
#pragma unroll
            for (int r = 0; r < 8; ++r)
#pragma unroll
                for (int j = 0; j < 4; ++j) acc[r][j] = fmaf(ar[r], wr[j], acc[r][j]);
        }
        __syncthreads();
    }
#pragma unroll
    for (int r = 0; r < 8; ++r)
#pragma unroll
        for (int j = 0; j < 4; ++j)
            atomicAdd(&outp[(size_t)(ty * 8 + r) * 1024 + col0 + tx * 4 + j], acc[r][j]);
}

// ---------------- K5 (MFMA): h[u,w,:] = relu((s_u.*s_w)@W1c + a[u]+b[w]+b1) ----------------
// A_u generated on the fly from bf16 spans; B = pre-transposed bf16 W1c [n][2368].
// LDS: chunk-swizzled [row][32] bf16, chunk c at c ^ ((row>>1)&3) -> bank-floor b128 R/W.
__global__ __launch_bounds__(256) void k5_mfma(
    const unsigned short* __restrict__ sb, const unsigned short* __restrict__ wT,
    const float* __restrict__ a, const float* __restrict__ b,
    const float* __restrict__ b1, unsigned short* __restrict__ h) {
    __shared__ __align__(16) unsigned short Ash[128 * 32];
    __shared__ __align__(16) unsigned short Bsh[128 * 32];
    int tid = threadIdx.x;
    int u = blockIdx.y;
    int col0 = blockIdx.x * 128;
    int lane = tid & 63, wave = tid >> 6;
    int wm = wave >> 1, wn = wave & 1;
    int q = lane >> 4, l15 = lane & 15;

    floatx4 acc[4][4];
#pragma unroll
    for (int i = 0; i < 4; ++i)
#pragma unroll
        for (int j = 0; j < 4; ++j) acc[i][j] = (floatx4){0.f, 0.f, 0.f, 0.f};

    int r = tid >> 1;
    int cb = (tid & 1) * 2;
    int sw = (r >> 1) & 3;
    const unsigned short* arow = sb + (size_t)r * 2368 + cb * 8;
    const unsigned short* urow = sb + (size_t)u * 2368 + cb * 8;
    const unsigned short* brow = wT + (size_t)(col0 + r) * 2368 + cb * 8;
    unsigned short* awp0 = Ash + r * 32 + (cb ^ sw) * 8;
    unsigned short* awp1 = Ash + r * 32 + ((cb + 1) ^ sw) * 8;
    unsigned short* bwp0 = Bsh + r * 32 + (cb ^ sw) * 8;
    unsigned short* bwp1 = Bsh + r * 32 + ((cb + 1) ^ sw) * 8;

    for (int kt = 0; kt < 74; ++kt) {
        int k0 = kt * 32;
        uint4 av0 = *(const uint4*)(arow + k0);
        uint4 av1 = *(const uint4*)(arow + k0 + 8);
        uint4 uv0 = *(const uint4*)(urow + k0);
        uint4 uv1 = *(const uint4*)(urow + k0 + 8);
        uint4 bv0 = *(const uint4*)(brow + k0);
        uint4 bv1 = *(const uint4*)(brow + k0 + 8);
        __syncthreads();
        uint4 p0, p1;
        p0.x = mul2bf(av0.x, uv0.x); p0.y = mul2bf(av0.y, uv0.y);
        p0.z = mul2bf(av0.z, uv0.z); p0.w = mul2bf(av0.w, uv0.w);
        p1.x = mul2bf(av1.x, uv1.x); p1.y = mul2bf(av1.y, uv1.y);
        p1.z = mul2bf(av1.z, uv1.z); p1.w = mul2bf(av1.w, uv1.w);
        *(uint4*)awp0 = p0;
        *(uint4*)awp1 = p1;
        *(uint4*)bwp0 = bv0;
        *(uint4*)bwp1 = bv1;
        __syncthreads();
        short8 af[4], bfv[4];
#pragma unroll
        for (int i = 0; i < 4; ++i) {
            int rA = wm * 64 + i * 16 + l15;
            af[i] = *(const short8*)(Ash + rA * 32 + (q ^ ((rA >> 1) & 3)) * 8);
        }
#pragma unroll
        for (int j = 0; j < 4; ++j) {
            int rB = wn * 64 + j * 16 + l15;
            bfv[j] = *(const short8*)(Bsh + rB * 32 + (q ^ ((rB >> 1) & 3)) * 8);
        }
#pragma unroll
        for (int i = 0; i < 4; ++i)
#pragma unroll
            for (int j = 0; j < 4; ++j)
                acc[i][j] = __builtin_amdgcn_mfma_f32_16x16x32_bf16(af[i], bfv[j], acc[i][j], 0, 0, 0);
    }

    float aU[4], b1v[4];
    int nj[4];
#pragma unroll
    for (int j = 0; j < 4; ++j) {
        nj[j] = col0 + wn * 64 + j * 16 + l15;
        aU[j] = a[u * 1024 + nj[j]];
        b1v[j] = b1[nj[j]];
    }
    size_t hbase = (size_t)u * 128 * 1024;
#pragma unroll
    for (int i = 0; i < 4; ++i) {
#pragma unroll
        for (int reg = 0; reg < 4; ++reg) {
            int w = wm * 64 + i * 16 + q * 4 + reg;
            const float* brw = b + (size_t)w * 1024;
            unsigned short* hrow = h + hbase + (size_t)w * 1024;
#pragma unroll
            for (int j = 0; j < 4; ++j) {
                float v = acc[i][j][reg] + aU[j] + brw[nj[j]] + b1v[j];
                hrow[nj[j]] = f2b(fmaxf(v, 0.f));
            }
        }
    }
}

// ---------------- K6 (MFMA): ts[m] += sum_n relu(h@W2 + b2)[m,n] * w3[n] ----------------
__global__ __launch_bounds__(256) void k6_mfma(
    const unsigned short* __restrict__ h, const unsigned short* __restrict__ w2T,
    const float* __restrict__ b2, const float* __restrict__ w3,
    float* __restrict__ ts) {
    __shared__ __align__(16) unsigned short Ash[128 * 32];
    __shared__ __align__(16) unsigned short Bsh[128 * 32];
    int tid = threadIdx.x;
    int m0 = blockIdx.y * 128;
    int col0 = blockIdx.x * 128;
    int lane = tid & 63, wave = tid >> 6;
    int wm = wave >> 1, wn = wave & 1;
    int q = lane >> 4, l15 = lane & 15;

    floatx4 acc[4][4];
#pragma unroll
    for (int i = 0; i < 4; ++i)
#pragma unroll
        for (int j = 0; j < 4; ++j) acc[i][j] = (floatx4){0.f, 0.f, 0.f, 0.f};

    int r = tid >> 1;
    int cb = (tid & 1) * 2;
    int sw = (r >> 1) & 3;
    const unsigned short* arow = h + (size_t)(m0 + r) * 1024 + cb * 8;
    const unsigned short* brow = w2T + (size_t)(col0 + r) * 1024 + cb * 8;
    unsigned short* awp0 = Ash + r * 32 + (cb ^ sw) * 8;
    unsigned short* awp1 = Ash + r * 32 + ((cb + 1) ^ sw) * 8;
    unsigned short* bwp0 = Bsh + r * 32 + (cb ^ sw) * 8;
    unsigned short* bwp1 = Bsh + r * 32 + ((cb + 1) ^ sw) * 8;

    for (int kt = 0; kt < 32; ++kt) {
        int k0 = kt * 32;
        uint4 av0 = *(const uint4*)(arow + k0);
        uint4 av1 = *(const uint4*)(arow + k0 + 8);
        uint4 bv0 = *(const uint4*)(brow + k0);
        uint4 bv1 = *(const uint4*)(brow + k0 + 8);
        __syncthreads();
        *(uint4*)awp0 = av0;
        *(uint4*)awp1 = av1;
        *(uint4*)bwp0 = bv0;
        *(uint4*)bwp1 = bv1;
        __syncthreads();
        short8 af[4], bfv[4];
#pragma unroll
        for (int i = 0; i < 4; ++i) {
            int rA = wm * 64 + i * 16 + l15;
            af[i] = *(const short8*)(Ash + rA * 32 + (q ^ ((rA >> 1) & 3)) * 8);
        }
#pragma unroll
        for (int j = 0; j < 4; ++j) {
            int rB = wn * 64 + j * 16 + l15;
            bfv[j] = *(const short8*)(Bsh + rB * 32 + (q ^ ((rB >> 1) & 3)) * 8);
        }
#pragma unroll
        for (int i = 0; i < 4; ++i)
#pragma unroll
            for (int j = 0; j < 4; ++j)
                acc[i][j] = __builtin_amdgcn_mfma_f32_16x16x32_bf16(af[i], bfv[j], acc[i][j], 0, 0, 0);
    }

    float b2v[4], w3v[4];
    int nj[4];
#pragma unroll
    for (int j = 0; j < 4; ++j) {
        nj[j] = col0 + wn * 64 + j * 16 + l15;
        b2v[j] = b2[nj[j]];
        w3v[j] = w3[nj[j]];
    }
#pragma unroll
    for (int i = 0; i < 4; ++i) {
#pragma unroll
        for (int reg = 0; reg < 4; ++reg) {
            float s = 0.f;
#pragma unroll
            for (int j = 0; j < 4; ++j)
                s += fmaxf(acc[i][j][reg] + b2v[j], 0.f) * w3v[j];
            s += __shfl_down(s, 8, 16);
            s += __shfl_down(s, 4, 16);
            s += __shfl_down(s, 2, 16);
            s += __shfl_down(s, 1, 16);
            if (l15 == 0)
                atomicAdd(&ts[m0 + wm * 64 + i * 16 + q * 4 + reg], s);
        }
    }
}

// ---------------- K7: adaptive S_c + final loss ----------------
__global__ void k7_final(const float* __restrict__ ts, const float* __restrict__ Sg,
                         const float* __restrict__ m1, const float* __restrict__ b3,
                         float* __restrict__ out) {
    __shared__ float Sc[64];
    __shared__ float mg[8][8], mgT[8][8], mc[8][8];
    int tid = threadIdx.x;
    float b3v = b3[0];
    if (tid < 64) {
        int s = tid >> 3, v = tid & 7;
        float cs = 0.f, cv = 0.f;
        for (int k = 0; k < 16; ++k) { cs += m1[s * 16 + k]; cv += m1[v * 16 + k]; }
        float max1 = NEG_INF;
        for (int i = 0; i < 16; ++i) {
            float rm = 0.f;
            for (int j = 0; j < 16; ++j)
                rm += (ts[(size_t)(s * 16 + i) * 128 + v * 16 + j] + b3v) * m1[v * 16 + j];
            rm /= cv;
            if (m1[s * 16 + i] > 0.f) max1 = fmaxf(max1, rm);
        }
        float max2 = NEG_INF;
        for (int j = 0; j < 16; ++j) {
            float cm = 0.f;
            for (int i = 0; i < 16; ++i)
                cm += (ts[(size_t)(s * 16 + i) * 128 + v * 16 + j] + b3v) * m1[s * 16 + i];
            cm /= cs;
            if (m1[v * 16 + j] > 0.f) max2 = fmaxf(max2, cm);
        }
        Sc[tid] = 0.5f * (max1 + max2);
    }
    __syncthreads();
    if (tid < 8) {
        int r = tid;
        float mx = NEG_INF;
        for (int v = 0; v < 8; ++v) mx = fmaxf(mx, Sg[r * 8 + v]);
        float sm = 0.f;
        for (int v = 0; v < 8; ++v) sm += expf(Sg[r * 8 + v] - mx);
        for (int v = 0; v < 8; ++v) mg[r][v] = expf(Sg[r * 8 + v] - mx) / sm;

        mx = NEG_INF;
        for (int v = 0; v < 8; ++v) mx = fmaxf(mx, Sc[r * 8 + v]);
        sm = 0.f;
        for (int v = 0; v < 8; ++v) sm += expf(Sc[r * 8 + v] - mx);
        for (int v = 0; v < 8; ++v) mc[r][v] = expf(Sc[r * 8 + v] - mx) / sm;

        mx = NEG_INF;
        for (int s2 = 0; s2 < 8; ++s2) mx = fmaxf(mx, Sg[s2 * 8 + r]);
        sm = 0.f;
        for (int s2 = 0; s2 < 8; ++s2) sm += expf(Sg[s2 * 8 + r] - mx);
        for (int s2 = 0; s2 < 8; ++s2) mgT[r][s2] = expf(Sg[s2 * 8 + r] - mx) / sm;
    }
    __syncthreads();
    if (tid == 0) {
        float loss = 0.f;
        for (int r = 0; r < 8; ++r) {
            float d1 = 0.f, d2 = 0.f;
            for (int v = 0; v < 8; ++v) {
                d1 += mg[r][v] * mc[r][v];
                d2 += mgT[r][v] * mc[r][v];
            }
            loss -= logf(d1) + logf(d2);
        }
        out[0] = loss / 8.f;
    }
}

extern "C" void kernel_launch(void* const* d_in, const int* in_sizes, int n_in,
                              void* d_out, int out_size, void* d_ws, size_t ws_size,
                              hipStream_t stream) {
    const float* doc   = (const float*)d_in[0];
    const float* img   = (const float*)d_in[1];
    const float* tm    = (const float*)d_in[2];
    const float* im    = (const float*)d_in[3];
    const float* se    = (const float*)d_in[4];
    const float* cont  = (const float*)d_in[5];
    const int*   width = (const int*)d_in[6];
    const float* m1    = (const float*)d_in[7];
    const float* aw1   = (const float*)d_in[8];
    const float* ab1   = (const float*)d_in[9];
    const float* aw2   = (const float*)d_in[10];
    const float* ab2   = (const float*)d_in[11];
    const float* wemb  = (const float*)d_in[12];
    const float* pw_w1 = (const float*)d_in[13];
    const float* pw_b1 = (const float*)d_in[14];
    const float* pw_w2 = (const float*)d_in[15];
    const float* pw_b2 = (const float*)d_in[16];
    const float* pw_w3 = (const float*)d_in[17];
    const float* pw_b3 = (const float*)d_in[18];
    float* out = (float*)d_out;

    char* ws = (char*)d_ws;
    float* spans            = (float*)(ws + 0);               // 128*2324 f32
    float* scores           = (float*)(ws + 1189888);         // 1280 f32
    float* a                = (float*)(ws + 1195008);         // 128*1024 f32
    float* b                = (float*)(ws + 1719296);         // 128*1024 f32
    float* Sg               = (float*)(ws + 2243584);         // 64 f32
    float* ts               = (float*)(ws + 2243840);         // 16384 f32
    unsigned short* sb      = (unsigned short*)(ws + 2309376); // 128*2368 bf16
    unsigned short* w1cT    = (unsigned short*)(ws + 2915584); // 1024*2368 bf16
    unsigned short* w2T     = (unsigned short*)(ws + 7765248); // 1024*1024 bf16
    unsigned short* h       = (unsigned short*)(ws + 9862400); // 16384*1024 bf16

    k0_init<<<512, 256, 0, stream>>>(ts, a, b);
    kT_transpose<<<dim3(37, 16), 256, 0, stream>>>(pw_w1 + (size_t)2 * 2324 * 1024, 1024, 2324, w1cT, 2368);
    kT_transpose<<<dim3(16, 16), 256, 0, stream>>>(pw_w2, 1024, 1024, w2T, 1024);
    k1_span_scores<<<128, 256, 0, stream>>>(cont, aw1, ab1, aw2, ab2, scores);
    k2_assemble<<<128, 256, 0, stream>>>(se, cont, width, scores, wemb, spans);
    kP_spansbf<<<1184, 256, 0, stream>>>(spans, sb);
    k3_grounding<<<64, 256, 0, stream>>>(doc, img, tm, im, Sg);
    k4_ab<<<dim3(16, 2, 4), 256, 0, stream>>>(spans, pw_w1, a, b);
    k5_mfma<<<dim3(8, 128), 256, 0, stream>>>(sb, w1cT, a, b, pw_b1, h);
    k6_mfma<<<dim3(8, 128), 256, 0, stream>>>(h, w2T, pw_b2, pw_w3, ts);
    k7_final<<<1, 64, 0, stream>>>(ts, Sg, m1, pw_b3, out);
}

// Round 3
// 699.657 us; speedup vs baseline: 2.9247x; 1.0432x over previous
//
#include <hip/hip_runtime.h>
#include <hip/hip_bf16.h>

#define NEGV -1e10f
#define NEG_INF -3.402823466e38f

typedef __attribute__((ext_vector_type(8))) short short8;
typedef __attribute__((ext_vector_type(4))) float floatx4;

__device__ inline float bf2f(unsigned short u) {
    union { unsigned int i; float f; } c; c.i = ((unsigned int)u) << 16; return c.f;
}
__device__ inline unsigned short f2b(float f) {
    __hip_bfloat16 h = __float2bfloat16(f);
    return *reinterpret_cast<unsigned short*>(&h);
}
// product of two packed bf16 pairs -> packed bf16 pair (RNE)
__device__ inline unsigned int mul2bf(unsigned int x, unsigned int y) {
    union { unsigned int i; float f; } xl, xh, yl, yh;
    xl.i = x << 16; xh.i = x & 0xffff0000u;
    yl.i = y << 16; yh.i = y & 0xffff0000u;
    unsigned int lo = f2b(xl.f * yl.f);
    unsigned int hi = f2b(xh.f * yh.f);
    return lo | (hi << 16);
}

#define GLL16(g, l) __builtin_amdgcn_global_load_lds( \
    (const __attribute__((address_space(1))) void*)(g), \
    (__attribute__((address_space(3))) void*)(l), 16, 0, 0)

// ---------------- K0: zero-init ts, a, b ----------------
__global__ void k0_init(float* ts, float* a, float* b) {
    int i = blockIdx.x * blockDim.x + threadIdx.x;
    if (i < 16384) ts[i] = 0.f;
    if (i < 131072) { a[i] = 0.f; b[i] = 0.f; }
}

// ---------------- KT: transpose fp32 [K][N] -> bf16 [N][Kpad] (zero-pad K) ----------------
__global__ __launch_bounds__(256) void kT_transpose(
    const float* __restrict__ in, int ldin, int krows,
    unsigned short* __restrict__ out, int ldout) {
    __shared__ unsigned short L[64][66];
    int t = threadIdx.x;
    int kt = blockIdx.x * 64, nt = blockIdx.y * 64;
    int nl = t & 63, g = t >> 6;
#pragma unroll
    for (int i = 0; i < 16; ++i) {
        int kl = g * 16 + i;
        int k = kt + kl;
        float v = (k < krows) ? in[(size_t)k * ldin + nt + nl] : 0.f;
        L[kl][nl] = f2b(v);
    }
    __syncthreads();
    int kl2 = t & 63;
#pragma unroll
    for (int i = 0; i < 16; ++i) {
        int nl2 = g * 16 + i;
        out[(size_t)(nt + nl2) * ldout + kt + kl2] = L[kl2][nl2];
    }
}

// ---------------- KP: spans fp32 [128][2324] -> bf16 [128][2368] zero-padded ----------------
__global__ void kP_spansbf(const float* __restrict__ spans, unsigned short* __restrict__ sb) {
    int i = blockIdx.x * 256 + threadIdx.x;
    if (i >= 128 * 2368) return;
    int r = i / 2368, k = i - r * 2368;
    float v = (k < 2324) ? spans[r * 2324 + k] : 0.f;
    sb[i] = f2b(v);
}

// ---------------- KP2: P[u*128+w][k] = sb[u][k]*sb[w][k]  (bf16, memory-bound) ------------
__global__ __launch_bounds__(256) void kP2_products(
    const unsigned short* __restrict__ sb, unsigned short* __restrict__ P) {
    int w = blockIdx.x, u = blockIdx.y;
    int tid = threadIdx.x;
    const uint4* su = (const uint4*)(sb + (size_t)u * 2368);
    const uint4* sw = (const uint4*)(sb + (size_t)w * 2368);
    uint4* out = (uint4*)(P + ((size_t)u * 128 + w) * 2368);
    for (int i = tid; i < 296; i += 256) {
        uint4 a = su[i], b = sw[i];
        uint4 r;
        r.x = mul2bf(a.x, b.x); r.y = mul2bf(a.y, b.y);
        r.z = mul2bf(a.z, b.z); r.w = mul2bf(a.w, b.w);
        out[i] = r;
    }
}

// ---------------- K1: span head-attention scores (fp32) ----------------
__global__ __launch_bounds__(256) void k1_span_scores(
    const float* __restrict__ cont, const float* __restrict__ aw1,
    const float* __restrict__ ab1, const float* __restrict__ aw2,
    const float* __restrict__ ab2, float* __restrict__ scores) {
    __shared__ float cont_sh[10][768];
    __shared__ float red[4][10];
    int nm = blockIdx.x;
    int tid = threadIdx.x;
    const float* cbase = cont + (size_t)nm * 7680;
    for (int idx = tid; idx < 7680; idx += 256) cont_sh[idx / 768][idx % 768] = cbase[idx];
    __syncthreads();
    int c0 = tid * 4;
    float acc[10][4];
#pragma unroll
    for (int t = 0; t < 10; ++t)
#pragma unroll
        for (int j = 0; j < 4; ++j) acc[t][j] = 0.f;
    for (int k = 0; k < 768; ++k) {
        float4 w = *(const float4*)&aw1[(size_t)k * 1024 + c0];
#pragma unroll
        for (int t = 0; t < 10; ++t) {
            float cv = cont_sh[t][k];
            acc[t][0] = fmaf(cv, w.x, acc[t][0]);
            acc[t][1] = fmaf(cv, w.y, acc[t][1]);
            acc[t][2] = fmaf(cv, w.z, acc[t][2]);
            acc[t][3] = fmaf(cv, w.w, acc[t][3]);
        }
    }
    float4 b1 = *(const float4*)&ab1[c0];
    float4 w2 = *(const float4*)&aw2[c0];
    int lane = tid & 63, wave = tid >> 6;
#pragma unroll
    for (int t = 0; t < 10; ++t) {
        float s = fmaxf(acc[t][0] + b1.x, 0.f) * w2.x
                + fmaxf(acc[t][1] + b1.y, 0.f) * w2.y
                + fmaxf(acc[t][2] + b1.z, 0.f) * w2.z
                + fmaxf(acc[t][3] + b1.w, 0.f) * w2.w;
        for (int off = 32; off > 0; off >>= 1) s += __shfl_down(s, off);
        if (lane == 0) red[wave][t] = s;
    }
    __syncthreads();
    if (tid < 10)
        scores[nm * 10 + tid] = red[0][tid] + red[1][tid] + red[2][tid] + red[3][tid] + ab2[0];
}

// ---------------- K2: softmax over span tokens, assemble span embeddings ----------------
__global__ __launch_bounds__(256) void k2_assemble(
    const float* __restrict__ se, const float* __restrict__ cont,
    const int* __restrict__ width, const float* __restrict__ scores,
    const float* __restrict__ wemb, float* __restrict__ spans) {
    int nm = blockIdx.x, tid = threadIdx.x;
    int wd = width[nm];
    float sc[10];
    float m = NEG_INF;
#pragma unroll
    for (int t = 0; t < 10; ++t) {
        float s = scores[nm * 10 + t];
        sc[t] = (t < wd) ? s : NEGV;
        m = fmaxf(m, sc[t]);
    }
    float sum = 0.f;
#pragma unroll
    for (int t = 0; t < 10; ++t) { sc[t] = expf(sc[t] - m); sum += sc[t]; }
    float inv = 1.f / sum;
#pragma unroll
    for (int t = 0; t < 10; ++t) sc[t] *= inv;
    const float* cbase = cont + (size_t)nm * 7680;
    float* srow = spans + (size_t)nm * 2324;
    for (int d = tid; d < 768; d += 256) {
        float acc = 0.f;
#pragma unroll
        for (int t = 0; t < 10; ++t) acc = fmaf(sc[t], cbase[t * 768 + d], acc);
        srow[1536 + d] = acc;
    }
    for (int idx = tid; idx < 1536; idx += 256) srow[idx] = se[(size_t)nm * 1536 + idx];
    if (tid < 20) srow[2304 + tid] = wemb[min(wd, 4) * 20 + tid];
}

// ---------------- K3: grounding S_g, one block per (s,v) ----------------
__global__ __launch_bounds__(256) void k3_grounding(
    const float* __restrict__ doc, const float* __restrict__ img,
    const float* __restrict__ tm, const float* __restrict__ im,
    float* __restrict__ Sg) {
    __shared__ float dsh[64][65];
    __shared__ float ish[36][65];
    __shared__ float att[64][37];
    __shared__ float tmv[64], imv[36];
    __shared__ float s1sh;
    int b = blockIdx.x;
    int s = b >> 3, v = b & 7;
    int tid = threadIdx.x;
    if (tid < 64) tmv[tid] = tm[s * 64 + tid];
    if (tid >= 64 && tid < 100) imv[tid - 64] = im[v * 36 + (tid - 64)];
    float accv[9];
#pragma unroll
    for (int r = 0; r < 9; ++r) accv[r] = 0.f;
    for (int kc = 0; kc < 16; ++kc) {
        int k0 = kc * 64;
        __syncthreads();
#pragma unroll
        for (int l = 0; l < 16; ++l) {
            int idx = tid + 256 * l;
            dsh[idx >> 6][idx & 63] = doc[(size_t)(s * 64 + (idx >> 6)) * 1024 + k0 + (idx & 63)];
        }
#pragma unroll
        for (int l = 0; l < 9; ++l) {
            int idx = tid + 256 * l;
            ish[idx >> 6][idx & 63] = img[(size_t)(v * 36 + (idx >> 6)) * 1024 + k0 + (idx & 63)];
        }
        __syncthreads();
#pragma unroll
        for (int r = 0; r < 9; ++r) {
            int e = tid + 256 * r;
            int i = e / 36, j = e - i * 36;
            float a = 0.f;
            for (int k = 0; k < 64; ++k) a = fmaf(dsh[i][k], ish[j][k], a);
            accv[r] += a;
        }
    }
    __syncthreads();
#pragma unroll
    for (int r = 0; r < 9; ++r) {
        int e = tid + 256 * r;
        int i = e / 36, j = e - i * 36;
        float x = accv[r] * tmv[i] * imv[j];
        att[i][j] = (x != 0.f) ? x : NEGV;
    }
    __syncthreads();
    float part = 0.f;
    if (tid < 64) {
        int i = tid;
        float mx = NEG_INF;
        for (int j = 0; j < 36; ++j) mx = fmaxf(mx, att[i][j] * imv[j]);
        float sum = 0.f;
        for (int j = 0; j < 36; ++j) sum += expf(att[i][j] * imv[j] - mx);
        float invs = 1.f / sum;
        for (int j = 0; j < 36; ++j) {
            float aw = expf(att[i][j] * imv[j] - mx) * invs * (tmv[i] * imv[j]);
            part += aw * att[i][j];
        }
        for (int off = 32; off > 0; off >>= 1) part += __shfl_down(part, off);
        if (tid == 0) s1sh = part;
    }
    __syncthreads();
    if (tid < 64) {
        float part2 = 0.f;
        if (tid < 36) {
            int j = tid;
            float mx = NEG_INF;
            for (int i = 0; i < 64; ++i) mx = fmaxf(mx, att[i][j]);
            float sum = 0.f;
            for (int i = 0; i < 64; ++i) sum += expf(att[i][j] - mx);
            float invs = 1.f / sum;
            for (int i = 0; i < 64; ++i) {
                float aw = expf(att[i][j] - mx) * invs * (tmv[i] * imv[j]);
                part2 += aw * att[i][j];
            }
        }
        for (int off = 32; off > 0; off >>= 1) part2 += __shfl_down(part2, off);
        if (tid == 0) Sg[s * 8 + v] = s1sh + part2;
    }
}

// ---------------- K4: a = spans@w1[:SD], b = spans@w1[SD:2SD]  (fp32, K-split, atomic) ----
__global__ __launch_bounds__(256) void k4_ab(
    const float* __restrict__ spans, const float* __restrict__ w1,
    float* __restrict__ aout, float* __restrict__ bout) {
    __shared__ __align__(16) float As[4][128];
    __shared__ __align__(16) float Ws[4][64];
    int tid = threadIdx.x;
    int tx = tid & 15, ty = tid >> 4;
    int col0 = blockIdx.x * 64;
    int half = blockIdx.y;
    int kz = blockIdx.z;
    const float* wbase = w1 + (size_t)half * 2324 * 1024;
    float* outp = half ? bout : aout;
    float acc[8][4];
#pragma unroll
    for (int r = 0; r < 8; ++r)
#pragma unroll
        for (int j = 0; j < 4; ++j) acc[r][j] = 0.f;
    for (int k0 = kz * 4; k0 < 2324; k0 += 16) {
#pragma unroll
        for (int l = 0; l < 2; ++l) {
            int idx = tid * 2 + l;
            int mm = idx >> 2, kk = idx & 3;
            As[kk][mm] = spans[(size_t)mm * 2324 + k0 + kk];
        }
        {
            int kk = tid >> 6, c = tid & 63;
            Ws[kk][c] = wbase[(size_t)(k0 + kk) * 1024 + col0 + c];
        }
        __syncthreads();
#pragma unroll
        for (int kk = 0; kk < 4; ++kk) {
            float4 w = *(const float4*)&Ws[kk][tx * 4];
            float4 x0 = *(const float4*)&As[kk][ty * 8];
            float4 x1 = *(const float4*)&As[kk][ty * 8 + 4];
            float ar[8] = {x0.x, x0.y, x0.z, x0.w, x1.x, x1.y, x1.z, x1.w};
            float wr[4] = {w.x, w.y, w.z, w.w};
#pragma unroll
            for (int r = 0; r < 8; ++r)
#pragma unroll
                for (int j = 0; j < 4; ++j) acc[r][j] = fmaf(ar[r], wr[j], acc[r][j]);
        }
        __syncthreads();
    }
#pragma unroll
    for (int r = 0; r < 8; ++r)
#pragma unroll
        for (int j = 0; j < 4; ++j)
            atomicAdd(&outp[(size_t)(ty * 8 + r) * 1024 + col0 + tx * 4 + j], acc[r][j]);
}

// ---------------- K5v3 (MFMA + global_load_lds): h = relu(P[u] @ W1cT + a[u]+b[w]+b1) -----
// LDS chunk-swizzle applied on the GLOBAL source side (lane-constant), since
// global_load_lds forces LDS dest = base + lane*16.
__global__ __launch_bounds__(256) void k5_gemm(
    const unsigned short* __restrict__ P, const unsigned short* __restrict__ wT,
    const float* __restrict__ a, const float* __restrict__ b,
    const float* __restrict__ b1, unsigned short* __restrict__ h) {
    __shared__ __align__(16) unsigned short Ash[128 * 32];
    __shared__ __align__(16) unsigned short Bsh[128 * 32];
    int tid = threadIdx.x;
    int u = blockIdx.y;
    int col0 = blockIdx.x * 128;
    int lane = tid & 63, wave = tid >> 6;
    int wm = wave >> 1, wn = wave & 1;
    int q = lane >> 4, l15 = lane & 15;

    floatx4 acc[4][4];
#pragma unroll
    for (int i = 0; i < 4; ++i)
#pragma unroll
        for (int j = 0; j < 4; ++j) acc[i][j] = (floatx4){0.f, 0.f, 0.f, 0.f};

    // staging: wave covers LDS chunk-ids ci0=2*wave, ci1=2*wave+1 for A and B
    int ci0 = wave * 2, ci1 = wave * 2 + 1;
    int p = lane & 3;
    int r0 = ci0 * 16 + (lane >> 2), r1 = ci1 * 16 + (lane >> 2);
    int c0s = p ^ ((r0 >> 1) & 3), c1s = p ^ ((r1 >> 1) & 3);
    const char* gA0 = (const char*)(P + (size_t)(u * 128 + r0) * 2368) + c0s * 16;
    const char* gA1 = (const char*)(P + (size_t)(u * 128 + r1) * 2368) + c1s * 16;
    const char* gB0 = (const char*)(wT + (size_t)(col0 + r0) * 2368) + c0s * 16;
    const char* gB1 = (const char*)(wT + (size_t)(col0 + r1) * 2368) + c1s * 16;
    unsigned short* lA0 = Ash + ci0 * 512;
    unsigned short* lA1 = Ash + ci1 * 512;
    unsigned short* lB0 = Bsh + ci0 * 512;
    unsigned short* lB1 = Bsh + ci1 * 512;

    for (int kt = 0; kt < 74; ++kt) {
        __syncthreads();             // all waves done reading previous tile
        GLL16(gA0, lA0);
        GLL16(gA1, lA1);
        GLL16(gB0, lB0);
        GLL16(gB1, lB1);
        gA0 += 64; gA1 += 64; gB0 += 64; gB1 += 64;
        __syncthreads();             // staging complete (vmcnt drained by barrier)
        short8 af[4], bfv[4];
#pragma unroll
        for (int i = 0; i < 4; ++i) {
            int rA = wm * 64 + i * 16 + l15;
            af[i] = *(const short8*)(Ash + rA * 32 + (q ^ ((rA >> 1) & 3)) * 8);
        }
#pragma unroll
        for (int j = 0; j < 4; ++j) {
            int rB = wn * 64 + j * 16 + l15;
            bfv[j] = *(const short8*)(Bsh + rB * 32 + (q ^ ((rB >> 1) & 3)) * 8);
        }
#pragma unroll
        for (int i = 0; i < 4; ++i)
#pragma unroll
            for (int j = 0; j < 4; ++j)
                acc[i][j] = __builtin_amdgcn_mfma_f32_16x16x32_bf16(af[i], bfv[j], acc[i][j], 0, 0, 0);
    }

    float aU[4], b1v[4];
    int nj[4];
#pragma unroll
    for (int j = 0; j < 4; ++j) {
        nj[j] = col0 + wn * 64 + j * 16 + l15;
        aU[j] = a[u * 1024 + nj[j]];
        b1v[j] = b1[nj[j]];
    }
    size_t hbase = (size_t)u * 128 * 1024;
#pragma unroll
    for (int i = 0; i < 4; ++i) {
#pragma unroll
        for (int reg = 0; reg < 4; ++reg) {
            int w = wm * 64 + i * 16 + q * 4 + reg;
            const float* brw = b + (size_t)w * 1024;
            unsigned short* hrow = h + hbase + (size_t)w * 1024;
#pragma unroll
            for (int j = 0; j < 4; ++j) {
                float v = acc[i][j][reg] + aU[j] + brw[nj[j]] + b1v[j];
                hrow[nj[j]] = f2b(fmaxf(v, 0.f));
            }
        }
    }
}

// ---------------- K5 fallback (round-2, on-the-fly product; used if ws too small) --------
__global__ __launch_bounds__(256) void k5_mfma(
    const unsigned short* __restrict__ sb, const unsigned short* __restrict__ wT,
    const float* __restrict__ a, const float* __restrict__ b,
    const float* __restrict__ b1, unsigned short* __restrict__ h) {
    __shared__ __align__(16) unsigned short Ash[128 * 32];
    __shared__ __align__(16) unsigned short Bsh[128 * 32];
    int tid = threadIdx.x;
    int u = blockIdx.y;
    int col0 = blockIdx.x * 128;
    int lane = tid & 63, wave = tid >> 6;
    int wm = wave >> 1, wn = wave & 1;
    int q = lane >> 4, l15 = lane & 15;

    floatx4 acc[4][4];
#pragma unroll
    for (int i = 0; i < 4; ++i)
#pragma unroll
        for (int j = 0; j < 4; ++j) acc[i][j] = (floatx4){0.f, 0.f, 0.f, 0.f};

    int r = tid >> 1;
    int cb = (tid & 1) * 2;
    int sw = (r >> 1) & 3;
    const unsigned short* arow = sb + (size_t)r * 2368 + cb * 8;
    const unsigned short* urow = sb + (size_t)u * 2368 + cb * 8;
    const unsigned short* brow = wT + (size_t)(col0 + r) * 2368 + cb * 8;
    unsigned short* awp0 = Ash + r * 32 + (cb ^ sw) * 8;
    unsigned short* awp1 = Ash + r * 32 + ((cb + 1) ^ sw) * 8;
    unsigned short* bwp0 = Bsh + r * 32 + (cb ^ sw) * 8;
    unsigned short* bwp1 = Bsh + r * 32 + ((cb + 1) ^ sw) * 8;

    for (int kt = 0; kt < 74; ++kt) {
        int k0 = kt * 32;
        uint4 av0 = *(const uint4*)(arow + k0);
        uint4 av1 = *(const uint4*)(arow + k0 + 8);
        uint4 uv0 = *(const uint4*)(urow + k0);
        uint4 uv1 = *(const uint4*)(urow + k0 + 8);
        uint4 bv0 = *(const uint4*)(brow + k0);
        uint4 bv1 = *(const uint4*)(brow + k0 + 8);
        __syncthreads();
        uint4 p0, p1;
        p0.x = mul2bf(av0.x, uv0.x); p0.y = mul2bf(av0.y, uv0.y);
        p0.z = mul2bf(av0.z, uv0.z); p0.w = mul2bf(av0.w, uv0.w);
        p1.x = mul2bf(av1.x, uv1.x); p1.y = mul2bf(av1.y, uv1.y);
        p1.z = mul2bf(av1.z, uv1.z); p1.w = mul2bf(av1.w, uv1.w);
        *(uint4*)awp0 = p0;
        *(uint4*)awp1 = p1;
        *(uint4*)bwp0 = bv0;
        *(uint4*)bwp1 = bv1;
        __syncthreads();
        short8 af[4], bfv[4];
#pragma unroll
        for (int i = 0; i < 4; ++i) {
            int rA = wm * 64 + i * 16 + l15;
            af[i] = *(const short8*)(Ash + rA * 32 + (q ^ ((rA >> 1) & 3)) * 8);
        }
#pragma unroll
        for (int j = 0; j < 4; ++j) {
            int rB = wn * 64 + j * 16 + l15;
            bfv[j] = *(const short8*)(Bsh + rB * 32 + (q ^ ((rB >> 1) & 3)) * 8);
        }
#pragma unroll
        for (int i = 0; i < 4; ++i)
#pragma unroll
            for (int j = 0; j < 4; ++j)
                acc[i][j] = __builtin_amdgcn_mfma_f32_16x16x32_bf16(af[i], bfv[j], acc[i][j], 0, 0, 0);
    }

    float aU[4], b1v[4];
    int nj[4];
#pragma unroll
    for (int j = 0; j < 4; ++j) {
        nj[j] = col0 + wn * 64 + j * 16 + l15;
        aU[j] = a[u * 1024 + nj[j]];
        b1v[j] = b1[nj[j]];
    }
    size_t hbase = (size_t)u * 128 * 1024;
#pragma unroll
    for (int i = 0; i < 4; ++i) {
#pragma unroll
        for (int reg = 0; reg < 4; ++reg) {
            int w = wm * 64 + i * 16 + q * 4 + reg;
            const float* brw = b + (size_t)w * 1024;
            unsigned short* hrow = h + hbase + (size_t)w * 1024;
#pragma unroll
            for (int j = 0; j < 4; ++j) {
                float v = acc[i][j][reg] + aU[j] + brw[nj[j]] + b1v[j];
                hrow[nj[j]] = f2b(fmaxf(v, 0.f));
            }
        }
    }
}

// ---------------- K6v3 (MFMA + global_load_lds): ts += (relu(h@W2+b2))@w3 ----------------
__global__ __launch_bounds__(256) void k6_gemm(
    const unsigned short* __restrict__ h, const unsigned short* __restrict__ w2T,
    const float* __restrict__ b2, const float* __restrict__ w3,
    float* __restrict__ ts) {
    __shared__ __align__(16) unsigned short Ash[128 * 32];
    __shared__ __align__(16) unsigned short Bsh[128 * 32];
    int tid = threadIdx.x;
    int m0 = blockIdx.y * 128;
    int col0 = blockIdx.x * 128;
    int lane = tid & 63, wave = tid >> 6;
    int wm = wave >> 1, wn = wave & 1;
    int q = lane >> 4, l15 = lane & 15;

    floatx4 acc[4][4];
#pragma unroll
    for (int i = 0; i < 4; ++i)
#pragma unroll
        for (int j = 0; j < 4; ++j) acc[i][j] = (floatx4){0.f, 0.f, 0.f, 0.f};

    int ci0 = wave * 2, ci1 = wave * 2 + 1;
    int p = lane & 3;
    int r0 = ci0 * 16 + (lane >> 2), r1 = ci1 * 16 + (lane >> 2);
    int c0s = p ^ ((r0 >> 1) & 3), c1s = p ^ ((r1 >> 1) & 3);
    const char* gA0 = (const char*)(h + (size_t)(m0 + r0) * 1024) + c0s * 16;
    const char* gA1 = (const char*)(h + (size_t)(m0 + r1) * 1024) + c1s * 16;
    const char* gB0 = (const char*)(w2T + (size_t)(col0 + r0) * 1024) + c0s * 16;
    const char* gB1 = (const char*)(w2T + (size_t)(col0 + r1) * 1024) + c1s * 16;
    unsigned short* lA0 = Ash + ci0 * 512;
    unsigned short* lA1 = Ash + ci1 * 512;
    unsigned short* lB0 = Bsh + ci0 * 512;
    unsigned short* lB1 = Bsh + ci1 * 512;

    for (int kt = 0; kt < 32; ++kt) {
        __syncthreads();
        GLL16(gA0, lA0);
        GLL16(gA1, lA1);
        GLL16(gB0, lB0);
        GLL16(gB1, lB1);
        gA0 += 64; gA1 += 64; gB0 += 64; gB1 += 64;
        __syncthreads();
        short8 af[4], bfv[4];
#pragma unroll
        for (int i = 0; i < 4; ++i) {
            int rA = wm * 64 + i * 16 + l15;
            af[i] = *(const short8*)(Ash + rA * 32 + (q ^ ((rA >> 1) & 3)) * 8);
        }
#pragma unroll
        for (int j = 0; j < 4; ++j) {
            int rB = wn * 64 + j * 16 + l15;
            bfv[j] = *(const short8*)(Bsh + rB * 32 + (q ^ ((rB >> 1) & 3)) * 8);
        }
#pragma unroll
        for (int i = 0; i < 4; ++i)
#pragma unroll
            for (int j = 0; j < 4; ++j)
                acc[i][j] = __builtin_amdgcn_mfma_f32_16x16x32_bf16(af[i], bfv[j], acc[i][j], 0, 0, 0);
    }

    float b2v[4], w3v[4];
    int nj[4];
#pragma unroll
    for (int j = 0; j < 4; ++j) {
        nj[j] = col0 + wn * 64 + j * 16 + l15;
        b2v[j] = b2[nj[j]];
        w3v[j] = w3[nj[j]];
    }
#pragma unroll
    for (int i = 0; i < 4; ++i) {
#pragma unroll
        for (int reg = 0; reg < 4; ++reg) {
            float s = 0.f;
#pragma unroll
            for (int j = 0; j < 4; ++j)
                s += fmaxf(acc[i][j][reg] + b2v[j], 0.f) * w3v[j];
            s += __shfl_down(s, 8, 16);
            s += __shfl_down(s, 4, 16);
            s += __shfl_down(s, 2, 16);
            s += __shfl_down(s, 1, 16);
            if (l15 == 0)
                atomicAdd(&ts[m0 + wm * 64 + i * 16 + q * 4 + reg], s);
        }
    }
}

// ---------------- K7: adaptive S_c + final loss ----------------
__global__ void k7_final(const float* __restrict__ ts, const float* __restrict__ Sg,
                         const float* __restrict__ m1, const float* __restrict__ b3,
                         float* __restrict__ out) {
    __shared__ float Sc[64];
    __shared__ float mg[8][8], mgT[8][8], mc[8][8];
    int tid = threadIdx.x;
    float b3v = b3[0];
    if (tid < 64) {
        int s = tid >> 3, v = tid & 7;
        float cs = 0.f, cv = 0.f;
        for (int k = 0; k < 16; ++k) { cs += m1[s * 16 + k]; cv += m1[v * 16 + k]; }
        float max1 = NEG_INF;
        for (int i = 0; i < 16; ++i) {
            float rm = 0.f;
            for (int j = 0; j < 16; ++j)
                rm += (ts[(size_t)(s * 16 + i) * 128 + v * 16 + j] + b3v) * m1[v * 16 + j];
            rm /= cv;
            if (m1[s * 16 + i] > 0.f) max1 = fmaxf(max1, rm);
        }
        float max2 = NEG_INF;
        for (int j = 0; j < 16; ++j) {
            float cm = 0.f;
            for (int i = 0; i < 16; ++i)
                cm += (ts[(size_t)(s * 16 + i) * 128 + v * 16 + j] + b3v) * m1[s * 16 + i];
            cm /= cs;
            if (m1[v * 16 + j] > 0.f) max2 = fmaxf(max2, cm);
        }
        Sc[tid] = 0.5f * (max1 + max2);
    }
    __syncthreads();
    if (tid < 8) {
        int r = tid;
        float mx = NEG_INF;
        for (int v = 0; v < 8; ++v) mx = fmaxf(mx, Sg[r * 8 + v]);
        float sm = 0.f;
        for (int v = 0; v < 8; ++v) sm += expf(Sg[r * 8 + v] - mx);
        for (int v = 0; v < 8; ++v) mg[r][v] = expf(Sg[r * 8 + v] - mx) / sm;

        mx = NEG_INF;
        for (int v = 0; v < 8; ++v) mx = fmaxf(mx, Sc[r * 8 + v]);
        sm = 0.f;
        for (int v = 0; v < 8; ++v) sm += expf(Sc[r * 8 + v] - mx);
        for (int v = 0; v < 8; ++v) mc[r][v] = expf(Sc[r * 8 + v] - mx) / sm;

        mx = NEG_INF;
        for (int s2 = 0; s2 < 8; ++s2) mx = fmaxf(mx, Sg[s2 * 8 + r]);
        sm = 0.f;
        for (int s2 = 0; s2 < 8; ++s2) sm += expf(Sg[s2 * 8 + r] - mx);
        for (int s2 = 0; s2 < 8; ++s2) mgT[r][s2] = expf(Sg[s2 * 8 + r] - mx) / sm;
    }
    __syncthreads();
    if (tid == 0) {
        float loss = 0.f;
        for (int r = 0; r < 8; ++r) {
            float d1 = 0.f, d2 = 0.f;
            for (int v = 0; v < 8; ++v) {
                d1 += mg[r][v] * mc[r][v];
                d2 += mgT[r][v] * mc[r][v];
            }
            loss -= logf(d1) + logf(d2);
        }
        out[0] = loss / 8.f;
    }
}

extern "C" void kernel_launch(void* const* d_in, const int* in_sizes, int n_in,
                              void* d_out, int out_size, void* d_ws, size_t ws_size,
                              hipStream_t stream) {
    const float* doc   = (const float*)d_in[0];
    const float* img   = (const float*)d_in[1];
    const float* tm    = (const float*)d_in[2];
    const float* im    = (const float*)d_in[3];
    const float* se    = (const float*)d_in[4];
    const float* cont  = (const float*)d_in[5];
    const int*   width = (const int*)d_in[6];
    const float* m1    = (const float*)d_in[7];
    const float* aw1   = (const float*)d_in[8];
    const float* ab1   = (const float*)d_in[9];
    const float* aw2   = (const float*)d_in[10];
    const float* ab2   = (const float*)d_in[11];
    const float* wemb  = (const float*)d_in[12];
    const float* pw_w1 = (const float*)d_in[13];
    const float* pw_b1 = (const float*)d_in[14];
    const float* pw_w2 = (const float*)d_in[15];
    const float* pw_b2 = (const float*)d_in[16];
    const float* pw_w3 = (const float*)d_in[17];
    const float* pw_b3 = (const float*)d_in[18];
    float* out = (float*)d_out;

    char* ws = (char*)d_ws;
    float* spans            = (float*)(ws + 0);                // 128*2324 f32
    float* scores           = (float*)(ws + 1189888);          // 1280 f32
    float* a                = (float*)(ws + 1195008);          // 128*1024 f32
    float* b                = (float*)(ws + 1719296);          // 128*1024 f32
    float* Sg               = (float*)(ws + 2243584);          // 64 f32
    float* ts               = (float*)(ws + 2243840);          // 16384 f32
    unsigned short* sb      = (unsigned short*)(ws + 2309376); // 128*2368 bf16
    unsigned short* w1cT    = (unsigned short*)(ws + 2915584); // 1024*2368 bf16
    unsigned short* w2T     = (unsigned short*)(ws + 7765248); // 1024*1024 bf16
    unsigned short* h       = (unsigned short*)(ws + 9862400); // 16384*1024 bf16 (33.5 MB)
    unsigned short* P       = (unsigned short*)(ws + 43416832); // 16384*2368 bf16 (77.6 MB)
    const size_t NEED_P = 43416832ull + 16384ull * 2368ull * 2ull; // 121 MB

    k0_init<<<512, 256, 0, stream>>>(ts, a, b);
    kT_transpose<<<dim3(37, 16), 256, 0, stream>>>(pw_w1 + (size_t)2 * 2324 * 1024, 1024, 2324, w1cT, 2368);
    kT_transpose<<<dim3(16, 16), 256, 0, stream>>>(pw_w2, 1024, 1024, w2T, 1024);
    k1_span_scores<<<128, 256, 0, stream>>>(cont, aw1, ab1, aw2, ab2, scores);
    k2_assemble<<<128, 256, 0, stream>>>(se, cont, width, scores, wemb, spans);
    kP_spansbf<<<1184, 256, 0, stream>>>(spans, sb);
    k3_grounding<<<64, 256, 0, stream>>>(doc, img, tm, im, Sg);
    k4_ab<<<dim3(16, 2, 4), 256, 0, stream>>>(spans, pw_w1, a, b);
    if (ws_size >= NEED_P) {
        kP2_products<<<dim3(128, 128), 256, 0, stream>>>(sb, P);
        k5_gemm<<<dim3(8, 128), 256, 0, stream>>>(P, w1cT, a, b, pw_b1, h);
    } else {
        k5_mfma<<<dim3(8, 128), 256, 0, stream>>>(sb, w1cT, a, b, pw_b1, h);
    }
    k6_gemm<<<dim3(8, 128), 256, 0, stream>>>(h, w2T, pw_b2, pw_w3, ts);
    k7_final<<<1, 64, 0, stream>>>(ts, Sg, m1, pw_b3, out);
}

// Round 4
// 569.810 us; speedup vs baseline: 3.5912x; 1.2279x over previous
//
#include <hip/hip_runtime.h>
#include <hip/hip_bf16.h>

#define NEGV -1e10f
#define NEG_INF -3.402823466e38f

typedef __attribute__((ext_vector_type(8))) short short8;
typedef __attribute__((ext_vector_type(4))) float floatx4;

__device__ inline float bf2f(unsigned short u) {
    union { unsigned int i; float f; } c; c.i = ((unsigned int)u) << 16; return c.f;
}
__device__ inline unsigned short f2b(float f) {
    __hip_bfloat16 h = __float2bfloat16(f);
    return *reinterpret_cast<unsigned short*>(&h);
}
// product of two packed bf16 pairs -> packed bf16 pair (RNE)
__device__ inline unsigned int mul2bf(unsigned int x, unsigned int y) {
    union { unsigned int i; float f; } xl, xh, yl, yh;
    xl.i = x << 16; xh.i = x & 0xffff0000u;
    yl.i = y << 16; yh.i = y & 0xffff0000u;
    unsigned int lo = f2b(xl.f * yl.f);
    unsigned int hi = f2b(xh.f * yh.f);
    return lo | (hi << 16);
}

#define GLL16(g, l) __builtin_amdgcn_global_load_lds( \
    (const __attribute__((address_space(1))) void*)(g), \
    (__attribute__((address_space(3))) void*)(l), 16, 0, 0)

// ---------------- K0: zero-init ts + scores ----------------
__global__ void k0_init(float* ts, float* scores) {
    int i = blockIdx.x * blockDim.x + threadIdx.x;
    if (i < 16384) ts[i] = 0.f;
    if (i < 1280) scores[i] = 0.f;
}

// ---------------- KT: transpose fp32 [K][N] -> bf16 [N][Kpad] (zero-pad K) ----------------
__global__ __launch_bounds__(256) void kT_transpose(
    const float* __restrict__ in, int ldin, int krows,
    unsigned short* __restrict__ out, int ldout) {
    __shared__ unsigned short L[64][66];
    int t = threadIdx.x;
    int kt = blockIdx.x * 64, nt = blockIdx.y * 64;
    int nl = t & 63, g = t >> 6;
#pragma unroll
    for (int i = 0; i < 16; ++i) {
        int kl = g * 16 + i;
        int k = kt + kl;
        float v = (k < krows) ? in[(size_t)k * ldin + nt + nl] : 0.f;
        L[kl][nl] = f2b(v);
    }
    __syncthreads();
    int kl2 = t & 63;
#pragma unroll
    for (int i = 0; i < 16; ++i) {
        int nl2 = g * 16 + i;
        out[(size_t)(nt + nl2) * ldout + kt + kl2] = L[kl2][nl2];
    }
}

// ---------------- KCb: cont fp32 -> bf16 flat (1280x768, no pad needed) ----------------
__global__ void kCb(const float* __restrict__ cont, unsigned short* __restrict__ cb) {
    int i = blockIdx.x * 256 + threadIdx.x;
    if (i < 1280 * 768) cb[i] = f2b(cont[i]);
}

// ---------------- KP: spans fp32 [128][2324] -> bf16 [128][2368] zero-padded ----------------
__global__ void kP_spansbf(const float* __restrict__ spans, unsigned short* __restrict__ sb) {
    int i = blockIdx.x * 256 + threadIdx.x;
    if (i >= 128 * 2368) return;
    int r = i / 2368, k = i - r * 2368;
    float v = (k < 2324) ? spans[r * 2324 + k] : 0.f;
    sb[i] = f2b(v);
}

// ---------------- KP2: P[u*128+w][k] = sb[u][k]*sb[w][k]  (bf16, memory-bound) ------------
__global__ __launch_bounds__(256) void kP2_products(
    const unsigned short* __restrict__ sb, unsigned short* __restrict__ P) {
    int w = blockIdx.x, u = blockIdx.y;
    int tid = threadIdx.x;
    const uint4* su = (const uint4*)(sb + (size_t)u * 2368);
    const uint4* sw = (const uint4*)(sb + (size_t)w * 2368);
    uint4* out = (uint4*)(P + ((size_t)u * 128 + w) * 2368);
    for (int i = tid; i < 296; i += 256) {
        uint4 a = su[i], b = sw[i];
        uint4 r;
        r.x = mul2bf(a.x, b.x); r.y = mul2bf(a.y, b.y);
        r.z = mul2bf(a.z, b.z); r.w = mul2bf(a.w, b.w);
        out[i] = r;
    }
}

// ---------------- KSCORE (MFMA): scores[m] += sum_n relu(contb@aw1T + ab1)[m,n]*aw2[n] ----
__global__ __launch_bounds__(256) void kscore_gemm(
    const unsigned short* __restrict__ A, const unsigned short* __restrict__ B,
    const float* __restrict__ ab1, const float* __restrict__ aw2,
    float* __restrict__ scores) {
    __shared__ __align__(16) unsigned short Ash[128 * 32];
    __shared__ __align__(16) unsigned short Bsh[128 * 32];
    int tid = threadIdx.x;
    int m0 = blockIdx.y * 128;
    int col0 = blockIdx.x * 128;
    int lane = tid & 63, wave = tid >> 6;
    int wm = wave >> 1, wn = wave & 1;
    int q = lane >> 4, l15 = lane & 15;

    floatx4 acc[4][4];
#pragma unroll
    for (int i = 0; i < 4; ++i)
#pragma unroll
        for (int j = 0; j < 4; ++j) acc[i][j] = (floatx4){0.f, 0.f, 0.f, 0.f};

    int ci0 = wave * 2, ci1 = wave * 2 + 1;
    int p = lane & 3;
    int r0 = ci0 * 16 + (lane >> 2), r1 = ci1 * 16 + (lane >> 2);
    int c0s = p ^ ((r0 >> 1) & 3), c1s = p ^ ((r1 >> 1) & 3);
    const char* gA0 = (const char*)(A + (size_t)(m0 + r0) * 768) + c0s * 16;
    const char* gA1 = (const char*)(A + (size_t)(m0 + r1) * 768) + c1s * 16;
    const char* gB0 = (const char*)(B + (size_t)(col0 + r0) * 768) + c0s * 16;
    const char* gB1 = (const char*)(B + (size_t)(col0 + r1) * 768) + c1s * 16;
    unsigned short* lA0 = Ash + ci0 * 512;
    unsigned short* lA1 = Ash + ci1 * 512;
    unsigned short* lB0 = Bsh + ci0 * 512;
    unsigned short* lB1 = Bsh + ci1 * 512;

    for (int kt = 0; kt < 24; ++kt) {
        __syncthreads();
        GLL16(gA0, lA0);
        GLL16(gA1, lA1);
        GLL16(gB0, lB0);
        GLL16(gB1, lB1);
        gA0 += 64; gA1 += 64; gB0 += 64; gB1 += 64;
        __syncthreads();
        short8 af[4], bfv[4];
#pragma unroll
        for (int i = 0; i < 4; ++i) {
            int rA = wm * 64 + i * 16 + l15;
            af[i] = *(const short8*)(Ash + rA * 32 + (q ^ ((rA >> 1) & 3)) * 8);
        }
#pragma unroll
        for (int j = 0; j < 4; ++j) {
            int rB = wn * 64 + j * 16 + l15;
            bfv[j] = *(const short8*)(Bsh + rB * 32 + (q ^ ((rB >> 1) & 3)) * 8);
        }
#pragma unroll
        for (int i = 0; i < 4; ++i)
#pragma unroll
            for (int j = 0; j < 4; ++j)
                acc[i][j] = __builtin_amdgcn_mfma_f32_16x16x32_bf16(af[i], bfv[j], acc[i][j], 0, 0, 0);
    }

    float b1v[4], w2v[4];
    int nj[4];
#pragma unroll
    for (int j = 0; j < 4; ++j) {
        nj[j] = col0 + wn * 64 + j * 16 + l15;
        b1v[j] = ab1[nj[j]];
        w2v[j] = aw2[nj[j]];
    }
#pragma unroll
    for (int i = 0; i < 4; ++i) {
#pragma unroll
        for (int reg = 0; reg < 4; ++reg) {
            float s = 0.f;
#pragma unroll
            for (int j = 0; j < 4; ++j)
                s += fmaxf(acc[i][j][reg] + b1v[j], 0.f) * w2v[j];
            s += __shfl_down(s, 8, 16);
            s += __shfl_down(s, 4, 16);
            s += __shfl_down(s, 2, 16);
            s += __shfl_down(s, 1, 16);
            if (l15 == 0)
                atomicAdd(&scores[m0 + wm * 64 + i * 16 + q * 4 + reg], s);
        }
    }
}

// ---------------- K4 (MFMA): a = sb@w1aT', b = sb@w1bT'  (full K, direct fp32 store) ------
__global__ __launch_bounds__(256) void k4_gemm(
    const unsigned short* __restrict__ sb, const unsigned short* __restrict__ w1aT,
    const unsigned short* __restrict__ w1bT, float* __restrict__ aout,
    float* __restrict__ bout) {
    __shared__ __align__(16) unsigned short Ash[128 * 32];
    __shared__ __align__(16) unsigned short Bsh[128 * 32];
    int tid = threadIdx.x;
    int col0 = blockIdx.x * 128;
    int half = blockIdx.y;
    const unsigned short* wT = half ? w1bT : w1aT;
    float* outp = half ? bout : aout;
    int lane = tid & 63, wave = tid >> 6;
    int wm = wave >> 1, wn = wave & 1;
    int q = lane >> 4, l15 = lane & 15;

    floatx4 acc[4][4];
#pragma unroll
    for (int i = 0; i < 4; ++i)
#pragma unroll
        for (int j = 0; j < 4; ++j) acc[i][j] = (floatx4){0.f, 0.f, 0.f, 0.f};

    int ci0 = wave * 2, ci1 = wave * 2 + 1;
    int p = lane & 3;
    int r0 = ci0 * 16 + (lane >> 2), r1 = ci1 * 16 + (lane >> 2);
    int c0s = p ^ ((r0 >> 1) & 3), c1s = p ^ ((r1 >> 1) & 3);
    const char* gA0 = (const char*)(sb + (size_t)r0 * 2368) + c0s * 16;
    const char* gA1 = (const char*)(sb + (size_t)r1 * 2368) + c1s * 16;
    const char* gB0 = (const char*)(wT + (size_t)(col0 + r0) * 2368) + c0s * 16;
    const char* gB1 = (const char*)(wT + (size_t)(col0 + r1) * 2368) + c1s * 16;
    unsigned short* lA0 = Ash + ci0 * 512;
    unsigned short* lA1 = Ash + ci1 * 512;
    unsigned short* lB0 = Bsh + ci0 * 512;
    unsigned short* lB1 = Bsh + ci1 * 512;

    for (int kt = 0; kt < 74; ++kt) {
        __syncthreads();
        GLL16(gA0, lA0);
        GLL16(gA1, lA1);
        GLL16(gB0, lB0);
        GLL16(gB1, lB1);
        gA0 += 64; gA1 += 64; gB0 += 64; gB1 += 64;
        __syncthreads();
        short8 af[4], bfv[4];
#pragma unroll
        for (int i = 0; i < 4; ++i) {
            int rA = wm * 64 + i * 16 + l15;
            af[i] = *(const short8*)(Ash + rA * 32 + (q ^ ((rA >> 1) & 3)) * 8);
        }
#pragma unroll
        for (int j = 0; j < 4; ++j) {
            int rB = wn * 64 + j * 16 + l15;
            bfv[j] = *(const short8*)(Bsh + rB * 32 + (q ^ ((rB >> 1) & 3)) * 8);
        }
#pragma unroll
        for (int i = 0; i < 4; ++i)
#pragma unroll
            for (int j = 0; j < 4; ++j)
                acc[i][j] = __builtin_amdgcn_mfma_f32_16x16x32_bf16(af[i], bfv[j], acc[i][j], 0, 0, 0);
    }

    int nj[4];
#pragma unroll
    for (int j = 0; j < 4; ++j) nj[j] = col0 + wn * 64 + j * 16 + l15;
#pragma unroll
    for (int i = 0; i < 4; ++i) {
#pragma unroll
        for (int reg = 0; reg < 4; ++reg) {
            int row = wm * 64 + i * 16 + q * 4 + reg;
#pragma unroll
            for (int j = 0; j < 4; ++j)
                outp[(size_t)row * 1024 + nj[j]] = acc[i][j][reg];
        }
    }
}

// ---------------- K2: softmax over span tokens, assemble span embeddings ----------------
__global__ __launch_bounds__(256) void k2_assemble(
    const float* __restrict__ se, const float* __restrict__ cont,
    const int* __restrict__ width, const float* __restrict__ scores,
    const float* __restrict__ ab2, const float* __restrict__ wemb,
    float* __restrict__ spans) {
    int nm = blockIdx.x, tid = threadIdx.x;
    int wd = width[nm];
    float ab2v = ab2[0];
    float sc[10];
    float m = NEG_INF;
#pragma unroll
    for (int t = 0; t < 10; ++t) {
        float s = scores[nm * 10 + t] + ab2v;
        sc[t] = (t < wd) ? s : NEGV;
        m = fmaxf(m, sc[t]);
    }
    float sum = 0.f;
#pragma unroll
    for (int t = 0; t < 10; ++t) { sc[t] = expf(sc[t] - m); sum += sc[t]; }
    float inv = 1.f / sum;
#pragma unroll
    for (int t = 0; t < 10; ++t) sc[t] *= inv;
    const float* cbase = cont + (size_t)nm * 7680;
    float* srow = spans + (size_t)nm * 2324;
    for (int d = tid; d < 768; d += 256) {
        float acc = 0.f;
#pragma unroll
        for (int t = 0; t < 10; ++t) acc = fmaf(sc[t], cbase[t * 768 + d], acc);
        srow[1536 + d] = acc;
    }
    for (int idx = tid; idx < 1536; idx += 256) srow[idx] = se[(size_t)nm * 1536 + idx];
    if (tid < 20) srow[2304 + tid] = wemb[min(wd, 4) * 20 + tid];
}

// ---------------- K3: grounding S_g, one block per (s,v) ----------------
__global__ __launch_bounds__(256) void k3_grounding(
    const float* __restrict__ doc, const float* __restrict__ img,
    const float* __restrict__ tm, const float* __restrict__ im,
    float* __restrict__ Sg) {
    __shared__ float dsh[64][65];
    __shared__ float ish[36][65];
    __shared__ float att[64][37];
    __shared__ float tmv[64], imv[36];
    __shared__ float s1sh;
    int b = blockIdx.x;
    int s = b >> 3, v = b & 7;
    int tid = threadIdx.x;
    if (tid < 64) tmv[tid] = tm[s * 64 + tid];
    if (tid >= 64 && tid < 100) imv[tid - 64] = im[v * 36 + (tid - 64)];
    float accv[9];
#pragma unroll
    for (int r = 0; r < 9; ++r) accv[r] = 0.f;
    for (int kc = 0; kc < 16; ++kc) {
        int k0 = kc * 64;
        __syncthreads();
#pragma unroll
        for (int l = 0; l < 16; ++l) {
            int idx = tid + 256 * l;
            dsh[idx >> 6][idx & 63] = doc[(size_t)(s * 64 + (idx >> 6)) * 1024 + k0 + (idx & 63)];
        }
#pragma unroll
        for (int l = 0; l < 9; ++l) {
            int idx = tid + 256 * l;
            ish[idx >> 6][idx & 63] = img[(size_t)(v * 36 + (idx >> 6)) * 1024 + k0 + (idx & 63)];
        }
        __syncthreads();
#pragma unroll
        for (int r = 0; r < 9; ++r) {
            int e = tid + 256 * r;
            int i = e / 36, j = e - i * 36;
            float a = 0.f;
            for (int k = 0; k < 64; ++k) a = fmaf(dsh[i][k], ish[j][k], a);
            accv[r] += a;
        }
    }
    __syncthreads();
#pragma unroll
    for (int r = 0; r < 9; ++r) {
        int e = tid + 256 * r;
        int i = e / 36, j = e - i * 36;
        float x = accv[r] * tmv[i] * imv[j];
        att[i][j] = (x != 0.f) ? x : NEGV;
    }
    __syncthreads();
    float part = 0.f;
    if (tid < 64) {
        int i = tid;
        float mx = NEG_INF;
        for (int j = 0; j < 36; ++j) mx = fmaxf(mx, att[i][j] * imv[j]);
        float sum = 0.f;
        for (int j = 0; j < 36; ++j) sum += expf(att[i][j] * imv[j] - mx);
        float invs = 1.f / sum;
        for (int j = 0; j < 36; ++j) {
            float aw = expf(att[i][j] * imv[j] - mx) * invs * (tmv[i] * imv[j]);
            part += aw * att[i][j];
        }
        for (int off = 32; off > 0; off >>= 1) part += __shfl_down(part, off);
        if (tid == 0) s1sh = part;
    }
    __syncthreads();
    if (tid < 64) {
        float part2 = 0.f;
        if (tid < 36) {
            int j = tid;
            float mx = NEG_INF;
            for (int i = 0; i < 64; ++i) mx = fmaxf(mx, att[i][j]);
            float sum = 0.f;
            for (int i = 0; i < 64; ++i) sum += expf(att[i][j] - mx);
            float invs = 1.f / sum;
            for (int i = 0; i < 64; ++i) {
                float aw = expf(att[i][j] - mx) * invs * (tmv[i] * imv[j]);
                part2 += aw * att[i][j];
            }
        }
        for (int off = 32; off > 0; off >>= 1) part2 += __shfl_down(part2, off);
        if (tid == 0) Sg[s * 8 + v] = s1sh + part2;
    }
}

// ---------------- K5 (MFMA + global_load_lds): h = relu(P[u] @ W1cT + a[u]+b[w]+b1) -----
__global__ __launch_bounds__(256) void k5_gemm(
    const unsigned short* __restrict__ P, const unsigned short* __restrict__ wT,
    const float* __restrict__ a, const float* __restrict__ b,
    const float* __restrict__ b1, unsigned short* __restrict__ h) {
    __shared__ __align__(16) unsigned short Ash[128 * 32];
    __shared__ __align__(16) unsigned short Bsh[128 * 32];
    int tid = threadIdx.x;
    int u = blockIdx.y;
    int col0 = blockIdx.x * 128;
    int lane = tid & 63, wave = tid >> 6;
    int wm = wave >> 1, wn = wave & 1;
    int q = lane >> 4, l15 = lane & 15;

    floatx4 acc[4][4];
#pragma unroll
    for (int i = 0; i < 4; ++i)
#pragma unroll
        for (int j = 0; j < 4; ++j) acc[i][j] = (floatx4){0.f, 0.f, 0.f, 0.f};

    int ci0 = wave * 2, ci1 = wave * 2 + 1;
    int p = lane & 3;
    int r0 = ci0 * 16 + (lane >> 2), r1 = ci1 * 16 + (lane >> 2);
    int c0s = p ^ ((r0 >> 1) & 3), c1s = p ^ ((r1 >> 1) & 3);
    const char* gA0 = (const char*)(P + (size_t)(u * 128 + r0) * 2368) + c0s * 16;
    const char* gA1 = (const char*)(P + (size_t)(u * 128 + r1) * 2368) + c1s * 16;
    const char* gB0 = (const char*)(wT + (size_t)(col0 + r0) * 2368) + c0s * 16;
    const char* gB1 = (const char*)(wT + (size_t)(col0 + r1) * 2368) + c1s * 16;
    unsigned short* lA0 = Ash + ci0 * 512;
    unsigned short* lA1 = Ash + ci1 * 512;
    unsigned short* lB0 = Bsh + ci0 * 512;
    unsigned short* lB1 = Bsh + ci1 * 512;

    for (int kt = 0; kt < 74; ++kt) {
        __syncthreads();
        GLL16(gA0, lA0);
        GLL16(gA1, lA1);
        GLL16(gB0, lB0);
        GLL16(gB1, lB1);
        gA0 += 64; gA1 += 64; gB0 += 64; gB1 += 64;
        __syncthreads();
        short8 af[4], bfv[4];
#pragma unroll
        for (int i = 0; i < 4; ++i) {
            int rA = wm * 64 + i * 16 + l15;
            af[i] = *(const short8*)(Ash + rA * 32 + (q ^ ((rA >> 1) & 3)) * 8);
        }
#pragma unroll
        for (int j = 0; j < 4; ++j) {
            int rB = wn * 64 + j * 16 + l15;
            bfv[j] = *(const short8*)(Bsh + rB * 32 + (q ^ ((rB >> 1) & 3)) * 8);
        }
#pragma unroll
        for (int i = 0; i < 4; ++i)
#pragma unroll
            for (int j = 0; j < 4; ++j)
                acc[i][j] = __builtin_amdgcn_mfma_f32_16x16x32_bf16(af[i], bfv[j], acc[i][j], 0, 0, 0);
    }

    float aU[4], b1v[4];
    int nj[4];
#pragma unroll
    for (int j = 0; j < 4; ++j) {
        nj[j] = col0 + wn * 64 + j * 16 + l15;
        aU[j] = a[u * 1024 + nj[j]];
        b1v[j] = b1[nj[j]];
    }
    size_t hbase = (size_t)u * 128 * 1024;
#pragma unroll
    for (int i = 0; i < 4; ++i) {
#pragma unroll
        for (int reg = 0; reg < 4; ++reg) {
            int w = wm * 64 + i * 16 + q * 4 + reg;
            const float* brw = b + (size_t)w * 1024;
            unsigned short* hrow = h + hbase + (size_t)w * 1024;
#pragma unroll
            for (int j = 0; j < 4; ++j) {
                float v = acc[i][j][reg] + aU[j] + brw[nj[j]] + b1v[j];
                hrow[nj[j]] = f2b(fmaxf(v, 0.f));
            }
        }
    }
}

// ---------------- K5 fallback (on-the-fly product; used if ws too small) --------
__global__ __launch_bounds__(256) void k5_mfma(
    const unsigned short* __restrict__ sb, const unsigned short* __restrict__ wT,
    const float* __restrict__ a, const float* __restrict__ b,
    const float* __restrict__ b1, unsigned short* __restrict__ h) {
    __shared__ __align__(16) unsigned short Ash[128 * 32];
    __shared__ __align__(16) unsigned short Bsh[128 * 32];
    int tid = threadIdx.x;
    int u = blockIdx.y;
    int col0 = blockIdx.x * 128;
    int lane = tid & 63, wave = tid >> 6;
    int wm = wave >> 1, wn = wave & 1;
    int q = lane >> 4, l15 = lane & 15;

    floatx4 acc[4][4];
#pragma unroll
    for (int i = 0; i < 4; ++i)
#pragma unroll
        for (int j = 0; j < 4; ++j) acc[i][j] = (floatx4){0.f, 0.f, 0.f, 0.f};

    int r = tid >> 1;
    int cb = (tid & 1) * 2;
    int sw = (r >> 1) & 3;
    const unsigned short* arow = sb + (size_t)r * 2368 + cb * 8;
    const unsigned short* urow = sb + (size_t)u * 2368 + cb * 8;
    const unsigned short* brow = wT + (size_t)(col0 + r) * 2368 + cb * 8;
    unsigned short* awp0 = Ash + r * 32 + (cb ^ sw) * 8;
    unsigned short* awp1 = Ash + r * 32 + ((cb + 1) ^ sw) * 8;
    unsigned short* bwp0 = Bsh + r * 32 + (cb ^ sw) * 8;
    unsigned short* bwp1 = Bsh + r * 32 + ((cb + 1) ^ sw) * 8;

    for (int kt = 0; kt < 74; ++kt) {
        int k0 = kt * 32;
        uint4 av0 = *(const uint4*)(arow + k0);
        uint4 av1 = *(const uint4*)(arow + k0 + 8);
        uint4 uv0 = *(const uint4*)(urow + k0);
        uint4 uv1 = *(const uint4*)(urow + k0 + 8);
        uint4 bv0 = *(const uint4*)(brow + k0);
        uint4 bv1 = *(const uint4*)(brow + k0 + 8);
        __syncthreads();
        uint4 p0, p1;
        p0.x = mul2bf(av0.x, uv0.x); p0.y = mul2bf(av0.y, uv0.y);
        p0.z = mul2bf(av0.z, uv0.z); p0.w = mul2bf(av0.w, uv0.w);
        p1.x = mul2bf(av1.x, uv1.x); p1.y = mul2bf(av1.y, uv1.y);
        p1.z = mul2bf(av1.z, uv1.z); p1.w = mul2bf(av1.w, uv1.w);
        *(uint4*)awp0 = p0;
        *(uint4*)awp1 = p1;
        *(uint4*)bwp0 = bv0;
        *(uint4*)bwp1 = bv1;
        __syncthreads();
        short8 af[4], bfv[4];
#pragma unroll
        for (int i = 0; i < 4; ++i) {
            int rA = wm * 64 + i * 16 + l15;
            af[i] = *(const short8*)(Ash + rA * 32 + (q ^ ((rA >> 1) & 3)) * 8);
        }
#pragma unroll
        for (int j = 0; j < 4; ++j) {
            int rB = wn * 64 + j * 16 + l15;
            bfv[j] = *(const short8*)(Bsh + rB * 32 + (q ^ ((rB >> 1) & 3)) * 8);
        }
#pragma unroll
        for (int i = 0; i < 4; ++i)
#pragma unroll
            for (int j = 0; j < 4; ++j)
                acc[i][j] = __builtin_amdgcn_mfma_f32_16x16x32_bf16(af[i], bfv[j], acc[i][j], 0, 0, 0);
    }

    float aU[4], b1v[4];
    int nj[4];
#pragma unroll
    for (int j = 0; j < 4; ++j) {
        nj[j] = col0 + wn * 64 + j * 16 + l15;
        aU[j] = a[u * 1024 + nj[j]];
        b1v[j] = b1[nj[j]];
    }
    size_t hbase = (size_t)u * 128 * 1024;
#pragma unroll
    for (int i = 0; i < 4; ++i) {
#pragma unroll
        for (int reg = 0; reg < 4; ++reg) {
            int w = wm * 64 + i * 16 + q * 4 + reg;
            const float* brw = b + (size_t)w * 1024;
            unsigned short* hrow = h + hbase + (size_t)w * 1024;
#pragma unroll
            for (int j = 0; j < 4; ++j) {
                float v = acc[i][j][reg] + aU[j] + brw[nj[j]] + b1v[j];
                hrow[nj[j]] = f2b(fmaxf(v, 0.f));
            }
        }
    }
}

// ---------------- K6 (MFMA + global_load_lds): ts += (relu(h@W2+b2))@w3 ----------------
__global__ __launch_bounds__(256) void k6_gemm(
    const unsigned short* __restrict__ h, const unsigned short* __restrict__ w2T,
    const float* __restrict__ b2, const float* __restrict__ w3,
    float* __restrict__ ts) {
    __shared__ __align__(16) unsigned short Ash[128 * 32];
    __shared__ __align__(16) unsigned short Bsh[128 * 32];
    int tid = threadIdx.x;
    int m0 = blockIdx.y * 128;
    int col0 = blockIdx.x * 128;
    int lane = tid & 63, wave = tid >> 6;
    int wm = wave >> 1, wn = wave & 1;
    int q = lane >> 4, l15 = lane & 15;

    floatx4 acc[4][4];
#pragma unroll
    for (int i = 0; i < 4; ++i)
#pragma unroll
        for (int j = 0; j < 4; ++j) acc[i][j] = (floatx4){0.f, 0.f, 0.f, 0.f};

    int ci0 = wave * 2, ci1 = wave * 2 + 1;
    int p = lane & 3;
    int r0 = ci0 * 16 + (lane >> 2), r1 = ci1 * 16 + (lane >> 2);
    int c0s = p ^ ((r0 >> 1) & 3), c1s = p ^ ((r1 >> 1) & 3);
    const char* gA0 = (const char*)(h + (size_t)(m0 + r0) * 1024) + c0s * 16;
    const char* gA1 = (const char*)(h + (size_t)(m0 + r1) * 1024) + c1s * 16;
    const char* gB0 = (const char*)(w2T + (size_t)(col0 + r0) * 1024) + c0s * 16;
    const char* gB1 = (const char*)(w2T + (size_t)(col0 + r1) * 1024) + c1s * 16;
    unsigned short* lA0 = Ash + ci0 * 512;
    unsigned short* lA1 = Ash + ci1 * 512;
    unsigned short* lB0 = Bsh + ci0 * 512;
    unsigned short* lB1 = Bsh + ci1 * 512;

    for (int kt = 0; kt < 32; ++kt) {
        __syncthreads();
        GLL16(gA0, lA0);
        GLL16(gA1, lA1);
        GLL16(gB0, lB0);
        GLL16(gB1, lB1);
        gA0 += 64; gA1 += 64; gB0 += 64; gB1 += 64;
        __syncthreads();
        short8 af[4], bfv[4];
#pragma unroll
        for (int i = 0; i < 4; ++i) {
            int rA = wm * 64 + i * 16 + l15;
            af[i] = *(const short8*)(Ash + rA * 32 + (q ^ ((rA >> 1) & 3)) * 8);
        }
#pragma unroll
        for (int j = 0; j < 4; ++j) {
            int rB = wn * 64 + j * 16 + l15;
            bfv[j] = *(const short8*)(Bsh + rB * 32 + (q ^ ((rB >> 1) & 3)) * 8);
        }
#pragma unroll
        for (int i = 0; i < 4; ++i)
#pragma unroll
            for (int j = 0; j < 4; ++j)
                acc[i][j] = __builtin_amdgcn_mfma_f32_16x16x32_bf16(af[i], bfv[j], acc[i][j], 0, 0, 0);
    }

    float b2v[4], w3v[4];
    int nj[4];
#pragma unroll
    for (int j = 0; j < 4; ++j) {
        nj[j] = col0 + wn * 64 + j * 16 + l15;
        b2v[j] = b2[nj[j]];
        w3v[j] = w3[nj[j]];
    }
#pragma unroll
    for (int i = 0; i < 4; ++i) {
#pragma unroll
        for (int reg = 0; reg < 4; ++reg) {
            float s = 0.f;
#pragma unroll
            for (int j = 0; j < 4; ++j)
                s += fmaxf(acc[i][j][reg] + b2v[j], 0.f) * w3v[j];
            s += __shfl_down(s, 8, 16);
            s += __shfl_down(s, 4, 16);
            s += __shfl_down(s, 2, 16);
            s += __shfl_down(s, 1, 16);
            if (l15 == 0)
                atomicAdd(&ts[m0 + wm * 64 + i * 16 + q * 4 + reg], s);
        }
    }
}

// ---------------- K7: adaptive S_c + final loss ----------------
__global__ void k7_final(const float* __restrict__ ts, const float* __restrict__ Sg,
                         const float* __restrict__ m1, const float* __restrict__ b3,
                         float* __restrict__ out) {
    __shared__ float Sc[64];
    __shared__ float mg[8][8], mgT[8][8], mc[8][8];
    int tid = threadIdx.x;
    float b3v = b3[0];
    if (tid < 64) {
        int s = tid >> 3, v = tid & 7;
        float cs = 0.f, cv = 0.f;
        for (int k = 0; k < 16; ++k) { cs += m1[s * 16 + k]; cv += m1[v * 16 + k]; }
        float max1 = NEG_INF;
        for (int i = 0; i < 16; ++i) {
            float rm = 0.f;
            for (int j = 0; j < 16; ++j)
                rm += (ts[(size_t)(s * 16 + i) * 128 + v * 16 + j] + b3v) * m1[v * 16 + j];
            rm /= cv;
            if (m1[s * 16 + i] > 0.f) max1 = fmaxf(max1, rm);
        }
        float max2 = NEG_INF;
        for (int j = 0; j < 16; ++j) {
            float cm = 0.f;
            for (int i = 0; i < 16; ++i)
                cm += (ts[(size_t)(s * 16 + i) * 128 + v * 16 + j] + b3v) * m1[s * 16 + i];
            cm /= cs;
            if (m1[v * 16 + j] > 0.f) max2 = fmaxf(max2, cm);
        }
        Sc[tid] = 0.5f * (max1 + max2);
    }
    __syncthreads();
    if (tid < 8) {
        int r = tid;
        float mx = NEG_INF;
        for (int v = 0; v < 8; ++v) mx = fmaxf(mx, Sg[r * 8 + v]);
        float sm = 0.f;
        for (int v = 0; v < 8; ++v) sm += expf(Sg[r * 8 + v] - mx);
        for (int v = 0; v < 8; ++v) mg[r][v] = expf(Sg[r * 8 + v] - mx) / sm;

        mx = NEG_INF;
        for (int v = 0; v < 8; ++v) mx = fmaxf(mx, Sc[r * 8 + v]);
        sm = 0.f;
        for (int v = 0; v < 8; ++v) sm += expf(Sc[r * 8 + v] - mx);
        for (int v = 0; v < 8; ++v) mc[r][v] = expf(Sc[r * 8 + v] - mx) / sm;

        mx = NEG_INF;
        for (int s2 = 0; s2 < 8; ++s2) mx = fmaxf(mx, Sg[s2 * 8 + r]);
        sm = 0.f;
        for (int s2 = 0; s2 < 8; ++s2) sm += expf(Sg[s2 * 8 + r] - mx);
        for (int s2 = 0; s2 < 8; ++s2) mgT[r][s2] = expf(Sg[s2 * 8 + r] - mx) / sm;
    }
    __syncthreads();
    if (tid == 0) {
        float loss = 0.f;
        for (int r = 0; r < 8; ++r) {
            float d1 = 0.f, d2 = 0.f;
            for (int v = 0; v < 8; ++v) {
                d1 += mg[r][v] * mc[r][v];
                d2 += mgT[r][v] * mc[r][v];
            }
            loss -= logf(d1) + logf(d2);
        }
        out[0] = loss / 8.f;
    }
}

extern "C" void kernel_launch(void* const* d_in, const int* in_sizes, int n_in,
                              void* d_out, int out_size, void* d_ws, size_t ws_size,
                              hipStream_t stream) {
    const float* doc   = (const float*)d_in[0];
    const float* img   = (const float*)d_in[1];
    const float* tm    = (const float*)d_in[2];
    const float* im    = (const float*)d_in[3];
    const float* se    = (const float*)d_in[4];
    const float* cont  = (const float*)d_in[5];
    const int*   width = (const int*)d_in[6];
    const float* m1    = (const float*)d_in[7];
    const float* aw1   = (const float*)d_in[8];
    const float* ab1   = (const float*)d_in[9];
    const float* aw2   = (const float*)d_in[10];
    const float* ab2   = (const float*)d_in[11];
    const float* wemb  = (const float*)d_in[12];
    const float* pw_w1 = (const float*)d_in[13];
    const float* pw_b1 = (const float*)d_in[14];
    const float* pw_w2 = (const float*)d_in[15];
    const float* pw_b2 = (const float*)d_in[16];
    const float* pw_w3 = (const float*)d_in[17];
    const float* pw_b3 = (const float*)d_in[18];
    float* out = (float*)d_out;

    char* ws = (char*)d_ws;
    float* spans            = (float*)(ws + 0);                // 128*2324 f32
    float* scores           = (float*)(ws + 1189888);          // 1280 f32
    float* a                = (float*)(ws + 1195008);          // 128*1024 f32
    float* b                = (float*)(ws + 1719296);          // 128*1024 f32
    float* Sg               = (float*)(ws + 2243584);          // 64 f32
    float* ts               = (float*)(ws + 2243840);          // 16384 f32
    unsigned short* sb      = (unsigned short*)(ws + 2309376); // 128*2368 bf16
    unsigned short* w1cT    = (unsigned short*)(ws + 2915584); // 1024*2368 bf16
    unsigned short* w2T     = (unsigned short*)(ws + 7765248); // 1024*1024 bf16
    unsigned short* h       = (unsigned short*)(ws + 9862400); // 16384*1024 bf16 (33.5 MB)
    unsigned short* P       = (unsigned short*)(ws + 43416832); // 16384*2368 bf16 (77.6 MB)
    const size_t NEED_P = 43416832ull + 16384ull * 2368ull * 2ull; // 121 MB
    // Overlays inside the h region (all dead before k5 writes h):
    unsigned short* contb   = (unsigned short*)(ws + 9862400);  // 1280*768 bf16
    unsigned short* aw1T    = (unsigned short*)(ws + 11828480); // 1024*768 bf16
    unsigned short* w1aT    = (unsigned short*)(ws + 13401344); // 1024*2368 bf16
    unsigned short* w1bT    = (unsigned short*)(ws + 18251008); // 1024*2368 bf16 (ends 23.1MB < 43.4MB)

    k0_init<<<64, 256, 0, stream>>>(ts, scores);
    kT_transpose<<<dim3(37, 16), 256, 0, stream>>>(pw_w1 + (size_t)2 * 2324 * 1024, 1024, 2324, w1cT, 2368);
    kT_transpose<<<dim3(16, 16), 256, 0, stream>>>(pw_w2, 1024, 1024, w2T, 1024);
    kT_transpose<<<dim3(37, 16), 256, 0, stream>>>(pw_w1, 1024, 2324, w1aT, 2368);
    kT_transpose<<<dim3(37, 16), 256, 0, stream>>>(pw_w1 + (size_t)2324 * 1024, 1024, 2324, w1bT, 2368);
    kT_transpose<<<dim3(12, 16), 256, 0, stream>>>(aw1, 1024, 768, aw1T, 768);
    kCb<<<3840, 256, 0, stream>>>(cont, contb);
    kscore_gemm<<<dim3(8, 10), 256, 0, stream>>>(contb, aw1T, ab1, aw2, scores);
    k2_assemble<<<128, 256, 0, stream>>>(se, cont, width, scores, ab2, wemb, spans);
    kP_spansbf<<<1184, 256, 0, stream>>>(spans, sb);
    k3_grounding<<<64, 256, 0, stream>>>(doc, img, tm, im, Sg);
    k4_gemm<<<dim3(8, 2), 256, 0, stream>>>(sb, w1aT, w1bT, a, b);
    if (ws_size >= NEED_P) {
        kP2_products<<<dim3(128, 128), 256, 0, stream>>>(sb, P);
        k5_gemm<<<dim3(8, 128), 256, 0, stream>>>(P, w1cT, a, b, pw_b1, h);
    } else {
        k5_mfma<<<dim3(8, 128), 256, 0, stream>>>(sb, w1cT, a, b, pw_b1, h);
    }
    k6_gemm<<<dim3(8, 128), 256, 0, stream>>>(h, w2T, pw_b2, pw_w3, ts);
    k7_final<<<1, 64, 0, stream>>>(ts, Sg, m1, pw_b3, out);
}

// Round 5
// 462.306 us; speedup vs baseline: 4.4263x; 1.2325x over previous
//
#include <hip/hip_runtime.h>
#include <hip/hip_bf16.h>

#define NEGV -1e10f
#define NEG_INF -3.402823466e38f

typedef __attribute__((ext_vector_type(8))) short short8;
typedef __attribute__((ext_vector_type(4))) float floatx4;

__device__ inline float bf2f(unsigned short u) {
    union { unsigned int i; float f; } c; c.i = ((unsigned int)u) << 16; return c.f;
}
__device__ inline unsigned short f2b(float f) {
    __hip_bfloat16 h = __float2bfloat16(f);
    return *reinterpret_cast<unsigned short*>(&h);
}
// product of two packed bf16 pairs -> packed bf16 pair (RNE)
__device__ inline unsigned int mul2bf(unsigned int x, unsigned int y) {
    union { unsigned int i; float f; } xl, xh, yl, yh;
    xl.i = x << 16; xh.i = x & 0xffff0000u;
    yl.i = y << 16; yh.i = y & 0xffff0000u;
    unsigned int lo = f2b(xl.f * yl.f);
    unsigned int hi = f2b(xh.f * yh.f);
    return lo | (hi << 16);
}

#define GLL16(g, l) __builtin_amdgcn_global_load_lds( \
    (const __attribute__((address_space(1))) void*)(g), \
    (__attribute__((address_space(3))) void*)(l), 16, 0, 0)

// ---------------- KPREP: fused transposes + cont->bf16 + zero-inits ----------------
// regions: [0,592) w1cT | [592,1184) w1aT | [1184,1776) w1bT | [1776,2032) w2T
//          [2032,2224) aw1T | [2224,6064) contb | [6064,8368) zero att/ts/scores
__device__ void transpose_tile(const float* __restrict__ in, int ldin, int krows,
                               unsigned short* __restrict__ out, int ldout,
                               int ktile, int ntile, unsigned short (*L)[66]) {
    int t = threadIdx.x;
    int kt = ktile * 64, nt = ntile * 64;
    int nl = t & 63, g = t >> 6;
#pragma unroll
    for (int i = 0; i < 16; ++i) {
        int kl = g * 16 + i;
        int k = kt + kl;
        float v = (k < krows) ? in[(size_t)k * ldin + nt + nl] : 0.f;
        L[kl][nl] = f2b(v);
    }
    __syncthreads();
    int kl2 = t & 63;
#pragma unroll
    for (int i = 0; i < 16; ++i) {
        int nl2 = g * 16 + i;
        out[(size_t)(nt + nl2) * ldout + kt + kl2] = L[kl2][nl2];
    }
}

__global__ __launch_bounds__(256) void kprep(
    const float* __restrict__ pw_w1, const float* __restrict__ pw_w2,
    const float* __restrict__ aw1, const float* __restrict__ cont,
    unsigned short* __restrict__ w1cT, unsigned short* __restrict__ w1aT,
    unsigned short* __restrict__ w1bT, unsigned short* __restrict__ w2T,
    unsigned short* __restrict__ aw1T, unsigned short* __restrict__ contb,
    float* __restrict__ ts, float* __restrict__ scores, float* __restrict__ attall) {
    __shared__ unsigned short L[64][66];
    int bid = blockIdx.x;
    int tid = threadIdx.x;
    if (bid < 592) {
        transpose_tile(pw_w1 + (size_t)2 * 2324 * 1024, 1024, 2324, w1cT, 2368,
                       bid % 37, bid / 37, L);
    } else if (bid < 1184) {
        int r = bid - 592;
        transpose_tile(pw_w1, 1024, 2324, w1aT, 2368, r % 37, r / 37, L);
    } else if (bid < 1776) {
        int r = bid - 1184;
        transpose_tile(pw_w1 + (size_t)2324 * 1024, 1024, 2324, w1bT, 2368, r % 37, r / 37, L);
    } else if (bid < 2032) {
        int r = bid - 1776;
        transpose_tile(pw_w2, 1024, 1024, w2T, 1024, r % 16, r / 16, L);
    } else if (bid < 2224) {
        int r = bid - 2032;
        transpose_tile(aw1, 1024, 768, aw1T, 768, r % 12, r / 12, L);
    } else if (bid < 6064) {
        int i = (bid - 2224) * 256 + tid;   // < 983040 exactly
        contb[i] = f2b(cont[i]);
    } else {
        int i = (bid - 6064) * 256 + tid;   // < 589824 exactly
        attall[i] = 0.f;
        if (i < 16384) ts[i] = 0.f;
        if (i < 1280) scores[i] = 0.f;
    }
}

// ---------------- KSCORE (MFMA): scores[m] += sum_n relu(contb@aw1T + ab1)[m,n]*aw2[n] ----
__global__ __launch_bounds__(256) void kscore_gemm(
    const unsigned short* __restrict__ A, const unsigned short* __restrict__ B,
    const float* __restrict__ ab1, const float* __restrict__ aw2,
    float* __restrict__ scores) {
    __shared__ __align__(16) unsigned short Ash[128 * 32];
    __shared__ __align__(16) unsigned short Bsh[128 * 32];
    int tid = threadIdx.x;
    int m0 = blockIdx.y * 128;
    int col0 = blockIdx.x * 128;
    int lane = tid & 63, wave = tid >> 6;
    int wm = wave >> 1, wn = wave & 1;
    int q = lane >> 4, l15 = lane & 15;

    floatx4 acc[4][4];
#pragma unroll
    for (int i = 0; i < 4; ++i)
#pragma unroll
        for (int j = 0; j < 4; ++j) acc[i][j] = (floatx4){0.f, 0.f, 0.f, 0.f};

    int ci0 = wave * 2, ci1 = wave * 2 + 1;
    int p = lane & 3;
    int r0 = ci0 * 16 + (lane >> 2), r1 = ci1 * 16 + (lane >> 2);
    int c0s = p ^ ((r0 >> 1) & 3), c1s = p ^ ((r1 >> 1) & 3);
    const char* gA0 = (const char*)(A + (size_t)(m0 + r0) * 768) + c0s * 16;
    const char* gA1 = (const char*)(A + (size_t)(m0 + r1) * 768) + c1s * 16;
    const char* gB0 = (const char*)(B + (size_t)(col0 + r0) * 768) + c0s * 16;
    const char* gB1 = (const char*)(B + (size_t)(col0 + r1) * 768) + c1s * 16;
    unsigned short* lA0 = Ash + ci0 * 512;
    unsigned short* lA1 = Ash + ci1 * 512;
    unsigned short* lB0 = Bsh + ci0 * 512;
    unsigned short* lB1 = Bsh + ci1 * 512;

    for (int kt = 0; kt < 24; ++kt) {
        __syncthreads();
        GLL16(gA0, lA0);
        GLL16(gA1, lA1);
        GLL16(gB0, lB0);
        GLL16(gB1, lB1);
        gA0 += 64; gA1 += 64; gB0 += 64; gB1 += 64;
        __syncthreads();
        short8 af[4], bfv[4];
#pragma unroll
        for (int i = 0; i < 4; ++i) {
            int rA = wm * 64 + i * 16 + l15;
            af[i] = *(const short8*)(Ash + rA * 32 + (q ^ ((rA >> 1) & 3)) * 8);
        }
#pragma unroll
        for (int j = 0; j < 4; ++j) {
            int rB = wn * 64 + j * 16 + l15;
            bfv[j] = *(const short8*)(Bsh + rB * 32 + (q ^ ((rB >> 1) & 3)) * 8);
        }
#pragma unroll
        for (int i = 0; i < 4; ++i)
#pragma unroll
            for (int j = 0; j < 4; ++j)
                acc[i][j] = __builtin_amdgcn_mfma_f32_16x16x32_bf16(af[i], bfv[j], acc[i][j], 0, 0, 0);
    }

    float b1v[4], w2v[4];
    int nj[4];
#pragma unroll
    for (int j = 0; j < 4; ++j) {
        nj[j] = col0 + wn * 64 + j * 16 + l15;
        b1v[j] = ab1[nj[j]];
        w2v[j] = aw2[nj[j]];
    }
#pragma unroll
    for (int i = 0; i < 4; ++i) {
#pragma unroll
        for (int reg = 0; reg < 4; ++reg) {
            float s = 0.f;
#pragma unroll
            for (int j = 0; j < 4; ++j)
                s += fmaxf(acc[i][j][reg] + b1v[j], 0.f) * w2v[j];
            s += __shfl_down(s, 8, 16);
            s += __shfl_down(s, 4, 16);
            s += __shfl_down(s, 2, 16);
            s += __shfl_down(s, 1, 16);
            if (l15 == 0)
                atomicAdd(&scores[m0 + wm * 64 + i * 16 + q * 4 + reg], s);
        }
    }
}

// ---------------- K2: softmax over span tokens, assemble bf16 span embeddings -------------
__global__ __launch_bounds__(256) void k2_assemble(
    const float* __restrict__ se, const float* __restrict__ cont,
    const int* __restrict__ width, const float* __restrict__ scores,
    const float* __restrict__ ab2, const float* __restrict__ wemb,
    unsigned short* __restrict__ sb) {
    int nm = blockIdx.x, tid = threadIdx.x;
    int wd = width[nm];
    float ab2v = ab2[0];
    float sc[10];
    float m = NEG_INF;
#pragma unroll
    for (int t = 0; t < 10; ++t) {
        float s = scores[nm * 10 + t] + ab2v;
        sc[t] = (t < wd) ? s : NEGV;
        m = fmaxf(m, sc[t]);
    }
    float sum = 0.f;
#pragma unroll
    for (int t = 0; t < 10; ++t) { sc[t] = expf(sc[t] - m); sum += sc[t]; }
    float inv = 1.f / sum;
#pragma unroll
    for (int t = 0; t < 10; ++t) sc[t] *= inv;
    const float* cbase = cont + (size_t)nm * 7680;
    unsigned short* srow = sb + (size_t)nm * 2368;
    for (int d = tid; d < 768; d += 256) {
        float acc = 0.f;
#pragma unroll
        for (int t = 0; t < 10; ++t) acc = fmaf(sc[t], cbase[t * 768 + d], acc);
        srow[1536 + d] = f2b(acc);
    }
    for (int idx = tid; idx < 1536; idx += 256) srow[idx] = f2b(se[(size_t)nm * 1536 + idx]);
    if (tid < 20) srow[2304 + tid] = f2b(wemb[min(wd, 4) * 20 + tid]);
    if (tid >= 20 && tid < 64) srow[2304 + tid] = 0;   // zero pad 2324..2367
}

// ---------------- K3a: att_all[512][288] = doc(512,1024) @ img(288,1024)^T, fp32, K-split --
__global__ __launch_bounds__(256) void k3a_att(
    const float* __restrict__ doc, const float* __restrict__ img,
    float* __restrict__ attall) {
    __shared__ float As[32][132];   // [k][m], pad 132
    __shared__ float Bs[32][100];   // [k][n], pad 100
    int tid = threadIdx.x;
    int n0 = blockIdx.x * 96;
    int m0 = blockIdx.y * 128;
    int k0base = blockIdx.z * 128;
    int tx = tid & 15, ty = tid >> 4;   // tx: 6-col group, ty: 8-row group
    float acc[8][6];
#pragma unroll
    for (int r = 0; r < 8; ++r)
#pragma unroll
        for (int c = 0; c < 6; ++c) acc[r][c] = 0.f;

    for (int kc = 0; kc < 4; ++kc) {
        int k0 = k0base + kc * 32;
        __syncthreads();
#pragma unroll
        for (int p2 = 0; p2 < 4; ++p2) {
            int f = tid + 256 * p2;               // 0..1023
            int mm = f >> 3, kq = (f & 7) * 4;
            float4 v = *(const float4*)&doc[(size_t)(m0 + mm) * 1024 + k0 + kq];
            As[kq + 0][mm] = v.x; As[kq + 1][mm] = v.y;
            As[kq + 2][mm] = v.z; As[kq + 3][mm] = v.w;
        }
#pragma unroll
        for (int p2 = 0; p2 < 3; ++p2) {
            int f = tid + 256 * p2;               // 0..767
            int nn = f >> 3, kq = (f & 7) * 4;
            float4 v = *(const float4*)&img[(size_t)(n0 + nn) * 1024 + k0 + kq];
            Bs[kq + 0][nn] = v.x; Bs[kq + 1][nn] = v.y;
            Bs[kq + 2][nn] = v.z; Bs[kq + 3][nn] = v.w;
        }
        __syncthreads();
#pragma unroll 4
        for (int k = 0; k < 32; ++k) {
            float4 a0 = *(const float4*)&As[k][ty * 8];
            float4 a1 = *(const float4*)&As[k][ty * 8 + 4];
            float2 b0 = *(const float2*)&Bs[k][tx * 6];
            float2 b1 = *(const float2*)&Bs[k][tx * 6 + 2];
            float2 b2 = *(const float2*)&Bs[k][tx * 6 + 4];
            float ar[8] = {a0.x, a0.y, a0.z, a0.w, a1.x, a1.y, a1.z, a1.w};
            float br[6] = {b0.x, b0.y, b1.x, b1.y, b2.x, b2.y};
#pragma unroll
            for (int r = 0; r < 8; ++r)
#pragma unroll
                for (int c = 0; c < 6; ++c) acc[r][c] = fmaf(ar[r], br[c], acc[r][c]);
        }
    }
#pragma unroll
    for (int r = 0; r < 8; ++r)
#pragma unroll
        for (int c = 0; c < 6; ++c)
            atomicAdd(&attall[(size_t)(m0 + ty * 8 + r) * 288 + n0 + tx * 6 + c], acc[r][c]);
}

// ---------------- K3b: per (s,v) mask + two softmax-reductions -> Sg ----------------
__global__ __launch_bounds__(256) void k3b_reduce(
    const float* __restrict__ attall, const float* __restrict__ tm,
    const float* __restrict__ im, float* __restrict__ Sg) {
    __shared__ float att[64][37];
    __shared__ float tmv[64], imv[36];
    __shared__ float s1sh;
    int b = blockIdx.x;
    int s = b >> 3, v = b & 7;
    int tid = threadIdx.x;
    if (tid < 64) tmv[tid] = tm[s * 64 + tid];
    if (tid >= 64 && tid < 100) imv[tid - 64] = im[v * 36 + (tid - 64)];
    __syncthreads();
    for (int idx = tid; idx < 2304; idx += 256) {
        int i = idx / 36, j = idx - i * 36;
        float raw = attall[(size_t)(s * 64 + i) * 288 + v * 36 + j];
        float x = raw * tmv[i] * imv[j];
        att[i][j] = (x != 0.f) ? x : NEGV;
    }
    __syncthreads();
    float part = 0.f;
    if (tid < 64) {
        int i = tid;
        float mx = NEG_INF;
        for (int j = 0; j < 36; ++j) mx = fmaxf(mx, att[i][j] * imv[j]);
        float sum = 0.f;
        for (int j = 0; j < 36; ++j) sum += expf(att[i][j] * imv[j] - mx);
        float invs = 1.f / sum;
        for (int j = 0; j < 36; ++j) {
            float aw = expf(att[i][j] * imv[j] - mx) * invs * (tmv[i] * imv[j]);
            part += aw * att[i][j];
        }
        for (int off = 32; off > 0; off >>= 1) part += __shfl_down(part, off);
        if (tid == 0) s1sh = part;
    }
    __syncthreads();
    if (tid < 64) {
        float part2 = 0.f;
        if (tid < 36) {
            int j = tid;
            float mx = NEG_INF;
            for (int i = 0; i < 64; ++i) mx = fmaxf(mx, att[i][j]);
            float sum = 0.f;
            for (int i = 0; i < 64; ++i) sum += expf(att[i][j] - mx);
            float invs = 1.f / sum;
            for (int i = 0; i < 64; ++i) {
                float aw = expf(att[i][j] - mx) * invs * (tmv[i] * imv[j]);
                part2 += aw * att[i][j];
            }
        }
        for (int off = 32; off > 0; off >>= 1) part2 += __shfl_down(part2, off);
        if (tid == 0) Sg[s * 8 + v] = s1sh + part2;
    }
}

// ---------------- K4 (MFMA): a = sb@w1aT', b = sb@w1bT'  (full K, direct fp32 store) ------
__global__ __launch_bounds__(256) void k4_gemm(
    const unsigned short* __restrict__ sb, const unsigned short* __restrict__ w1aT,
    const unsigned short* __restrict__ w1bT, float* __restrict__ aout,
    float* __restrict__ bout) {
    __shared__ __align__(16) unsigned short Ash[128 * 32];
    __shared__ __align__(16) unsigned short Bsh[128 * 32];
    int tid = threadIdx.x;
    int col0 = blockIdx.x * 128;
    int half = blockIdx.y;
    const unsigned short* wT = half ? w1bT : w1aT;
    float* outp = half ? bout : aout;
    int lane = tid & 63, wave = tid >> 6;
    int wm = wave >> 1, wn = wave & 1;
    int q = lane >> 4, l15 = lane & 15;

    floatx4 acc[4][4];
#pragma unroll
    for (int i = 0; i < 4; ++i)
#pragma unroll
        for (int j = 0; j < 4; ++j) acc[i][j] = (floatx4){0.f, 0.f, 0.f, 0.f};

    int ci0 = wave * 2, ci1 = wave * 2 + 1;
    int p = lane & 3;
    int r0 = ci0 * 16 + (lane >> 2), r1 = ci1 * 16 + (lane >> 2);
    int c0s = p ^ ((r0 >> 1) & 3), c1s = p ^ ((r1 >> 1) & 3);
    const char* gA0 = (const char*)(sb + (size_t)r0 * 2368) + c0s * 16;
    const char* gA1 = (const char*)(sb + (size_t)r1 * 2368) + c1s * 16;
    const char* gB0 = (const char*)(wT + (size_t)(col0 + r0) * 2368) + c0s * 16;
    const char* gB1 = (const char*)(wT + (size_t)(col0 + r1) * 2368) + c1s * 16;
    unsigned short* lA0 = Ash + ci0 * 512;
    unsigned short* lA1 = Ash + ci1 * 512;
    unsigned short* lB0 = Bsh + ci0 * 512;
    unsigned short* lB1 = Bsh + ci1 * 512;

    for (int kt = 0; kt < 74; ++kt) {
        __syncthreads();
        GLL16(gA0, lA0);
        GLL16(gA1, lA1);
        GLL16(gB0, lB0);
        GLL16(gB1, lB1);
        gA0 += 64; gA1 += 64; gB0 += 64; gB1 += 64;
        __syncthreads();
        short8 af[4], bfv[4];
#pragma unroll
        for (int i = 0; i < 4; ++i) {
            int rA = wm * 64 + i * 16 + l15;
            af[i] = *(const short8*)(Ash + rA * 32 + (q ^ ((rA >> 1) & 3)) * 8);
        }
#pragma unroll
        for (int j = 0; j < 4; ++j) {
            int rB = wn * 64 + j * 16 + l15;
            bfv[j] = *(const short8*)(Bsh + rB * 32 + (q ^ ((rB >> 1) & 3)) * 8);
        }
#pragma unroll
        for (int i = 0; i < 4; ++i)
#pragma unroll
            for (int j = 0; j < 4; ++j)
                acc[i][j] = __builtin_amdgcn_mfma_f32_16x16x32_bf16(af[i], bfv[j], acc[i][j], 0, 0, 0);
    }

    int nj[4];
#pragma unroll
    for (int j = 0; j < 4; ++j) nj[j] = col0 + wn * 64 + j * 16 + l15;
#pragma unroll
    for (int i = 0; i < 4; ++i) {
#pragma unroll
        for (int reg = 0; reg < 4; ++reg) {
            int row = wm * 64 + i * 16 + q * 4 + reg;
#pragma unroll
            for (int j = 0; j < 4; ++j)
                outp[(size_t)row * 1024 + nj[j]] = acc[i][j][reg];
        }
    }
}

// ---------------- KP2: P[u*128+w][k] = sb[u][k]*sb[w][k]  (bf16, memory-bound) ------------
__global__ __launch_bounds__(256) void kP2_products(
    const unsigned short* __restrict__ sb, unsigned short* __restrict__ P) {
    int w = blockIdx.x, u = blockIdx.y;
    int tid = threadIdx.x;
    const uint4* su = (const uint4*)(sb + (size_t)u * 2368);
    const uint4* sw = (const uint4*)(sb + (size_t)w * 2368);
    uint4* out = (uint4*)(P + ((size_t)u * 128 + w) * 2368);
    for (int i = tid; i < 296; i += 256) {
        uint4 a = su[i], b = sw[i];
        uint4 r;
        r.x = mul2bf(a.x, b.x); r.y = mul2bf(a.y, b.y);
        r.z = mul2bf(a.z, b.z); r.w = mul2bf(a.w, b.w);
        out[i] = r;
    }
}

// ---------------- K5 (MFMA + global_load_lds): h = relu(P[u] @ W1cT + a[u]+b[w]+b1) -----
__global__ __launch_bounds__(256) void k5_gemm(
    const unsigned short* __restrict__ P, const unsigned short* __restrict__ wT,
    const float* __restrict__ a, const float* __restrict__ b,
    const float* __restrict__ b1, unsigned short* __restrict__ h) {
    __shared__ __align__(16) unsigned short Ash[128 * 32];
    __shared__ __align__(16) unsigned short Bsh[128 * 32];
    int tid = threadIdx.x;
    int u = blockIdx.y;
    int col0 = blockIdx.x * 128;
    int lane = tid & 63, wave = tid >> 6;
    int wm = wave >> 1, wn = wave & 1;
    int q = lane >> 4, l15 = lane & 15;

    floatx4 acc[4][4];
#pragma unroll
    for (int i = 0; i < 4; ++i)
#pragma unroll
        for (int j = 0; j < 4; ++j) acc[i][j] = (floatx4){0.f, 0.f, 0.f, 0.f};

    int ci0 = wave * 2, ci1 = wave * 2 + 1;
    int p = lane & 3;
    int r0 = ci0 * 16 + (lane >> 2), r1 = ci1 * 16 + (lane >> 2);
    int c0s = p ^ ((r0 >> 1) & 3), c1s = p ^ ((r1 >> 1) & 3);
    const char* gA0 = (const char*)(P + (size_t)(u * 128 + r0) * 2368) + c0s * 16;
    const char* gA1 = (const char*)(P + (size_t)(u * 128 + r1) * 2368) + c1s * 16;
    const char* gB0 = (const char*)(wT + (size_t)(col0 + r0) * 2368) + c0s * 16;
    const char* gB1 = (const char*)(wT + (size_t)(col0 + r1) * 2368) + c1s * 16;
    unsigned short* lA0 = Ash + ci0 * 512;
    unsigned short* lA1 = Ash + ci1 * 512;
    unsigned short* lB0 = Bsh + ci0 * 512;
    unsigned short* lB1 = Bsh + ci1 * 512;

    for (int kt = 0; kt < 74; ++kt) {
        __syncthreads();
        GLL16(gA0, lA0);
        GLL16(gA1, lA1);
        GLL16(gB0, lB0);
        GLL16(gB1, lB1);
        gA0 += 64; gA1 += 64; gB0 += 64; gB1 += 64;
        __syncthreads();
        short8 af[4], bfv[4];
#pragma unroll
        for (int i = 0; i < 4; ++i) {
            int rA = wm * 64 + i * 16 + l15;
            af[i] = *(const short8*)(Ash + rA * 32 + (q ^ ((rA >> 1) & 3)) * 8);
        }
#pragma unroll
        for (int j = 0; j < 4; ++j) {
            int rB = wn * 64 + j * 16 + l15;
            bfv[j] = *(const short8*)(Bsh + rB * 32 + (q ^ ((rB >> 1) & 3)) * 8);
        }
#pragma unroll
        for (int i = 0; i < 4; ++i)
#pragma unroll
            for (int j = 0; j < 4; ++j)
                acc[i][j] = __builtin_amdgcn_mfma_f32_16x16x32_bf16(af[i], bfv[j], acc[i][j], 0, 0, 0);
    }

    float aU[4], b1v[4];
    int nj[4];
#pragma unroll
    for (int j = 0; j < 4; ++j) {
        nj[j] = col0 + wn * 64 + j * 16 + l15;
        aU[j] = a[u * 1024 + nj[j]];
        b1v[j] = b1[nj[j]];
    }
    size_t hbase = (size_t)u * 128 * 1024;
#pragma unroll
    for (int i = 0; i < 4; ++i) {
#pragma unroll
        for (int reg = 0; reg < 4; ++reg) {
            int w = wm * 64 + i * 16 + q * 4 + reg;
            const float* brw = b + (size_t)w * 1024;
            unsigned short* hrow = h + hbase + (size_t)w * 1024;
#pragma unroll
            for (int j = 0; j < 4; ++j) {
                float v = acc[i][j][reg] + aU[j] + brw[nj[j]] + b1v[j];
                hrow[nj[j]] = f2b(fmaxf(v, 0.f));
            }
        }
    }
}

// ---------------- K5 fallback (on-the-fly product; used if ws too small) --------
__global__ __launch_bounds__(256) void k5_mfma(
    const unsigned short* __restrict__ sb, const unsigned short* __restrict__ wT,
    const float* __restrict__ a, const float* __restrict__ b,
    const float* __restrict__ b1, unsigned short* __restrict__ h) {
    __shared__ __align__(16) unsigned short Ash[128 * 32];
    __shared__ __align__(16) unsigned short Bsh[128 * 32];
    int tid = threadIdx.x;
    int u = blockIdx.y;
    int col0 = blockIdx.x * 128;
    int lane = tid & 63, wave = tid >> 6;
    int wm = wave >> 1, wn = wave & 1;
    int q = lane >> 4, l15 = lane & 15;

    floatx4 acc[4][4];
#pragma unroll
    for (int i = 0; i < 4; ++i)
#pragma unroll
        for (int j = 0; j < 4; ++j) acc[i][j] = (floatx4){0.f, 0.f, 0.f, 0.f};

    int r = tid >> 1;
    int cb = (tid & 1) * 2;
    int sw = (r >> 1) & 3;
    const unsigned short* arow = sb + (size_t)r * 2368 + cb * 8;
    const unsigned short* urow = sb + (size_t)u * 2368 + cb * 8;
    const unsigned short* brow = wT + (size_t)(col0 + r) * 2368 + cb * 8;
    unsigned short* awp0 = Ash + r * 32 + (cb ^ sw) * 8;
    unsigned short* awp1 = Ash + r * 32 + ((cb + 1) ^ sw) * 8;
    unsigned short* bwp0 = Bsh + r * 32 + (cb ^ sw) * 8;
    unsigned short* bwp1 = Bsh + r * 32 + ((cb + 1) ^ sw) * 8;

    for (int kt = 0; kt < 74; ++kt) {
        int k0 = kt * 32;
        uint4 av0 = *(const uint4*)(arow + k0);
        uint4 av1 = *(const uint4*)(arow + k0 + 8);
        uint4 uv0 = *(const uint4*)(urow + k0);
        uint4 uv1 = *(const uint4*)(urow + k0 + 8);
        uint4 bv0 = *(const uint4*)(brow + k0);
        uint4 bv1 = *(const uint4*)(brow + k0 + 8);
        __syncthreads();
        uint4 p0, p1;
        p0.x = mul2bf(av0.x, uv0.x); p0.y = mul2bf(av0.y, uv0.y);
        p0.z = mul2bf(av0.z, uv0.z); p0.w = mul2bf(av0.w, uv0.w);
        p1.x = mul2bf(av1.x, uv1.x); p1.y = mul2bf(av1.y, uv1.y);
        p1.z = mul2bf(av1.z, uv1.z); p1.w = mul2bf(av1.w, uv1.w);
        *(uint4*)awp0 = p0;
        *(uint4*)awp1 = p1;
        *(uint4*)bwp0 = bv0;
        *(uint4*)bwp1 = bv1;
        __syncthreads();
        short8 af[4], bfv[4];
#pragma unroll
        for (int i = 0; i < 4; ++i) {
            int rA = wm * 64 + i * 16 + l15;
            af[i] = *(const short8*)(Ash + rA * 32 + (q ^ ((rA >> 1) & 3)) * 8);
        }
#pragma unroll
        for (int j = 0; j < 4; ++j) {
            int rB = wn * 64 + j * 16 + l15;
            bfv[j] = *(const short8*)(Bsh + rB * 32 + (q ^ ((rB >> 1) & 3)) * 8);
        }
#pragma unroll
        for (int i = 0; i < 4; ++i)
#pragma unroll
            for (int j = 0; j < 4; ++j)
                acc[i][j] = __builtin_amdgcn_mfma_f32_16x16x32_bf16(af[i], bfv[j], acc[i][j], 0, 0, 0);
    }

    float aU[4], b1v[4];
    int nj[4];
#pragma unroll
    for (int j = 0; j < 4; ++j) {
        nj[j] = col0 + wn * 64 + j * 16 + l15;
        aU[j] = a[u * 1024 + nj[j]];
        b1v[j] = b1[nj[j]];
    }
    size_t hbase = (size_t)u * 128 * 1024;
#pragma unroll
    for (int i = 0; i < 4; ++i) {
#pragma unroll
        for (int reg = 0; reg < 4; ++reg) {
            int w = wm * 64 + i * 16 + q * 4 + reg;
            const float* brw = b + (size_t)w * 1024;
            unsigned short* hrow = h + hbase + (size_t)w * 1024;
#pragma unroll
            for (int j = 0; j < 4; ++j) {
                float v = acc[i][j][reg] + aU[j] + brw[nj[j]] + b1v[j];
                hrow[nj[j]] = f2b(fmaxf(v, 0.f));
            }
        }
    }
}

// ---------------- K6 (MFMA + global_load_lds): ts += (relu(h@W2+b2))@w3 ----------------
__global__ __launch_bounds__(256) void k6_gemm(
    const unsigned short* __restrict__ h, const unsigned short* __restrict__ w2T,
    const float* __restrict__ b2, const float* __restrict__ w3,
    float* __restrict__ ts) {
    __shared__ __align__(16) unsigned short Ash[128 * 32];
    __shared__ __align__(16) unsigned short Bsh[128 * 32];
    int tid = threadIdx.x;
    int m0 = blockIdx.y * 128;
    int col0 = blockIdx.x * 128;
    int lane = tid & 63, wave = tid >> 6;
    int wm = wave >> 1, wn = wave & 1;
    int q = lane >> 4, l15 = lane & 15;

    floatx4 acc[4][4];
#pragma unroll
    for (int i = 0; i < 4; ++i)
#pragma unroll
        for (int j = 0; j < 4; ++j) acc[i][j] = (floatx4){0.f, 0.f, 0.f, 0.f};

    int ci0 = wave * 2, ci1 = wave * 2 + 1;
    int p = lane & 3;
    int r0 = ci0 * 16 + (lane >> 2), r1 = ci1 * 16 + (lane >> 2);
    int c0s = p ^ ((r0 >> 1) & 3), c1s = p ^ ((r1 >> 1) & 3);
    const char* gA0 = (const char*)(h + (size_t)(m0 + r0) * 1024) + c0s * 16;
    const char* gA1 = (const char*)(h + (size_t)(m0 + r1) * 1024) + c1s * 16;
    const char* gB0 = (const char*)(w2T + (size_t)(col0 + r0) * 1024) + c0s * 16;
    const char* gB1 = (const char*)(w2T + (size_t)(col0 + r1) * 1024) + c1s * 16;
    unsigned short* lA0 = Ash + ci0 * 512;
    unsigned short* lA1 = Ash + ci1 * 512;
    unsigned short* lB0 = Bsh + ci0 * 512;
    unsigned short* lB1 = Bsh + ci1 * 512;

    for (int kt = 0; kt < 32; ++kt) {
        __syncthreads();
        GLL16(gA0, lA0);
        GLL16(gA1, lA1);
        GLL16(gB0, lB0);
        GLL16(gB1, lB1);
        gA0 += 64; gA1 += 64; gB0 += 64; gB1 += 64;
        __syncthreads();
        short8 af[4], bfv[4];
#pragma unroll
        for (int i = 0; i < 4; ++i) {
            int rA = wm * 64 + i * 16 + l15;
            af[i] = *(const short8*)(Ash + rA * 32 + (q ^ ((rA >> 1) & 3)) * 8);
        }
#pragma unroll
        for (int j = 0; j < 4; ++j) {
            int rB = wn * 64 + j * 16 + l15;
            bfv[j] = *(const short8*)(Bsh + rB * 32 + (q ^ ((rB >> 1) & 3)) * 8);
        }
#pragma unroll
        for (int i = 0; i < 4; ++i)
#pragma unroll
            for (int j = 0; j < 4; ++j)
                acc[i][j] = __builtin_amdgcn_mfma_f32_16x16x32_bf16(af[i], bfv[j], acc[i][j], 0, 0, 0);
    }

    float b2v[4], w3v[4];
    int nj[4];
#pragma unroll
    for (int j = 0; j < 4; ++j) {
        nj[j] = col0 + wn * 64 + j * 16 + l15;
        b2v[j] = b2[nj[j]];
        w3v[j] = w3[nj[j]];
    }
#pragma unroll
    for (int i = 0; i < 4; ++i) {
#pragma unroll
        for (int reg = 0; reg < 4; ++reg) {
            float s = 0.f;
#pragma unroll
            for (int j = 0; j < 4; ++j)
                s += fmaxf(acc[i][j][reg] + b2v[j], 0.f) * w3v[j];
            s += __shfl_down(s, 8, 16);
            s += __shfl_down(s, 4, 16);
            s += __shfl_down(s, 2, 16);
            s += __shfl_down(s, 1, 16);
            if (l15 == 0)
                atomicAdd(&ts[m0 + wm * 64 + i * 16 + q * 4 + reg], s);
        }
    }
}

// ---------------- K7: adaptive S_c + final loss (parallelized) ----------------
__global__ __launch_bounds__(256) void k7_final(
    const float* __restrict__ ts, const float* __restrict__ Sg,
    const float* __restrict__ m1, const float* __restrict__ b3,
    float* __restrict__ out) {
    __shared__ float rmv[1024], cmv[1024];
    __shared__ float cnt[8], m1s[128];
    __shared__ float Sc[64];
    __shared__ float mg[8][8], mgT[8][8], mc[8][8];
    int tid = threadIdx.x;
    if (tid < 128) m1s[tid] = m1[tid];
    __syncthreads();
    if (tid < 8) {
        float c = 0.f;
        for (int k = 0; k < 16; ++k) c += m1s[tid * 16 + k];
        cnt[tid] = c;
    }
    __syncthreads();
    float b3v = b3[0];
    for (int t = tid; t < 1024; t += 256) {
        int s = t >> 7, v = (t >> 4) & 7, x = t & 15;
        const float* row = ts + (size_t)(s * 16 + x) * 128 + v * 16;
        float r = 0.f;
#pragma unroll
        for (int j = 0; j < 16; ++j) r += (row[j] + b3v) * m1s[v * 16 + j];
        rmv[t] = r / cnt[v];
        float c2 = 0.f;
#pragma unroll
        for (int i = 0; i < 16; ++i)
            c2 += (ts[(size_t)(s * 16 + i) * 128 + v * 16 + x] + b3v) * m1s[s * 16 + i];
        cmv[t] = c2 / cnt[s];
    }
    __syncthreads();
    if (tid < 64) {
        int s = tid >> 3, v = tid & 7;
        float max1 = NEG_INF, max2 = NEG_INF;
        for (int i = 0; i < 16; ++i)
            if (m1s[s * 16 + i] > 0.f) max1 = fmaxf(max1, rmv[(s << 7) | (v << 4) | i]);
        for (int j = 0; j < 16; ++j)
            if (m1s[v * 16 + j] > 0.f) max2 = fmaxf(max2, cmv[(s << 7) | (v << 4) | j]);
        Sc[tid] = 0.5f * (max1 + max2);
    }
    __syncthreads();
    if (tid < 8) {
        int r = tid;
        float mx = NEG_INF;
        for (int v = 0; v < 8; ++v) mx = fmaxf(mx, Sg[r * 8 + v]);
        float sm = 0.f;
        for (int v = 0; v < 8; ++v) sm += expf(Sg[r * 8 + v] - mx);
        for (int v = 0; v < 8; ++v) mg[r][v] = expf(Sg[r * 8 + v] - mx) / sm;

        mx = NEG_INF;
        for (int v = 0; v < 8; ++v) mx = fmaxf(mx, Sc[r * 8 + v]);
        sm = 0.f;
        for (int v = 0; v < 8; ++v) sm += expf(Sc[r * 8 + v] - mx);
        for (int v = 0; v < 8; ++v) mc[r][v] = expf(Sc[r * 8 + v] - mx) / sm;

        mx = NEG_INF;
        for (int s2 = 0; s2 < 8; ++s2) mx = fmaxf(mx, Sg[s2 * 8 + r]);
        sm = 0.f;
        for (int s2 = 0; s2 < 8; ++s2) sm += expf(Sg[s2 * 8 + r] - mx);
        for (int s2 = 0; s2 < 8; ++s2) mgT[r][s2] = expf(Sg[s2 * 8 + r] - mx) / sm;
    }
    __syncthreads();
    if (tid == 0) {
        float loss = 0.f;
        for (int r = 0; r < 8; ++r) {
            float d1 = 0.f, d2 = 0.f;
            for (int v = 0; v < 8; ++v) {
                d1 += mg[r][v] * mc[r][v];
                d2 += mgT[r][v] * mc[r][v];
            }
            loss -= logf(d1) + logf(d2);
        }
        out[0] = loss / 8.f;
    }
}

extern "C" void kernel_launch(void* const* d_in, const int* in_sizes, int n_in,
                              void* d_out, int out_size, void* d_ws, size_t ws_size,
                              hipStream_t stream) {
    const float* doc   = (const float*)d_in[0];
    const float* img   = (const float*)d_in[1];
    const float* tm    = (const float*)d_in[2];
    const float* im    = (const float*)d_in[3];
    const float* se    = (const float*)d_in[4];
    const float* cont  = (const float*)d_in[5];
    const int*   width = (const int*)d_in[6];
    const float* m1    = (const float*)d_in[7];
    const float* aw1   = (const float*)d_in[8];
    const float* ab1   = (const float*)d_in[9];
    const float* aw2   = (const float*)d_in[10];
    const float* ab2   = (const float*)d_in[11];
    const float* wemb  = (const float*)d_in[12];
    const float* pw_w1 = (const float*)d_in[13];
    const float* pw_b1 = (const float*)d_in[14];
    const float* pw_w2 = (const float*)d_in[15];
    const float* pw_b2 = (const float*)d_in[16];
    const float* pw_w3 = (const float*)d_in[17];
    const float* pw_b3 = (const float*)d_in[18];
    float* out = (float*)d_out;

    char* ws = (char*)d_ws;
    float* scores           = (float*)(ws + 0);                 // 1280 f32
    float* a                = (float*)(ws + 8192);              // 128*1024 f32
    float* b                = (float*)(ws + 532480);            // 128*1024 f32
    float* Sg               = (float*)(ws + 1056768);           // 64 f32
    float* ts               = (float*)(ws + 1057024);           // 16384 f32
    unsigned short* sb      = (unsigned short*)(ws + 1122560);  // 128*2368 bf16
    unsigned short* w1cT    = (unsigned short*)(ws + 1728768);  // 1024*2368 bf16
    unsigned short* w2T     = (unsigned short*)(ws + 6578432);  // 1024*1024 bf16
    unsigned short* h       = (unsigned short*)(ws + 8675584);  // 16384*1024 bf16 (33.5 MB)
    unsigned short* P       = (unsigned short*)(ws + 42230016); // 16384*2368 bf16 (77.6 MB)
    const size_t NEED_P = 42230016ull + 16384ull * 2368ull * 2ull;
    // Overlays inside the h region (all dead before k5 writes h):
    unsigned short* contb   = (unsigned short*)(ws + 8675584);  // 1280*768 bf16
    unsigned short* aw1T    = (unsigned short*)(ws + 10641664); // 1024*768 bf16
    unsigned short* w1aT    = (unsigned short*)(ws + 12214528); // 1024*2368 bf16
    unsigned short* w1bT    = (unsigned short*)(ws + 17064192); // 1024*2368 bf16
    float* attall           = (float*)(ws + 21913856);          // 512*288 f32 (ends 22.5MB < 42.2MB)

    kprep<<<8368, 256, 0, stream>>>(pw_w1, pw_w2, aw1, cont, w1cT, w1aT, w1bT,
                                    w2T, aw1T, contb, ts, scores, attall);
    kscore_gemm<<<dim3(8, 10), 256, 0, stream>>>(contb, aw1T, ab1, aw2, scores);
    k2_assemble<<<128, 256, 0, stream>>>(se, cont, width, scores, ab2, wemb, sb);
    k3a_att<<<dim3(3, 4, 8), 256, 0, stream>>>(doc, img, attall);
    k3b_reduce<<<64, 256, 0, stream>>>(attall, tm, im, Sg);
    k4_gemm<<<dim3(8, 2), 256, 0, stream>>>(sb, w1aT, w1bT, a, b);
    if (ws_size >= NEED_P) {
        kP2_products<<<dim3(128, 128), 256, 0, stream>>>(sb, P);
        k5_gemm<<<dim3(8, 128), 256, 0, stream>>>(P, w1cT, a, b, pw_b1, h);
    } else {
        k5_mfma<<<dim3(8, 128), 256, 0, stream>>>(sb, w1cT, a, b, pw_b1, h);
    }
    k6_gemm<<<dim3(8, 128), 256, 0, stream>>>(h, w2T, pw_b2, pw_w3, ts);
    k7_final<<<1, 256, 0, stream>>>(ts, Sg, m1, pw_b3, out);
}

// Round 6
// 402.656 us; speedup vs baseline: 5.0820x; 1.1481x over previous
//
#include <hip/hip_runtime.h>
#include <hip/hip_bf16.h>

#define NEGV -1e10f
#define NEG_INF -3.402823466e38f

typedef __attribute__((ext_vector_type(8))) short short8;
typedef __attribute__((ext_vector_type(4))) float floatx4;

__device__ inline float bf2f(unsigned short u) {
    union { unsigned int i; float f; } c; c.i = ((unsigned int)u) << 16; return c.f;
}
__device__ inline unsigned short f2b(float f) {
    __hip_bfloat16 h = __float2bfloat16(f);
    return *reinterpret_cast<unsigned short*>(&h);
}
// product of two packed bf16 pairs -> packed bf16 pair (RNE)
__device__ inline unsigned int mul2bf(unsigned int x, unsigned int y) {
    union { unsigned int i; float f; } xl, xh, yl, yh;
    xl.i = x << 16; xh.i = x & 0xffff0000u;
    yl.i = y << 16; yh.i = y & 0xffff0000u;
    unsigned int lo = f2b(xl.f * yl.f);
    unsigned int hi = f2b(xh.f * yh.f);
    return lo | (hi << 16);
}

#define GLL16(g, l) __builtin_amdgcn_global_load_lds( \
    (const __attribute__((address_space(1))) void*)(g), \
    (__attribute__((address_space(3))) void*)(l), 16, 0, 0)

// ---------------- KPREP: fused transposes + cont->bf16 + zero-inits ----------------
__device__ void transpose_tile(const float* __restrict__ in, int ldin, int krows,
                               unsigned short* __restrict__ out, int ldout,
                               int ktile, int ntile, unsigned short (*L)[66]) {
    int t = threadIdx.x;
    int kt = ktile * 64, nt = ntile * 64;
    int nl = t & 63, g = t >> 6;
#pragma unroll
    for (int i = 0; i < 16; ++i) {
        int kl = g * 16 + i;
        int k = kt + kl;
        float v = (k < krows) ? in[(size_t)k * ldin + nt + nl] : 0.f;
        L[kl][nl] = f2b(v);
    }
    __syncthreads();
    int kl2 = t & 63;
#pragma unroll
    for (int i = 0; i < 16; ++i) {
        int nl2 = g * 16 + i;
        out[(size_t)(nt + nl2) * ldout + kt + kl2] = L[kl2][nl2];
    }
}

__global__ __launch_bounds__(256) void kprep(
    const float* __restrict__ pw_w1, const float* __restrict__ pw_w2,
    const float* __restrict__ aw1, const float* __restrict__ cont,
    unsigned short* __restrict__ w1cT, unsigned short* __restrict__ w1aT,
    unsigned short* __restrict__ w1bT, unsigned short* __restrict__ w2T,
    unsigned short* __restrict__ aw1T, unsigned short* __restrict__ contb,
    float* __restrict__ ts, float* __restrict__ scores, float* __restrict__ attall) {
    __shared__ unsigned short L[64][66];
    int bid = blockIdx.x;
    int tid = threadIdx.x;
    if (bid < 592) {
        transpose_tile(pw_w1 + (size_t)2 * 2324 * 1024, 1024, 2324, w1cT, 2368,
                       bid % 37, bid / 37, L);
    } else if (bid < 1184) {
        int r = bid - 592;
        transpose_tile(pw_w1, 1024, 2324, w1aT, 2368, r % 37, r / 37, L);
    } else if (bid < 1776) {
        int r = bid - 1184;
        transpose_tile(pw_w1 + (size_t)2324 * 1024, 1024, 2324, w1bT, 2368, r % 37, r / 37, L);
    } else if (bid < 2032) {
        int r = bid - 1776;
        transpose_tile(pw_w2, 1024, 1024, w2T, 1024, r % 16, r / 16, L);
    } else if (bid < 2224) {
        int r = bid - 2032;
        transpose_tile(aw1, 1024, 768, aw1T, 768, r % 12, r / 12, L);
    } else if (bid < 6064) {
        int i = (bid - 2224) * 256 + tid;
        contb[i] = f2b(cont[i]);
    } else {
        int i = (bid - 6064) * 256 + tid;
        attall[i] = 0.f;
        if (i < 16384) ts[i] = 0.f;
        if (i < 1280) scores[i] = 0.f;
    }
}

// ---------------- KSCORE (MFMA): scores[m] += sum_n relu(contb@aw1T + ab1)[m,n]*aw2[n] ----
__global__ __launch_bounds__(256) void kscore_gemm(
    const unsigned short* __restrict__ A, const unsigned short* __restrict__ B,
    const float* __restrict__ ab1, const float* __restrict__ aw2,
    float* __restrict__ scores) {
    __shared__ __align__(16) unsigned short Ash[128 * 32];
    __shared__ __align__(16) unsigned short Bsh[128 * 32];
    int tid = threadIdx.x;
    int m0 = blockIdx.y * 128;
    int col0 = blockIdx.x * 128;
    int lane = tid & 63, wave = tid >> 6;
    int wm = wave >> 1, wn = wave & 1;
    int q = lane >> 4, l15 = lane & 15;

    floatx4 acc[4][4];
#pragma unroll
    for (int i = 0; i < 4; ++i)
#pragma unroll
        for (int j = 0; j < 4; ++j) acc[i][j] = (floatx4){0.f, 0.f, 0.f, 0.f};

    int ci0 = wave * 2, ci1 = wave * 2 + 1;
    int p = lane & 3;
    int r0 = ci0 * 16 + (lane >> 2), r1 = ci1 * 16 + (lane >> 2);
    int c0s = p ^ ((r0 >> 1) & 3), c1s = p ^ ((r1 >> 1) & 3);
    const char* gA0 = (const char*)(A + (size_t)(m0 + r0) * 768) + c0s * 16;
    const char* gA1 = (const char*)(A + (size_t)(m0 + r1) * 768) + c1s * 16;
    const char* gB0 = (const char*)(B + (size_t)(col0 + r0) * 768) + c0s * 16;
    const char* gB1 = (const char*)(B + (size_t)(col0 + r1) * 768) + c1s * 16;
    unsigned short* lA0 = Ash + ci0 * 512;
    unsigned short* lA1 = Ash + ci1 * 512;
    unsigned short* lB0 = Bsh + ci0 * 512;
    unsigned short* lB1 = Bsh + ci1 * 512;

    for (int kt = 0; kt < 24; ++kt) {
        __syncthreads();
        GLL16(gA0, lA0);
        GLL16(gA1, lA1);
        GLL16(gB0, lB0);
        GLL16(gB1, lB1);
        gA0 += 64; gA1 += 64; gB0 += 64; gB1 += 64;
        __syncthreads();
        short8 af[4], bfv[4];
#pragma unroll
        for (int i = 0; i < 4; ++i) {
            int rA = wm * 64 + i * 16 + l15;
            af[i] = *(const short8*)(Ash + rA * 32 + (q ^ ((rA >> 1) & 3)) * 8);
        }
#pragma unroll
        for (int j = 0; j < 4; ++j) {
            int rB = wn * 64 + j * 16 + l15;
            bfv[j] = *(const short8*)(Bsh + rB * 32 + (q ^ ((rB >> 1) & 3)) * 8);
        }
#pragma unroll
        for (int i = 0; i < 4; ++i)
#pragma unroll
            for (int j = 0; j < 4; ++j)
                acc[i][j] = __builtin_amdgcn_mfma_f32_16x16x32_bf16(af[i], bfv[j], acc[i][j], 0, 0, 0);
    }

    float b1v[4], w2v[4];
    int nj[4];
#pragma unroll
    for (int j = 0; j < 4; ++j) {
        nj[j] = col0 + wn * 64 + j * 16 + l15;
        b1v[j] = ab1[nj[j]];
        w2v[j] = aw2[nj[j]];
    }
#pragma unroll
    for (int i = 0; i < 4; ++i) {
#pragma unroll
        for (int reg = 0; reg < 4; ++reg) {
            float s = 0.f;
#pragma unroll
            for (int j = 0; j < 4; ++j)
                s += fmaxf(acc[i][j][reg] + b1v[j], 0.f) * w2v[j];
            s += __shfl_down(s, 8, 16);
            s += __shfl_down(s, 4, 16);
            s += __shfl_down(s, 2, 16);
            s += __shfl_down(s, 1, 16);
            if (l15 == 0)
                atomicAdd(&scores[m0 + wm * 64 + i * 16 + q * 4 + reg], s);
        }
    }
}

// ---------------- K2: softmax over span tokens, assemble bf16 span embeddings -------------
__global__ __launch_bounds__(256) void k2_assemble(
    const float* __restrict__ se, const float* __restrict__ cont,
    const int* __restrict__ width, const float* __restrict__ scores,
    const float* __restrict__ ab2, const float* __restrict__ wemb,
    unsigned short* __restrict__ sb) {
    int nm = blockIdx.x, tid = threadIdx.x;
    int wd = width[nm];
    float ab2v = ab2[0];
    float sc[10];
    float m = NEG_INF;
#pragma unroll
    for (int t = 0; t < 10; ++t) {
        float s = scores[nm * 10 + t] + ab2v;
        sc[t] = (t < wd) ? s : NEGV;
        m = fmaxf(m, sc[t]);
    }
    float sum = 0.f;
#pragma unroll
    for (int t = 0; t < 10; ++t) { sc[t] = expf(sc[t] - m); sum += sc[t]; }
    float inv = 1.f / sum;
#pragma unroll
    for (int t = 0; t < 10; ++t) sc[t] *= inv;
    const float* cbase = cont + (size_t)nm * 7680;
    unsigned short* srow = sb + (size_t)nm * 2368;
    for (int d = tid; d < 768; d += 256) {
        float acc = 0.f;
#pragma unroll
        for (int t = 0; t < 10; ++t) acc = fmaf(sc[t], cbase[t * 768 + d], acc);
        srow[1536 + d] = f2b(acc);
    }
    for (int idx = tid; idx < 1536; idx += 256) srow[idx] = f2b(se[(size_t)nm * 1536 + idx]);
    if (tid < 20) srow[2304 + tid] = f2b(wemb[min(wd, 4) * 20 + tid]);
    if (tid >= 20 && tid < 64) srow[2304 + tid] = 0;
}

// ---------------- K3a: att_all[512][288] = doc @ img^T, fp32, K-split --------------------
__global__ __launch_bounds__(256) void k3a_att(
    const float* __restrict__ doc, const float* __restrict__ img,
    float* __restrict__ attall) {
    __shared__ float As[32][132];
    __shared__ float Bs[32][100];
    int tid = threadIdx.x;
    int n0 = blockIdx.x * 96;
    int m0 = blockIdx.y * 128;
    int k0base = blockIdx.z * 128;
    int tx = tid & 15, ty = tid >> 4;
    float acc[8][6];
#pragma unroll
    for (int r = 0; r < 8; ++r)
#pragma unroll
        for (int c = 0; c < 6; ++c) acc[r][c] = 0.f;

    for (int kc = 0; kc < 4; ++kc) {
        int k0 = k0base + kc * 32;
        __syncthreads();
#pragma unroll
        for (int p2 = 0; p2 < 4; ++p2) {
            int f = tid + 256 * p2;
            int mm = f >> 3, kq = (f & 7) * 4;
            float4 v = *(const float4*)&doc[(size_t)(m0 + mm) * 1024 + k0 + kq];
            As[kq + 0][mm] = v.x; As[kq + 1][mm] = v.y;
            As[kq + 2][mm] = v.z; As[kq + 3][mm] = v.w;
        }
#pragma unroll
        for (int p2 = 0; p2 < 3; ++p2) {
            int f = tid + 256 * p2;
            int nn = f >> 3, kq = (f & 7) * 4;
            float4 v = *(const float4*)&img[(size_t)(n0 + nn) * 1024 + k0 + kq];
            Bs[kq + 0][nn] = v.x; Bs[kq + 1][nn] = v.y;
            Bs[kq + 2][nn] = v.z; Bs[kq + 3][nn] = v.w;
        }
        __syncthreads();
#pragma unroll 4
        for (int k = 0; k < 32; ++k) {
            float4 a0 = *(const float4*)&As[k][ty * 8];
            float4 a1 = *(const float4*)&As[k][ty * 8 + 4];
            float2 b0 = *(const float2*)&Bs[k][tx * 6];
            float2 b1 = *(const float2*)&Bs[k][tx * 6 + 2];
            float2 b2 = *(const float2*)&Bs[k][tx * 6 + 4];
            float ar[8] = {a0.x, a0.y, a0.z, a0.w, a1.x, a1.y, a1.z, a1.w};
            float br[6] = {b0.x, b0.y, b1.x, b1.y, b2.x, b2.y};
#pragma unroll
            for (int r = 0; r < 8; ++r)
#pragma unroll
                for (int c = 0; c < 6; ++c) acc[r][c] = fmaf(ar[r], br[c], acc[r][c]);
        }
    }
#pragma unroll
    for (int r = 0; r < 8; ++r)
#pragma unroll
        for (int c = 0; c < 6; ++c)
            atomicAdd(&attall[(size_t)(m0 + ty * 8 + r) * 288 + n0 + tx * 6 + c], acc[r][c]);
}

// ---------------- K3b: per (s,v) mask + two softmax-reductions -> Sg ----------------
__global__ __launch_bounds__(256) void k3b_reduce(
    const float* __restrict__ attall, const float* __restrict__ tm,
    const float* __restrict__ im, float* __restrict__ Sg) {
    __shared__ float att[64][37];
    __shared__ float tmv[64], imv[36];
    __shared__ float s1sh;
    int b = blockIdx.x;
    int s = b >> 3, v = b & 7;
    int tid = threadIdx.x;
    if (tid < 64) tmv[tid] = tm[s * 64 + tid];
    if (tid >= 64 && tid < 100) imv[tid - 64] = im[v * 36 + (tid - 64)];
    __syncthreads();
    for (int idx = tid; idx < 2304; idx += 256) {
        int i = idx / 36, j = idx - i * 36;
        float raw = attall[(size_t)(s * 64 + i) * 288 + v * 36 + j];
        float x = raw * tmv[i] * imv[j];
        att[i][j] = (x != 0.f) ? x : NEGV;
    }
    __syncthreads();
    float part = 0.f;
    if (tid < 64) {
        int i = tid;
        float mx = NEG_INF;
        for (int j = 0; j < 36; ++j) mx = fmaxf(mx, att[i][j] * imv[j]);
        float sum = 0.f;
        for (int j = 0; j < 36; ++j) sum += expf(att[i][j] * imv[j] - mx);
        float invs = 1.f / sum;
        for (int j = 0; j < 36; ++j) {
            float aw = expf(att[i][j] * imv[j] - mx) * invs * (tmv[i] * imv[j]);
            part += aw * att[i][j];
        }
        for (int off = 32; off > 0; off >>= 1) part += __shfl_down(part, off);
        if (tid == 0) s1sh = part;
    }
    __syncthreads();
    if (tid < 64) {
        float part2 = 0.f;
        if (tid < 36) {
            int j = tid;
            float mx = NEG_INF;
            for (int i = 0; i < 64; ++i) mx = fmaxf(mx, att[i][j]);
            float sum = 0.f;
            for (int i = 0; i < 64; ++i) sum += expf(att[i][j] - mx);
            float invs = 1.f / sum;
            for (int i = 0; i < 64; ++i) {
                float aw = expf(att[i][j] - mx) * invs * (tmv[i] * imv[j]);
                part2 += aw * att[i][j];
            }
        }
        for (int off = 32; off > 0; off >>= 1) part2 += __shfl_down(part2, off);
        if (tid == 0) Sg[s * 8 + v] = s1sh + part2;
    }
}

// ---------------- K4 (MFMA): a = sb@w1aT', b = sb@w1bT' ----------------
__global__ __launch_bounds__(256) void k4_gemm(
    const unsigned short* __restrict__ sb, const unsigned short* __restrict__ w1aT,
    const unsigned short* __restrict__ w1bT, float* __restrict__ aout,
    float* __restrict__ bout) {
    __shared__ __align__(16) unsigned short Ash[128 * 32];
    __shared__ __align__(16) unsigned short Bsh[128 * 32];
    int tid = threadIdx.x;
    int col0 = blockIdx.x * 128;
    int half = blockIdx.y;
    const unsigned short* wT = half ? w1bT : w1aT;
    float* outp = half ? bout : aout;
    int lane = tid & 63, wave = tid >> 6;
    int wm = wave >> 1, wn = wave & 1;
    int q = lane >> 4, l15 = lane & 15;

    floatx4 acc[4][4];
#pragma unroll
    for (int i = 0; i < 4; ++i)
#pragma unroll
        for (int j = 0; j < 4; ++j) acc[i][j] = (floatx4){0.f, 0.f, 0.f, 0.f};

    int ci0 = wave * 2, ci1 = wave * 2 + 1;
    int p = lane & 3;
    int r0 = ci0 * 16 + (lane >> 2), r1 = ci1 * 16 + (lane >> 2);
    int c0s = p ^ ((r0 >> 1) & 3), c1s = p ^ ((r1 >> 1) & 3);
    const char* gA0 = (const char*)(sb + (size_t)r0 * 2368) + c0s * 16;
    const char* gA1 = (const char*)(sb + (size_t)r1 * 2368) + c1s * 16;
    const char* gB0 = (const char*)(wT + (size_t)(col0 + r0) * 2368) + c0s * 16;
    const char* gB1 = (const char*)(wT + (size_t)(col0 + r1) * 2368) + c1s * 16;
    unsigned short* lA0 = Ash + ci0 * 512;
    unsigned short* lA1 = Ash + ci1 * 512;
    unsigned short* lB0 = Bsh + ci0 * 512;
    unsigned short* lB1 = Bsh + ci1 * 512;

    for (int kt = 0; kt < 74; ++kt) {
        __syncthreads();
        GLL16(gA0, lA0);
        GLL16(gA1, lA1);
        GLL16(gB0, lB0);
        GLL16(gB1, lB1);
        gA0 += 64; gA1 += 64; gB0 += 64; gB1 += 64;
        __syncthreads();
        short8 af[4], bfv[4];
#pragma unroll
        for (int i = 0; i < 4; ++i) {
            int rA = wm * 64 + i * 16 + l15;
            af[i] = *(const short8*)(Ash + rA * 32 + (q ^ ((rA >> 1) & 3)) * 8);
        }
#pragma unroll
        for (int j = 0; j < 4; ++j) {
            int rB = wn * 64 + j * 16 + l15;
            bfv[j] = *(const short8*)(Bsh + rB * 32 + (q ^ ((rB >> 1) & 3)) * 8);
        }
#pragma unroll
        for (int i = 0; i < 4; ++i)
#pragma unroll
            for (int j = 0; j < 4; ++j)
                acc[i][j] = __builtin_amdgcn_mfma_f32_16x16x32_bf16(af[i], bfv[j], acc[i][j], 0, 0, 0);
    }

    int nj[4];
#pragma unroll
    for (int j = 0; j < 4; ++j) nj[j] = col0 + wn * 64 + j * 16 + l15;
#pragma unroll
    for (int i = 0; i < 4; ++i) {
#pragma unroll
        for (int reg = 0; reg < 4; ++reg) {
            int row = wm * 64 + i * 16 + q * 4 + reg;
#pragma unroll
            for (int j = 0; j < 4; ++j)
                outp[(size_t)row * 1024 + nj[j]] = acc[i][j][reg];
        }
    }
}

// ---------------- KP2: P[u*128+w] = sb[u] .* sb[w], canonical pairs (w>=u) only ----------
__global__ __launch_bounds__(256) void kP2_products(
    const unsigned short* __restrict__ sb, unsigned short* __restrict__ P) {
    int w = blockIdx.x, u = blockIdx.y;
    if (u > w) return;   // P is symmetric; k5_sym reads only w>=u rows
    int tid = threadIdx.x;
    const uint4* su = (const uint4*)(sb + (size_t)u * 2368);
    const uint4* sw = (const uint4*)(sb + (size_t)w * 2368);
    uint4* out = (uint4*)(P + ((size_t)u * 128 + w) * 2368);
    for (int i = tid; i < 296; i += 256) {
        uint4 a = su[i], b = sw[i];
        uint4 r;
        r.x = mul2bf(a.x, b.x); r.y = mul2bf(a.y, b.y);
        r.z = mul2bf(a.z, b.z); r.w = mul2bf(a.w, b.w);
        out[i] = r;
    }
}

// ---------------- K5_SYM (MFMA, symmetric pair-tiles, XCD-swizzled) ----------------------
// M-tile = 16 u x 8 w = 128 pairs; only tiles intersecting {w>=u} are scheduled (72 of 128).
// Epilogue writes h[u,w] and h[w,u] from the same accumulator (different a/b combos).
// Flat grid id = pt%8 + 8*(col + 8*(pt/8)) -> all 8 col-blocks of a pair-tile on one XCD.
__global__ __launch_bounds__(256) void k5_sym(
    const unsigned short* __restrict__ P, const unsigned short* __restrict__ wT,
    const float* __restrict__ a, const float* __restrict__ b,
    const float* __restrict__ b1, unsigned short* __restrict__ h) {
    __shared__ __align__(16) unsigned short Ash[128 * 32];
    __shared__ __align__(16) unsigned short Bsh[128 * 32];
    int tid = threadIdx.x;
    int bid = blockIdx.x;
    int r8 = bid & 7, t = bid >> 3;
    int c = t & 7, pt = r8 + 8 * (t >> 3);           // pt in [0,72)
    const int offs[9] = {0, 16, 30, 42, 52, 60, 66, 70, 72};
    int ut = 0;
#pragma unroll
    for (int k = 1; k < 8; ++k) if (pt >= offs[k]) ut = k;
    int wt = 2 * ut + (pt - offs[ut]);               // wt in [2*ut,16)
    int col0 = c * 128;

    int lane = tid & 63, wave = tid >> 6;
    int wm = wave >> 1, wn = wave & 1;
    int q = lane >> 4, l15 = lane & 15;

    floatx4 acc[4][4];
#pragma unroll
    for (int i = 0; i < 4; ++i)
#pragma unroll
        for (int j = 0; j < 4; ++j) acc[i][j] = (floatx4){0.f, 0.f, 0.f, 0.f};

    int ci0 = wave * 2, ci1 = wave * 2 + 1;
    int p = lane & 3;
    int r0 = ci0 * 16 + (lane >> 2), r1 = ci1 * 16 + (lane >> 2);
    int c0s = p ^ ((r0 >> 1) & 3), c1s = p ^ ((r1 >> 1) & 3);
    size_t prow0 = (size_t)(ut * 16 + (r0 >> 3)) * 128 + (wt * 8 + (r0 & 7));
    size_t prow1 = (size_t)(ut * 16 + (r1 >> 3)) * 128 + (wt * 8 + (r1 & 7));
    const char* gA0 = (const char*)(P + prow0 * 2368) + c0s * 16;
    const char* gA1 = (const char*)(P + prow1 * 2368) + c1s * 16;
    const char* gB0 = (const char*)(wT + (size_t)(col0 + r0) * 2368) + c0s * 16;
    const char* gB1 = (const char*)(wT + (size_t)(col0 + r1) * 2368) + c1s * 16;
    unsigned short* lA0 = Ash + ci0 * 512;
    unsigned short* lA1 = Ash + ci1 * 512;
    unsigned short* lB0 = Bsh + ci0 * 512;
    unsigned short* lB1 = Bsh + ci1 * 512;

    for (int kt = 0; kt < 74; ++kt) {
        __syncthreads();
        GLL16(gA0, lA0);
        GLL16(gA1, lA1);
        GLL16(gB0, lB0);
        GLL16(gB1, lB1);
        gA0 += 64; gA1 += 64; gB0 += 64; gB1 += 64;
        __syncthreads();
        short8 af[4], bfv[4];
#pragma unroll
        for (int i = 0; i < 4; ++i) {
            int rA = wm * 64 + i * 16 + l15;
            af[i] = *(const short8*)(Ash + rA * 32 + (q ^ ((rA >> 1) & 3)) * 8);
        }
#pragma unroll
        for (int j = 0; j < 4; ++j) {
            int rB = wn * 64 + j * 16 + l15;
            bfv[j] = *(const short8*)(Bsh + rB * 32 + (q ^ ((rB >> 1) & 3)) * 8);
        }
#pragma unroll
        for (int i = 0; i < 4; ++i)
#pragma unroll
            for (int j = 0; j < 4; ++j)
                acc[i][j] = __builtin_amdgcn_mfma_f32_16x16x32_bf16(af[i], bfv[j], acc[i][j], 0, 0, 0);
    }

    float b1v[4];
    int nj[4];
#pragma unroll
    for (int j = 0; j < 4; ++j) {
        nj[j] = col0 + wn * 64 + j * 16 + l15;
        b1v[j] = b1[nj[j]];
    }
#pragma unroll
    for (int i = 0; i < 4; ++i) {
#pragma unroll
        for (int reg = 0; reg < 4; ++reg) {
            int m = wm * 64 + i * 16 + q * 4 + reg;
            int u = ut * 16 + (m >> 3);
            int w = wt * 8 + (m & 7);
            if (w < u) continue;                     // covered by canonical tile elsewhere
            const float* au = a + (size_t)u * 1024;
            const float* bw = b + (size_t)w * 1024;
            unsigned short* hrow = h + ((size_t)u * 128 + w) * 1024;
#pragma unroll
            for (int j = 0; j < 4; ++j)
                hrow[nj[j]] = f2b(fmaxf(acc[i][j][reg] + au[nj[j]] + bw[nj[j]] + b1v[j], 0.f));
            if (w > u) {
                const float* aw_ = a + (size_t)w * 1024;
                const float* bu = b + (size_t)u * 1024;
                unsigned short* hrow2 = h + ((size_t)w * 128 + u) * 1024;
#pragma unroll
                for (int j = 0; j < 4; ++j)
                    hrow2[nj[j]] = f2b(fmaxf(acc[i][j][reg] + aw_[nj[j]] + bu[nj[j]] + b1v[j], 0.f));
            }
        }
    }
}

// ---------------- K5 fallback (on-the-fly product; used if ws too small) --------
__global__ __launch_bounds__(256) void k5_mfma(
    const unsigned short* __restrict__ sb, const unsigned short* __restrict__ wT,
    const float* __restrict__ a, const float* __restrict__ b,
    const float* __restrict__ b1, unsigned short* __restrict__ h) {
    __shared__ __align__(16) unsigned short Ash[128 * 32];
    __shared__ __align__(16) unsigned short Bsh[128 * 32];
    int tid = threadIdx.x;
    int u = blockIdx.y;
    int col0 = blockIdx.x * 128;
    int lane = tid & 63, wave = tid >> 6;
    int wm = wave >> 1, wn = wave & 1;
    int q = lane >> 4, l15 = lane & 15;

    floatx4 acc[4][4];
#pragma unroll
    for (int i = 0; i < 4; ++i)
#pragma unroll
        for (int j = 0; j < 4; ++j) acc[i][j] = (floatx4){0.f, 0.f, 0.f, 0.f};

    int r = tid >> 1;
    int cb = (tid & 1) * 2;
    int sw = (r >> 1) & 3;
    const unsigned short* arow = sb + (size_t)r * 2368 + cb * 8;
    const unsigned short* urow = sb + (size_t)u * 2368 + cb * 8;
    const unsigned short* brow = wT + (size_t)(col0 + r) * 2368 + cb * 8;
    unsigned short* awp0 = Ash + r * 32 + (cb ^ sw) * 8;
    unsigned short* awp1 = Ash + r * 32 + ((cb + 1) ^ sw) * 8;
    unsigned short* bwp0 = Bsh + r * 32 + (cb ^ sw) * 8;
    unsigned short* bwp1 = Bsh + r * 32 + ((cb + 1) ^ sw) * 8;

    for (int kt = 0; kt < 74; ++kt) {
        int k0 = kt * 32;
        uint4 av0 = *(const uint4*)(arow + k0);
        uint4 av1 = *(const uint4*)(arow + k0 + 8);
        uint4 uv0 = *(const uint4*)(urow + k0);
        uint4 uv1 = *(const uint4*)(urow + k0 + 8);
        uint4 bv0 = *(const uint4*)(brow + k0);
        uint4 bv1 = *(const uint4*)(brow + k0 + 8);
        __syncthreads();
        uint4 p0, p1;
        p0.x = mul2bf(av0.x, uv0.x); p0.y = mul2bf(av0.y, uv0.y);
        p0.z = mul2bf(av0.z, uv0.z); p0.w = mul2bf(av0.w, uv0.w);
        p1.x = mul2bf(av1.x, uv1.x); p1.y = mul2bf(av1.y, uv1.y);
        p1.z = mul2bf(av1.z, uv1.z); p1.w = mul2bf(av1.w, uv1.w);
        *(uint4*)awp0 = p0;
        *(uint4*)awp1 = p1;
        *(uint4*)bwp0 = bv0;
        *(uint4*)bwp1 = bv1;
        __syncthreads();
        short8 af[4], bfv[4];
#pragma unroll
        for (int i = 0; i < 4; ++i) {
            int rA = wm * 64 + i * 16 + l15;
            af[i] = *(const short8*)(Ash + rA * 32 + (q ^ ((rA >> 1) & 3)) * 8);
        }
#pragma unroll
        for (int j = 0; j < 4; ++j) {
            int rB = wn * 64 + j * 16 + l15;
            bfv[j] = *(const short8*)(Bsh + rB * 32 + (q ^ ((rB >> 1) & 3)) * 8);
        }
#pragma unroll
        for (int i = 0; i < 4; ++i)
#pragma unroll
            for (int j = 0; j < 4; ++j)
                acc[i][j] = __builtin_amdgcn_mfma_f32_16x16x32_bf16(af[i], bfv[j], acc[i][j], 0, 0, 0);
    }

    float aU[4], b1v[4];
    int nj[4];
#pragma unroll
    for (int j = 0; j < 4; ++j) {
        nj[j] = col0 + wn * 64 + j * 16 + l15;
        aU[j] = a[u * 1024 + nj[j]];
        b1v[j] = b1[nj[j]];
    }
    size_t hbase = (size_t)u * 128 * 1024;
#pragma unroll
    for (int i = 0; i < 4; ++i) {
#pragma unroll
        for (int reg = 0; reg < 4; ++reg) {
            int w = wm * 64 + i * 16 + q * 4 + reg;
            const float* brw = b + (size_t)w * 1024;
            unsigned short* hrow = h + hbase + (size_t)w * 1024;
#pragma unroll
            for (int j = 0; j < 4; ++j) {
                float v = acc[i][j][reg] + aU[j] + brw[nj[j]] + b1v[j];
                hrow[nj[j]] = f2b(fmaxf(v, 0.f));
            }
        }
    }
}

// ---------------- K6 (MFMA, XCD-swizzled): ts += (relu(h@W2+b2))@w3 ----------------------
__global__ __launch_bounds__(256) void k6_gemm(
    const unsigned short* __restrict__ h, const unsigned short* __restrict__ w2T,
    const float* __restrict__ b2, const float* __restrict__ w3,
    float* __restrict__ ts) {
    __shared__ __align__(16) unsigned short Ash[128 * 32];
    __shared__ __align__(16) unsigned short Bsh[128 * 32];
    int tid = threadIdx.x;
    int bid = blockIdx.x;
    int r8 = bid & 7, t = bid >> 3;
    int cb = t & 7, mb = r8 + 8 * (t >> 3);          // all 8 col-blocks of mb on one XCD
    int m0 = mb * 128;
    int col0 = cb * 128;
    int lane = tid & 63, wave = tid >> 6;
    int wm = wave >> 1, wn = wave & 1;
    int q = lane >> 4, l15 = lane & 15;

    floatx4 acc[4][4];
#pragma unroll
    for (int i = 0; i < 4; ++i)
#pragma unroll
        for (int j = 0; j < 4; ++j) acc[i][j] = (floatx4){0.f, 0.f, 0.f, 0.f};

    int ci0 = wave * 2, ci1 = wave * 2 + 1;
    int p = lane & 3;
    int r0 = ci0 * 16 + (lane >> 2), r1 = ci1 * 16 + (lane >> 2);
    int c0s = p ^ ((r0 >> 1) & 3), c1s = p ^ ((r1 >> 1) & 3);
    const char* gA0 = (const char*)(h + (size_t)(m0 + r0) * 1024) + c0s * 16;
    const char* gA1 = (const char*)(h + (size_t)(m0 + r1) * 1024) + c1s * 16;
    const char* gB0 = (const char*)(w2T + (size_t)(col0 + r0) * 1024) + c0s * 16;
    const char* gB1 = (const char*)(w2T + (size_t)(col0 + r1) * 1024) + c1s * 16;
    unsigned short* lA0 = Ash + ci0 * 512;
    unsigned short* lA1 = Ash + ci1 * 512;
    unsigned short* lB0 = Bsh + ci0 * 512;
    unsigned short* lB1 = Bsh + ci1 * 512;

    for (int kt = 0; kt < 32; ++kt) {
        __syncthreads();
        GLL16(gA0, lA0);
        GLL16(gA1, lA1);
        GLL16(gB0, lB0);
        GLL16(gB1, lB1);
        gA0 += 64; gA1 += 64; gB0 += 64; gB1 += 64;
        __syncthreads();
        short8 af[4], bfv[4];
#pragma unroll
        for (int i = 0; i < 4; ++i) {
            int rA = wm * 64 + i * 16 + l15;
            af[i] = *(const short8*)(Ash + rA * 32 + (q ^ ((rA >> 1) & 3)) * 8);
        }
#pragma unroll
        for (int j = 0; j < 4; ++j) {
            int rB = wn * 64 + j * 16 + l15;
            bfv[j] = *(const short8*)(Bsh + rB * 32 + (q ^ ((rB >> 1) & 3)) * 8);
        }
#pragma unroll
        for (int i = 0; i < 4; ++i)
#pragma unroll
            for (int j = 0; j < 4; ++j)
                acc[i][j] = __builtin_amdgcn_mfma_f32_16x16x32_bf16(af[i], bfv[j], acc[i][j], 0, 0, 0);
    }

    float b2v[4], w3v[4];
    int nj[4];
#pragma unroll
    for (int j = 0; j < 4; ++j) {
        nj[j] = col0 + wn * 64 + j * 16 + l15;
        b2v[j] = b2[nj[j]];
        w3v[j] = w3[nj[j]];
    }
#pragma unroll
    for (int i = 0; i < 4; ++i) {
#pragma unroll
        for (int reg = 0; reg < 4; ++reg) {
            float s = 0.f;
#pragma unroll
            for (int j = 0; j < 4; ++j)
                s += fmaxf(acc[i][j][reg] + b2v[j], 0.f) * w3v[j];
            s += __shfl_down(s, 8, 16);
            s += __shfl_down(s, 4, 16);
            s += __shfl_down(s, 2, 16);
            s += __shfl_down(s, 1, 16);
            if (l15 == 0)
                atomicAdd(&ts[m0 + wm * 64 + i * 16 + q * 4 + reg], s);
        }
    }
}

// ---------------- K7: adaptive S_c + final loss (parallelized) ----------------
__global__ __launch_bounds__(256) void k7_final(
    const float* __restrict__ ts, const float* __restrict__ Sg,
    const float* __restrict__ m1, const float* __restrict__ b3,
    float* __restrict__ out) {
    __shared__ float rmv[1024], cmv[1024];
    __shared__ float cnt[8], m1s[128];
    __shared__ float Sc[64];
    __shared__ float mg[8][8], mgT[8][8], mc[8][8];
    int tid = threadIdx.x;
    if (tid < 128) m1s[tid] = m1[tid];
    __syncthreads();
    if (tid < 8) {
        float c = 0.f;
        for (int k = 0; k < 16; ++k) c += m1s[tid * 16 + k];
        cnt[tid] = c;
    }
    __syncthreads();
    float b3v = b3[0];
    for (int t = tid; t < 1024; t += 256) {
        int s = t >> 7, v = (t >> 4) & 7, x = t & 15;
        const float* row = ts + (size_t)(s * 16 + x) * 128 + v * 16;
        float r = 0.f;
#pragma unroll
        for (int j = 0; j < 16; ++j) r += (row[j] + b3v) * m1s[v * 16 + j];
        rmv[t] = r / cnt[v];
        float c2 = 0.f;
#pragma unroll
        for (int i = 0; i < 16; ++i)
            c2 += (ts[(size_t)(s * 16 + i) * 128 + v * 16 + x] + b3v) * m1s[s * 16 + i];
        cmv[t] = c2 / cnt[s];
    }
    __syncthreads();
    if (tid < 64) {
        int s = tid >> 3, v = tid & 7;
        float max1 = NEG_INF, max2 = NEG_INF;
        for (int i = 0; i < 16; ++i)
            if (m1s[s * 16 + i] > 0.f) max1 = fmaxf(max1, rmv[(s << 7) | (v << 4) | i]);
        for (int j = 0; j < 16; ++j)
            if (m1s[v * 16 + j] > 0.f) max2 = fmaxf(max2, cmv[(s << 7) | (v << 4) | j]);
        Sc[tid] = 0.5f * (max1 + max2);
    }
    __syncthreads();
    if (tid < 8) {
        int r = tid;
        float mx = NEG_INF;
        for (int v = 0; v < 8; ++v) mx = fmaxf(mx, Sg[r * 8 + v]);
        float sm = 0.f;
        for (int v = 0; v < 8; ++v) sm += expf(Sg[r * 8 + v] - mx);
        for (int v = 0; v < 8; ++v) mg[r][v] = expf(Sg[r * 8 + v] - mx) / sm;

        mx = NEG_INF;
        for (int v = 0; v < 8; ++v) mx = fmaxf(mx, Sc[r * 8 + v]);
        sm = 0.f;
        for (int v = 0; v < 8; ++v) sm += expf(Sc[r * 8 + v] - mx);
        for (int v = 0; v < 8; ++v) mc[r][v] = expf(Sc[r * 8 + v] - mx) / sm;

        mx = NEG_INF;
        for (int s2 = 0; s2 < 8; ++s2) mx = fmaxf(mx, Sg[s2 * 8 + r]);
        sm = 0.f;
        for (int s2 = 0; s2 < 8; ++s2) sm += expf(Sg[s2 * 8 + r] - mx);
        for (int s2 = 0; s2 < 8; ++s2) mgT[r][s2] = expf(Sg[s2 * 8 + r] - mx) / sm;
    }
    __syncthreads();
    if (tid == 0) {
        float loss = 0.f;
        for (int r = 0; r < 8; ++r) {
            float d1 = 0.f, d2 = 0.f;
            for (int v = 0; v < 8; ++v) {
                d1 += mg[r][v] * mc[r][v];
                d2 += mgT[r][v] * mc[r][v];
            }
            loss -= logf(d1) + logf(d2);
        }
        out[0] = loss / 8.f;
    }
}

extern "C" void kernel_launch(void* const* d_in, const int* in_sizes, int n_in,
                              void* d_out, int out_size, void* d_ws, size_t ws_size,
                              hipStream_t stream) {
    const float* doc   = (const float*)d_in[0];
    const float* img   = (const float*)d_in[1];
    const float* tm    = (const float*)d_in[2];
    const float* im    = (const float*)d_in[3];
    const float* se    = (const float*)d_in[4];
    const float* cont  = (const float*)d_in[5];
    const int*   width = (const int*)d_in[6];
    const float* m1    = (const float*)d_in[7];
    const float* aw1   = (const float*)d_in[8];
    const float* ab1   = (const float*)d_in[9];
    const float* aw2   = (const float*)d_in[10];
    const float* ab2   = (const float*)d_in[11];
    const float* wemb  = (const float*)d_in[12];
    const float* pw_w1 = (const float*)d_in[13];
    const float* pw_b1 = (const float*)d_in[14];
    const float* pw_w2 = (const float*)d_in[15];
    const float* pw_b2 = (const float*)d_in[16];
    const float* pw_w3 = (const float*)d_in[17];
    const float* pw_b3 = (const float*)d_in[18];
    float* out = (float*)d_out;

    char* ws = (char*)d_ws;
    float* scores           = (float*)(ws + 0);                 // 1280 f32
    float* a                = (float*)(ws + 8192);              // 128*1024 f32
    float* b                = (float*)(ws + 532480);            // 128*1024 f32
    float* Sg               = (float*)(ws + 1056768);           // 64 f32
    float* ts               = (float*)(ws + 1057024);           // 16384 f32
    unsigned short* sb      = (unsigned short*)(ws + 1122560);  // 128*2368 bf16
    unsigned short* w1cT    = (unsigned short*)(ws + 1728768);  // 1024*2368 bf16
    unsigned short* w2T     = (unsigned short*)(ws + 6578432);  // 1024*1024 bf16
    unsigned short* h       = (unsigned short*)(ws + 8675584);  // 16384*1024 bf16 (33.5 MB)
    unsigned short* P       = (unsigned short*)(ws + 42230016); // 16384*2368 bf16 (77.6 MB)
    const size_t NEED_P = 42230016ull + 16384ull * 2368ull * 2ull;
    // Overlays inside the h region (all dead before k5 writes h):
    unsigned short* contb   = (unsigned short*)(ws + 8675584);  // 1280*768 bf16
    unsigned short* aw1T    = (unsigned short*)(ws + 10641664); // 1024*768 bf16
    unsigned short* w1aT    = (unsigned short*)(ws + 12214528); // 1024*2368 bf16
    unsigned short* w1bT    = (unsigned short*)(ws + 17064192); // 1024*2368 bf16
    float* attall           = (float*)(ws + 21913856);          // 512*288 f32

    kprep<<<8368, 256, 0, stream>>>(pw_w1, pw_w2, aw1, cont, w1cT, w1aT, w1bT,
                                    w2T, aw1T, contb, ts, scores, attall);
    kscore_gemm<<<dim3(8, 10), 256, 0, stream>>>(contb, aw1T, ab1, aw2, scores);
    k2_assemble<<<128, 256, 0, stream>>>(se, cont, width, scores, ab2, wemb, sb);
    k3a_att<<<dim3(3, 4, 8), 256, 0, stream>>>(doc, img, attall);
    k3b_reduce<<<64, 256, 0, stream>>>(attall, tm, im, Sg);
    k4_gemm<<<dim3(8, 2), 256, 0, stream>>>(sb, w1aT, w1bT, a, b);
    if (ws_size >= NEED_P) {
        kP2_products<<<dim3(128, 128), 256, 0, stream>>>(sb, P);
        k5_sym<<<576, 256, 0, stream>>>(P, w1cT, a, b, pw_b1, h);
    } else {
        k5_mfma<<<dim3(8, 128), 256, 0, stream>>>(sb, w1cT, a, b, pw_b1, h);
    }
    k6_gemm<<<1024, 256, 0, stream>>>(h, w2T, pw_b2, pw_w3, ts);
    k7_final<<<1, 256, 0, stream>>>(ts, Sg, m1, pw_b3, out);
}

// Round 7
// 338.266 us; speedup vs baseline: 6.0494x; 1.1904x over previous
//
#include <hip/hip_runtime.h>
#include <hip/hip_bf16.h>

#define NEGV -1e10f
#define NEG_INF -3.402823466e38f

typedef __attribute__((ext_vector_type(8))) short short8;
typedef __attribute__((ext_vector_type(4))) float floatx4;

__device__ inline float bf2f(unsigned short u) {
    union { unsigned int i; float f; } c; c.i = ((unsigned int)u) << 16; return c.f;
}
__device__ inline unsigned short f2b(float f) {
    __hip_bfloat16 h = __float2bfloat16(f);
    return *reinterpret_cast<unsigned short*>(&h);
}
// product of two packed bf16 pairs -> packed bf16 pair (RNE)
__device__ inline unsigned int mul2bf(unsigned int x, unsigned int y) {
    union { unsigned int i; float f; } xl, xh, yl, yh;
    xl.i = x << 16; xh.i = x & 0xffff0000u;
    yl.i = y << 16; yh.i = y & 0xffff0000u;
    unsigned int lo = f2b(xl.f * yl.f);
    unsigned int hi = f2b(xh.f * yh.f);
    return lo | (hi << 16);
}

#define GLL16(g, l) __builtin_amdgcn_global_load_lds( \
    (const __attribute__((address_space(1))) void*)(g), \
    (__attribute__((address_space(3))) void*)(l), 16, 0, 0)

// ---------------- KPREP: fused transposes + cont->bf16 + zero-inits ----------------
__device__ void transpose_tile(const float* __restrict__ in, int ldin, int krows,
                               unsigned short* __restrict__ out, int ldout,
                               int ktile, int ntile, unsigned short (*L)[66]) {
    int t = threadIdx.x;
    int kt = ktile * 64, nt = ntile * 64;
    int nl = t & 63, g = t >> 6;
#pragma unroll
    for (int i = 0; i < 16; ++i) {
        int kl = g * 16 + i;
        int k = kt + kl;
        float v = (k < krows) ? in[(size_t)k * ldin + nt + nl] : 0.f;
        L[kl][nl] = f2b(v);
    }
    __syncthreads();
    int kl2 = t & 63;
#pragma unroll
    for (int i = 0; i < 16; ++i) {
        int nl2 = g * 16 + i;
        out[(size_t)(nt + nl2) * ldout + kt + kl2] = L[kl2][nl2];
    }
}

__global__ __launch_bounds__(256) void kprep(
    const float* __restrict__ pw_w1, const float* __restrict__ pw_w2,
    const float* __restrict__ aw1, const float* __restrict__ cont,
    unsigned short* __restrict__ w1cT, unsigned short* __restrict__ w1aT,
    unsigned short* __restrict__ w1bT, unsigned short* __restrict__ w2T,
    unsigned short* __restrict__ aw1T, unsigned short* __restrict__ contb,
    float* __restrict__ ts, float* __restrict__ scores, float* __restrict__ attall,
    float* __restrict__ a, float* __restrict__ b) {
    __shared__ unsigned short L[64][66];
    int bid = blockIdx.x;
    int tid = threadIdx.x;
    if (bid < 592) {
        transpose_tile(pw_w1 + (size_t)2 * 2324 * 1024, 1024, 2324, w1cT, 2368,
                       bid % 37, bid / 37, L);
    } else if (bid < 1184) {
        int r = bid - 592;
        transpose_tile(pw_w1, 1024, 2324, w1aT, 2368, r % 37, r / 37, L);
    } else if (bid < 1776) {
        int r = bid - 1184;
        transpose_tile(pw_w1 + (size_t)2324 * 1024, 1024, 2324, w1bT, 2368, r % 37, r / 37, L);
    } else if (bid < 2032) {
        int r = bid - 1776;
        transpose_tile(pw_w2, 1024, 1024, w2T, 1024, r % 16, r / 16, L);
    } else if (bid < 2224) {
        int r = bid - 2032;
        transpose_tile(aw1, 1024, 768, aw1T, 768, r % 12, r / 12, L);
    } else if (bid < 6064) {
        int i = (bid - 2224) * 256 + tid;
        contb[i] = f2b(cont[i]);
    } else if (bid < 8368) {
        int i = (bid - 6064) * 256 + tid;
        attall[i] = 0.f;
        if (i < 16384) ts[i] = 0.f;
        if (i < 1280) scores[i] = 0.f;
    } else {
        int i = (bid - 8368) * 256 + tid;   // < 131072
        a[i] = 0.f;
        b[i] = 0.f;
    }
}

// ---------------- KMIDA: kscore (80 blocks) + k3a (96 blocks) merged ----------------
__global__ __launch_bounds__(256) void kmidA(
    const unsigned short* __restrict__ contb, const unsigned short* __restrict__ aw1T,
    const float* __restrict__ ab1, const float* __restrict__ aw2,
    float* __restrict__ scores,
    const float* __restrict__ doc, const float* __restrict__ img,
    float* __restrict__ attall) {
    __shared__ __align__(16) unsigned short Ash[128 * 32];
    __shared__ __align__(16) unsigned short Bsh[128 * 32];
    __shared__ float As[32][132];
    __shared__ float Bs[32][100];
    int bid = blockIdx.x;
    int tid = threadIdx.x;

    if (bid < 80) {
        // ---- kscore: scores[m] += sum_n relu(contb@aw1T + ab1)[m,n]*aw2[n] ----
        int m0 = (bid >> 3) * 128;
        int col0 = (bid & 7) * 128;
        int lane = tid & 63, wave = tid >> 6;
        int wm = wave >> 1, wn = wave & 1;
        int q = lane >> 4, l15 = lane & 15;

        floatx4 acc[4][4];
#pragma unroll
        for (int i = 0; i < 4; ++i)
#pragma unroll
            for (int j = 0; j < 4; ++j) acc[i][j] = (floatx4){0.f, 0.f, 0.f, 0.f};

        int ci0 = wave * 2, ci1 = wave * 2 + 1;
        int p = lane & 3;
        int r0 = ci0 * 16 + (lane >> 2), r1 = ci1 * 16 + (lane >> 2);
        int c0s = p ^ ((r0 >> 1) & 3), c1s = p ^ ((r1 >> 1) & 3);
        const char* gA0 = (const char*)(contb + (size_t)(m0 + r0) * 768) + c0s * 16;
        const char* gA1 = (const char*)(contb + (size_t)(m0 + r1) * 768) + c1s * 16;
        const char* gB0 = (const char*)(aw1T + (size_t)(col0 + r0) * 768) + c0s * 16;
        const char* gB1 = (const char*)(aw1T + (size_t)(col0 + r1) * 768) + c1s * 16;
        unsigned short* lA0 = Ash + ci0 * 512;
        unsigned short* lA1 = Ash + ci1 * 512;
        unsigned short* lB0 = Bsh + ci0 * 512;
        unsigned short* lB1 = Bsh + ci1 * 512;

        for (int kt = 0; kt < 24; ++kt) {
            __syncthreads();
            GLL16(gA0, lA0);
            GLL16(gA1, lA1);
            GLL16(gB0, lB0);
            GLL16(gB1, lB1);
            gA0 += 64; gA1 += 64; gB0 += 64; gB1 += 64;
            __syncthreads();
            short8 af[4], bfv[4];
#pragma unroll
            for (int i = 0; i < 4; ++i) {
                int rA = wm * 64 + i * 16 + l15;
                af[i] = *(const short8*)(Ash + rA * 32 + (q ^ ((rA >> 1) & 3)) * 8);
            }
#pragma unroll
            for (int j = 0; j < 4; ++j) {
                int rB = wn * 64 + j * 16 + l15;
                bfv[j] = *(const short8*)(Bsh + rB * 32 + (q ^ ((rB >> 1) & 3)) * 8);
            }
#pragma unroll
            for (int i = 0; i < 4; ++i)
#pragma unroll
                for (int j = 0; j < 4; ++j)
                    acc[i][j] = __builtin_amdgcn_mfma_f32_16x16x32_bf16(af[i], bfv[j], acc[i][j], 0, 0, 0);
        }

        float b1v[4], w2v[4];
        int nj[4];
#pragma unroll
        for (int j = 0; j < 4; ++j) {
            nj[j] = col0 + wn * 64 + j * 16 + l15;
            b1v[j] = ab1[nj[j]];
            w2v[j] = aw2[nj[j]];
        }
#pragma unroll
        for (int i = 0; i < 4; ++i) {
#pragma unroll
            for (int reg = 0; reg < 4; ++reg) {
                float s = 0.f;
#pragma unroll
                for (int j = 0; j < 4; ++j)
                    s += fmaxf(acc[i][j][reg] + b1v[j], 0.f) * w2v[j];
                s += __shfl_down(s, 8, 16);
                s += __shfl_down(s, 4, 16);
                s += __shfl_down(s, 2, 16);
                s += __shfl_down(s, 1, 16);
                if (l15 == 0)
                    atomicAdd(&scores[m0 + wm * 64 + i * 16 + q * 4 + reg], s);
            }
        }
    } else {
        // ---- k3a: att_all[512][288] += doc @ img^T (K-chunk) ----
        int r = bid - 80;
        int n0 = (r % 3) * 96;
        int m0 = ((r / 3) & 3) * 128;
        int k0base = (r / 12) * 128;
        int tx = tid & 15, ty = tid >> 4;
        float acc[8][6];
#pragma unroll
        for (int rr = 0; rr < 8; ++rr)
#pragma unroll
            for (int c = 0; c < 6; ++c) acc[rr][c] = 0.f;

        for (int kc = 0; kc < 4; ++kc) {
            int k0 = k0base + kc * 32;
            __syncthreads();
#pragma unroll
            for (int p2 = 0; p2 < 4; ++p2) {
                int f = tid + 256 * p2;
                int mm = f >> 3, kq = (f & 7) * 4;
                float4 v = *(const float4*)&doc[(size_t)(m0 + mm) * 1024 + k0 + kq];
                As[kq + 0][mm] = v.x; As[kq + 1][mm] = v.y;
                As[kq + 2][mm] = v.z; As[kq + 3][mm] = v.w;
            }
#pragma unroll
            for (int p2 = 0; p2 < 3; ++p2) {
                int f = tid + 256 * p2;
                int nn = f >> 3, kq = (f & 7) * 4;
                float4 v = *(const float4*)&img[(size_t)(n0 + nn) * 1024 + k0 + kq];
                Bs[kq + 0][nn] = v.x; Bs[kq + 1][nn] = v.y;
                Bs[kq + 2][nn] = v.z; Bs[kq + 3][nn] = v.w;
            }
            __syncthreads();
#pragma unroll 4
            for (int k = 0; k < 32; ++k) {
                float4 a0 = *(const float4*)&As[k][ty * 8];
                float4 a1 = *(const float4*)&As[k][ty * 8 + 4];
                float2 b0 = *(const float2*)&Bs[k][tx * 6];
                float2 b1 = *(const float2*)&Bs[k][tx * 6 + 2];
                float2 b2 = *(const float2*)&Bs[k][tx * 6 + 4];
                float ar[8] = {a0.x, a0.y, a0.z, a0.w, a1.x, a1.y, a1.z, a1.w};
                float br[6] = {b0.x, b0.y, b1.x, b1.y, b2.x, b2.y};
#pragma unroll
                for (int rr = 0; rr < 8; ++rr)
#pragma unroll
                    for (int c = 0; c < 6; ++c) acc[rr][c] = fmaf(ar[rr], br[c], acc[rr][c]);
            }
        }
#pragma unroll
        for (int rr = 0; rr < 8; ++rr)
#pragma unroll
            for (int c = 0; c < 6; ++c)
                atomicAdd(&attall[(size_t)(m0 + ty * 8 + rr) * 288 + n0 + tx * 6 + c], acc[rr][c]);
    }
}

// ---------------- K2: softmax over span tokens, assemble bf16 span embeddings -------------
__global__ __launch_bounds__(256) void k2_assemble(
    const float* __restrict__ se, const float* __restrict__ cont,
    const int* __restrict__ width, const float* __restrict__ scores,
    const float* __restrict__ ab2, const float* __restrict__ wemb,
    unsigned short* __restrict__ sb) {
    int nm = blockIdx.x, tid = threadIdx.x;
    int wd = width[nm];
    float ab2v = ab2[0];
    float sc[10];
    float m = NEG_INF;
#pragma unroll
    for (int t = 0; t < 10; ++t) {
        float s = scores[nm * 10 + t] + ab2v;
        sc[t] = (t < wd) ? s : NEGV;
        m = fmaxf(m, sc[t]);
    }
    float sum = 0.f;
#pragma unroll
    for (int t = 0; t < 10; ++t) { sc[t] = expf(sc[t] - m); sum += sc[t]; }
    float inv = 1.f / sum;
#pragma unroll
    for (int t = 0; t < 10; ++t) sc[t] *= inv;
    const float* cbase = cont + (size_t)nm * 7680;
    unsigned short* srow = sb + (size_t)nm * 2368;
    for (int d = tid; d < 768; d += 256) {
        float acc = 0.f;
#pragma unroll
        for (int t = 0; t < 10; ++t) acc = fmaf(sc[t], cbase[t * 768 + d], acc);
        srow[1536 + d] = f2b(acc);
    }
    for (int idx = tid; idx < 1536; idx += 256) srow[idx] = f2b(se[(size_t)nm * 1536 + idx]);
    if (tid < 20) srow[2304 + tid] = f2b(wemb[min(wd, 4) * 20 + tid]);
    if (tid >= 20 && tid < 64) srow[2304 + tid] = 0;
}

// ---------------- KMIDB: kP2 (16384) + k4 K-split (128) + k3b (64) merged ----------------
__global__ __launch_bounds__(256) void kmidB(
    const unsigned short* __restrict__ sb, unsigned short* __restrict__ P, int doP,
    const unsigned short* __restrict__ w1aT, const unsigned short* __restrict__ w1bT,
    float* __restrict__ aout, float* __restrict__ bout,
    const float* __restrict__ attall, const float* __restrict__ tm,
    const float* __restrict__ im, float* __restrict__ Sg) {
    __shared__ __align__(16) unsigned short Ash[128 * 32];
    __shared__ __align__(16) unsigned short Bsh[128 * 32];
    __shared__ float att[64][37];
    __shared__ float tmv[64], imv[36];
    __shared__ float s1sh;
    int bid = blockIdx.x;
    int tid = threadIdx.x;

    if (bid < 16384) {
        // ---- kP2: canonical products ----
        if (!doP) return;
        int w = bid & 127, u = bid >> 7;
        if (u > w) return;
        const uint4* su = (const uint4*)(sb + (size_t)u * 2368);
        const uint4* sw = (const uint4*)(sb + (size_t)w * 2368);
        uint4* out = (uint4*)(P + ((size_t)u * 128 + w) * 2368);
        for (int i = tid; i < 296; i += 256) {
            uint4 a = su[i], b = sw[i];
            uint4 r;
            r.x = mul2bf(a.x, b.x); r.y = mul2bf(a.y, b.y);
            r.z = mul2bf(a.z, b.z); r.w = mul2bf(a.w, b.w);
            out[i] = r;
        }
    } else if (bid < 16512) {
        // ---- k4 K-split: a += sb@w1aT[kz], b += sb@w1bT[kz] (atomic fp32) ----
        int r = bid - 16384;
        int col0 = (r & 7) * 128;
        int half = (r >> 3) & 1;
        int kz = r >> 4;                          // [0,8)
        int kt0 = (74 * kz) / 8, kt1 = (74 * (kz + 1)) / 8;
        const unsigned short* wT = half ? w1bT : w1aT;
        float* outp = half ? bout : aout;
        int lane = tid & 63, wave = tid >> 6;
        int wm = wave >> 1, wn = wave & 1;
        int q = lane >> 4, l15 = lane & 15;

        floatx4 acc[4][4];
#pragma unroll
        for (int i = 0; i < 4; ++i)
#pragma unroll
            for (int j = 0; j < 4; ++j) acc[i][j] = (floatx4){0.f, 0.f, 0.f, 0.f};

        int ci0 = wave * 2, ci1 = wave * 2 + 1;
        int p = lane & 3;
        int r0 = ci0 * 16 + (lane >> 2), r1 = ci1 * 16 + (lane >> 2);
        int c0s = p ^ ((r0 >> 1) & 3), c1s = p ^ ((r1 >> 1) & 3);
        const char* gA0 = (const char*)(sb + (size_t)r0 * 2368) + c0s * 16 + kt0 * 64;
        const char* gA1 = (const char*)(sb + (size_t)r1 * 2368) + c1s * 16 + kt0 * 64;
        const char* gB0 = (const char*)(wT + (size_t)(col0 + r0) * 2368) + c0s * 16 + kt0 * 64;
        const char* gB1 = (const char*)(wT + (size_t)(col0 + r1) * 2368) + c1s * 16 + kt0 * 64;
        unsigned short* lA0 = Ash + ci0 * 512;
        unsigned short* lA1 = Ash + ci1 * 512;
        unsigned short* lB0 = Bsh + ci0 * 512;
        unsigned short* lB1 = Bsh + ci1 * 512;

        for (int kt = kt0; kt < kt1; ++kt) {
            __syncthreads();
            GLL16(gA0, lA0);
            GLL16(gA1, lA1);
            GLL16(gB0, lB0);
            GLL16(gB1, lB1);
            gA0 += 64; gA1 += 64; gB0 += 64; gB1 += 64;
            __syncthreads();
            short8 af[4], bfv[4];
#pragma unroll
            for (int i = 0; i < 4; ++i) {
                int rA = wm * 64 + i * 16 + l15;
                af[i] = *(const short8*)(Ash + rA * 32 + (q ^ ((rA >> 1) & 3)) * 8);
            }
#pragma unroll
            for (int j = 0; j < 4; ++j) {
                int rB = wn * 64 + j * 16 + l15;
                bfv[j] = *(const short8*)(Bsh + rB * 32 + (q ^ ((rB >> 1) & 3)) * 8);
            }
#pragma unroll
            for (int i = 0; i < 4; ++i)
#pragma unroll
                for (int j = 0; j < 4; ++j)
                    acc[i][j] = __builtin_amdgcn_mfma_f32_16x16x32_bf16(af[i], bfv[j], acc[i][j], 0, 0, 0);
        }

        int nj[4];
#pragma unroll
        for (int j = 0; j < 4; ++j) nj[j] = col0 + wn * 64 + j * 16 + l15;
#pragma unroll
        for (int i = 0; i < 4; ++i) {
#pragma unroll
            for (int reg = 0; reg < 4; ++reg) {
                int row = wm * 64 + i * 16 + q * 4 + reg;
#pragma unroll
                for (int j = 0; j < 4; ++j)
                    atomicAdd(&outp[(size_t)row * 1024 + nj[j]], acc[i][j][reg]);
            }
        }
    } else {
        // ---- k3b: per (s,v) mask + two softmax-reductions -> Sg ----
        int r2 = bid - 16512;
        int s = r2 >> 3, v = r2 & 7;
        if (tid < 64) tmv[tid] = tm[s * 64 + tid];
        if (tid >= 64 && tid < 100) imv[tid - 64] = im[v * 36 + (tid - 64)];
        __syncthreads();
        for (int idx = tid; idx < 2304; idx += 256) {
            int i = idx / 36, j = idx - i * 36;
            float raw = attall[(size_t)(s * 64 + i) * 288 + v * 36 + j];
            float x = raw * tmv[i] * imv[j];
            att[i][j] = (x != 0.f) ? x : NEGV;
        }
        __syncthreads();
        float part = 0.f;
        if (tid < 64) {
            int i = tid;
            float mx = NEG_INF;
            for (int j = 0; j < 36; ++j) mx = fmaxf(mx, att[i][j] * imv[j]);
            float sum = 0.f;
            for (int j = 0; j < 36; ++j) sum += expf(att[i][j] * imv[j] - mx);
            float invs = 1.f / sum;
            for (int j = 0; j < 36; ++j) {
                float aw = expf(att[i][j] * imv[j] - mx) * invs * (tmv[i] * imv[j]);
                part += aw * att[i][j];
            }
            for (int off = 32; off > 0; off >>= 1) part += __shfl_down(part, off);
            if (tid == 0) s1sh = part;
        }
        __syncthreads();
        if (tid < 64) {
            float part2 = 0.f;
            if (tid < 36) {
                int j = tid;
                float mx = NEG_INF;
                for (int i = 0; i < 64; ++i) mx = fmaxf(mx, att[i][j]);
                float sum = 0.f;
                for (int i = 0; i < 64; ++i) sum += expf(att[i][j] - mx);
                float invs = 1.f / sum;
                for (int i = 0; i < 64; ++i) {
                    float aw = expf(att[i][j] - mx) * invs * (tmv[i] * imv[j]);
                    part2 += aw * att[i][j];
                }
            }
            for (int off = 32; off > 0; off >>= 1) part2 += __shfl_down(part2, off);
            if (tid == 0) Sg[s * 8 + v] = s1sh + part2;
        }
    }
}

// ---------------- K5_SYM (MFMA, symmetric pair-tiles, XCD-swizzled) ----------------------
__global__ __launch_bounds__(256) void k5_sym(
    const unsigned short* __restrict__ P, const unsigned short* __restrict__ wT,
    const float* __restrict__ a, const float* __restrict__ b,
    const float* __restrict__ b1, unsigned short* __restrict__ h) {
    __shared__ __align__(16) unsigned short Ash[128 * 32];
    __shared__ __align__(16) unsigned short Bsh[128 * 32];
    int tid = threadIdx.x;
    int bid = blockIdx.x;
    int r8 = bid & 7, t = bid >> 3;
    int c = t & 7, pt = r8 + 8 * (t >> 3);
    const int offs[9] = {0, 16, 30, 42, 52, 60, 66, 70, 72};
    int ut = 0;
#pragma unroll
    for (int k = 1; k < 8; ++k) if (pt >= offs[k]) ut = k;
    int wt = 2 * ut + (pt - offs[ut]);
    int col0 = c * 128;

    int lane = tid & 63, wave = tid >> 6;
    int wm = wave >> 1, wn = wave & 1;
    int q = lane >> 4, l15 = lane & 15;

    floatx4 acc[4][4];
#pragma unroll
    for (int i = 0; i < 4; ++i)
#pragma unroll
        for (int j = 0; j < 4; ++j) acc[i][j] = (floatx4){0.f, 0.f, 0.f, 0.f};

    int ci0 = wave * 2, ci1 = wave * 2 + 1;
    int p = lane & 3;
    int r0 = ci0 * 16 + (lane >> 2), r1 = ci1 * 16 + (lane >> 2);
    int c0s = p ^ ((r0 >> 1) & 3), c1s = p ^ ((r1 >> 1) & 3);
    size_t prow0 = (size_t)(ut * 16 + (r0 >> 3)) * 128 + (wt * 8 + (r0 & 7));
    size_t prow1 = (size_t)(ut * 16 + (r1 >> 3)) * 128 + (wt * 8 + (r1 & 7));
    const char* gA0 = (const char*)(P + prow0 * 2368) + c0s * 16;
    const char* gA1 = (const char*)(P + prow1 * 2368) + c1s * 16;
    const char* gB0 = (const char*)(wT + (size_t)(col0 + r0) * 2368) + c0s * 16;
    const char* gB1 = (const char*)(wT + (size_t)(col0 + r1) * 2368) + c1s * 16;
    unsigned short* lA0 = Ash + ci0 * 512;
    unsigned short* lA1 = Ash + ci1 * 512;
    unsigned short* lB0 = Bsh + ci0 * 512;
    unsigned short* lB1 = Bsh + ci1 * 512;

    for (int kt = 0; kt < 74; ++kt) {
        __syncthreads();
        GLL16(gA0, lA0);
        GLL16(gA1, lA1);
        GLL16(gB0, lB0);
        GLL16(gB1, lB1);
        gA0 += 64; gA1 += 64; gB0 += 64; gB1 += 64;
        __syncthreads();
        short8 af[4], bfv[4];
#pragma unroll
        for (int i = 0; i < 4; ++i) {
            int rA = wm * 64 + i * 16 + l15;
            af[i] = *(const short8*)(Ash + rA * 32 + (q ^ ((rA >> 1) & 3)) * 8);
        }
#pragma unroll
        for (int j = 0; j < 4; ++j) {
            int rB = wn * 64 + j * 16 + l15;
            bfv[j] = *(const short8*)(Bsh + rB * 32 + (q ^ ((rB >> 1) & 3)) * 8);
        }
#pragma unroll
        for (int i = 0; i < 4; ++i)
#pragma unroll
            for (int j = 0; j < 4; ++j)
                acc[i][j] = __builtin_amdgcn_mfma_f32_16x16x32_bf16(af[i], bfv[j], acc[i][j], 0, 0, 0);
    }

    float b1v[4];
    int nj[4];
#pragma unroll
    for (int j = 0; j < 4; ++j) {
        nj[j] = col0 + wn * 64 + j * 16 + l15;
        b1v[j] = b1[nj[j]];
    }
#pragma unroll
    for (int i = 0; i < 4; ++i) {
#pragma unroll
        for (int reg = 0; reg < 4; ++reg) {
            int m = wm * 64 + i * 16 + q * 4 + reg;
            int u = ut * 16 + (m >> 3);
            int w = wt * 8 + (m & 7);
            if (w < u) continue;
            const float* au = a + (size_t)u * 1024;
            const float* bw = b + (size_t)w * 1024;
            unsigned short* hrow = h + ((size_t)u * 128 + w) * 1024;
#pragma unroll
            for (int j = 0; j < 4; ++j)
                hrow[nj[j]] = f2b(fmaxf(acc[i][j][reg] + au[nj[j]] + bw[nj[j]] + b1v[j], 0.f));
            if (w > u) {
                const float* aw_ = a + (size_t)w * 1024;
                const float* bu = b + (size_t)u * 1024;
                unsigned short* hrow2 = h + ((size_t)w * 128 + u) * 1024;
#pragma unroll
                for (int j = 0; j < 4; ++j)
                    hrow2[nj[j]] = f2b(fmaxf(acc[i][j][reg] + aw_[nj[j]] + bu[nj[j]] + b1v[j], 0.f));
            }
        }
    }
}

// ---------------- K5 fallback (on-the-fly product; used if ws too small) --------
__global__ __launch_bounds__(256) void k5_mfma(
    const unsigned short* __restrict__ sb, const unsigned short* __restrict__ wT,
    const float* __restrict__ a, const float* __restrict__ b,
    const float* __restrict__ b1, unsigned short* __restrict__ h) {
    __shared__ __align__(16) unsigned short Ash[128 * 32];
    __shared__ __align__(16) unsigned short Bsh[128 * 32];
    int tid = threadIdx.x;
    int u = blockIdx.y;
    int col0 = blockIdx.x * 128;
    int lane = tid & 63, wave = tid >> 6;
    int wm = wave >> 1, wn = wave & 1;
    int q = lane >> 4, l15 = lane & 15;

    floatx4 acc[4][4];
#pragma unroll
    for (int i = 0; i < 4; ++i)
#pragma unroll
        for (int j = 0; j < 4; ++j) acc[i][j] = (floatx4){0.f, 0.f, 0.f, 0.f};

    int r = tid >> 1;
    int cb = (tid & 1) * 2;
    int sw = (r >> 1) & 3;
    const unsigned short* arow = sb + (size_t)r * 2368 + cb * 8;
    const unsigned short* urow = sb + (size_t)u * 2368 + cb * 8;
    const unsigned short* brow = wT + (size_t)(col0 + r) * 2368 + cb * 8;
    unsigned short* awp0 = Ash + r * 32 + (cb ^ sw) * 8;
    unsigned short* awp1 = Ash + r * 32 + ((cb + 1) ^ sw) * 8;
    unsigned short* bwp0 = Bsh + r * 32 + (cb ^ sw) * 8;
    unsigned short* bwp1 = Bsh + r * 32 + ((cb + 1) ^ sw) * 8;

    for (int kt = 0; kt < 74; ++kt) {
        int k0 = kt * 32;
        uint4 av0 = *(const uint4*)(arow + k0);
        uint4 av1 = *(const uint4*)(arow + k0 + 8);
        uint4 uv0 = *(const uint4*)(urow + k0);
        uint4 uv1 = *(const uint4*)(urow + k0 + 8);
        uint4 bv0 = *(const uint4*)(brow + k0);
        uint4 bv1 = *(const uint4*)(brow + k0 + 8);
        __syncthreads();
        uint4 p0, p1;
        p0.x = mul2bf(av0.x, uv0.x); p0.y = mul2bf(av0.y, uv0.y);
        p0.z = mul2bf(av0.z, uv0.z); p0.w = mul2bf(av0.w, uv0.w);
        p1.x = mul2bf(av1.x, uv1.x); p1.y = mul2bf(av1.y, uv1.y);
        p1.z = mul2bf(av1.z, uv1.z); p1.w = mul2bf(av1.w, uv1.w);
        *(uint4*)awp0 = p0;
        *(uint4*)awp1 = p1;
        *(uint4*)bwp0 = bv0;
        *(uint4*)bwp1 = bv1;
        __syncthreads();
        short8 af[4], bfv[4];
#pragma unroll
        for (int i = 0; i < 4; ++i) {
            int rA = wm * 64 + i * 16 + l15;
            af[i] = *(const short8*)(Ash + rA * 32 + (q ^ ((rA >> 1) & 3)) * 8);
        }
#pragma unroll
        for (int j = 0; j < 4; ++j) {
            int rB = wn * 64 + j * 16 + l15;
            bfv[j] = *(const short8*)(Bsh + rB * 32 + (q ^ ((rB >> 1) & 3)) * 8);
        }
#pragma unroll
        for (int i = 0; i < 4; ++i)
#pragma unroll
            for (int j = 0; j < 4; ++j)
                acc[i][j] = __builtin_amdgcn_mfma_f32_16x16x32_bf16(af[i], bfv[j], acc[i][j], 0, 0, 0);
    }

    float aU[4], b1v[4];
    int nj[4];
#pragma unroll
    for (int j = 0; j < 4; ++j) {
        nj[j] = col0 + wn * 64 + j * 16 + l15;
        aU[j] = a[u * 1024 + nj[j]];
        b1v[j] = b1[nj[j]];
    }
    size_t hbase = (size_t)u * 128 * 1024;
#pragma unroll
    for (int i = 0; i < 4; ++i) {
#pragma unroll
        for (int reg = 0; reg < 4; ++reg) {
            int w = wm * 64 + i * 16 + q * 4 + reg;
            const float* brw = b + (size_t)w * 1024;
            unsigned short* hrow = h + hbase + (size_t)w * 1024;
#pragma unroll
            for (int j = 0; j < 4; ++j) {
                float v = acc[i][j][reg] + aU[j] + brw[nj[j]] + b1v[j];
                hrow[nj[j]] = f2b(fmaxf(v, 0.f));
            }
        }
    }
}

// ---------------- K6 (MFMA, XCD-swizzled): ts += (relu(h@W2+b2))@w3 ----------------------
__global__ __launch_bounds__(256) void k6_gemm(
    const unsigned short* __restrict__ h, const unsigned short* __restrict__ w2T,
    const float* __restrict__ b2, const float* __restrict__ w3,
    float* __restrict__ ts) {
    __shared__ __align__(16) unsigned short Ash[128 * 32];
    __shared__ __align__(16) unsigned short Bsh[128 * 32];
    int tid = threadIdx.x;
    int bid = blockIdx.x;
    int r8 = bid & 7, t = bid >> 3;
    int cb = t & 7, mb = r8 + 8 * (t >> 3);
    int m0 = mb * 128;
    int col0 = cb * 128;
    int lane = tid & 63, wave = tid >> 6;
    int wm = wave >> 1, wn = wave & 1;
    int q = lane >> 4, l15 = lane & 15;

    floatx4 acc[4][4];
#pragma unroll
    for (int i = 0; i < 4; ++i)
#pragma unroll
        for (int j = 0; j < 4; ++j) acc[i][j] = (floatx4){0.f, 0.f, 0.f, 0.f};

    int ci0 = wave * 2, ci1 = wave * 2 + 1;
    int p = lane & 3;
    int r0 = ci0 * 16 + (lane >> 2), r1 = ci1 * 16 + (lane >> 2);
    int c0s = p ^ ((r0 >> 1) & 3), c1s = p ^ ((r1 >> 1) & 3);
    const char* gA0 = (const char*)(h + (size_t)(m0 + r0) * 1024) + c0s * 16;
    const char* gA1 = (const char*)(h + (size_t)(m0 + r1) * 1024) + c1s * 16;
    const char* gB0 = (const char*)(w2T + (size_t)(col0 + r0) * 1024) + c0s * 16;
    const char* gB1 = (const char*)(w2T + (size_t)(col0 + r1) * 1024) + c1s * 16;
    unsigned short* lA0 = Ash + ci0 * 512;
    unsigned short* lA1 = Ash + ci1 * 512;
    unsigned short* lB0 = Bsh + ci0 * 512;
    unsigned short* lB1 = Bsh + ci1 * 512;

    for (int kt = 0; kt < 32; ++kt) {
        __syncthreads();
        GLL16(gA0, lA0);
        GLL16(gA1, lA1);
        GLL16(gB0, lB0);
        GLL16(gB1, lB1);
        gA0 += 64; gA1 += 64; gB0 += 64; gB1 += 64;
        __syncthreads();
        short8 af[4], bfv[4];
#pragma unroll
        for (int i = 0; i < 4; ++i) {
            int rA = wm * 64 + i * 16 + l15;
            af[i] = *(const short8*)(Ash + rA * 32 + (q ^ ((rA >> 1) & 3)) * 8);
        }
#pragma unroll
        for (int j = 0; j < 4; ++j) {
            int rB = wn * 64 + j * 16 + l15;
            bfv[j] = *(const short8*)(Bsh + rB * 32 + (q ^ ((rB >> 1) & 3)) * 8);
        }
#pragma unroll
        for (int i = 0; i < 4; ++i)
#pragma unroll
            for (int j = 0; j < 4; ++j)
                acc[i][j] = __builtin_amdgcn_mfma_f32_16x16x32_bf16(af[i], bfv[j], acc[i][j], 0, 0, 0);
    }

    float b2v[4], w3v[4];
    int nj[4];
#pragma unroll
    for (int j = 0; j < 4; ++j) {
        nj[j] = col0 + wn * 64 + j * 16 + l15;
        b2v[j] = b2[nj[j]];
        w3v[j] = w3[nj[j]];
    }
#pragma unroll
    for (int i = 0; i < 4; ++i) {
#pragma unroll
        for (int reg = 0; reg < 4; ++reg) {
            float s = 0.f;
#pragma unroll
            for (int j = 0; j < 4; ++j)
                s += fmaxf(acc[i][j][reg] + b2v[j], 0.f) * w3v[j];
            s += __shfl_down(s, 8, 16);
            s += __shfl_down(s, 4, 16);
            s += __shfl_down(s, 2, 16);
            s += __shfl_down(s, 1, 16);
            if (l15 == 0)
                atomicAdd(&ts[m0 + wm * 64 + i * 16 + q * 4 + reg], s);
        }
    }
}

// ---------------- K7: adaptive S_c + final loss (parallelized) ----------------
__global__ __launch_bounds__(256) void k7_final(
    const float* __restrict__ ts, const float* __restrict__ Sg,
    const float* __restrict__ m1, const float* __restrict__ b3,
    float* __restrict__ out) {
    __shared__ float rmv[1024], cmv[1024];
    __shared__ float cnt[8], m1s[128];
    __shared__ float Sc[64];
    __shared__ float mg[8][8], mgT[8][8], mc[8][8];
    int tid = threadIdx.x;
    if (tid < 128) m1s[tid] = m1[tid];
    __syncthreads();
    if (tid < 8) {
        float c = 0.f;
        for (int k = 0; k < 16; ++k) c += m1s[tid * 16 + k];
        cnt[tid] = c;
    }
    __syncthreads();
    float b3v = b3[0];
    for (int t = tid; t < 1024; t += 256) {
        int s = t >> 7, v = (t >> 4) & 7, x = t & 15;
        const float* row = ts + (size_t)(s * 16 + x) * 128 + v * 16;
        float r = 0.f;
#pragma unroll
        for (int j = 0; j < 16; ++j) r += (row[j] + b3v) * m1s[v * 16 + j];
        rmv[t] = r / cnt[v];
        float c2 = 0.f;
#pragma unroll
        for (int i = 0; i < 16; ++i)
            c2 += (ts[(size_t)(s * 16 + i) * 128 + v * 16 + x] + b3v) * m1s[s * 16 + i];
        cmv[t] = c2 / cnt[s];
    }
    __syncthreads();
    if (tid < 64) {
        int s = tid >> 3, v = tid & 7;
        float max1 = NEG_INF, max2 = NEG_INF;
        for (int i = 0; i < 16; ++i)
            if (m1s[s * 16 + i] > 0.f) max1 = fmaxf(max1, rmv[(s << 7) | (v << 4) | i]);
        for (int j = 0; j < 16; ++j)
            if (m1s[v * 16 + j] > 0.f) max2 = fmaxf(max2, cmv[(s << 7) | (v << 4) | j]);
        Sc[tid] = 0.5f * (max1 + max2);
    }
    __syncthreads();
    if (tid < 8) {
        int r = tid;
        float mx = NEG_INF;
        for (int v = 0; v < 8; ++v) mx = fmaxf(mx, Sg[r * 8 + v]);
        float sm = 0.f;
        for (int v = 0; v < 8; ++v) sm += expf(Sg[r * 8 + v] - mx);
        for (int v = 0; v < 8; ++v) mg[r][v] = expf(Sg[r * 8 + v] - mx) / sm;

        mx = NEG_INF;
        for (int v = 0; v < 8; ++v) mx = fmaxf(mx, Sc[r * 8 + v]);
        sm = 0.f;
        for (int v = 0; v < 8; ++v) sm += expf(Sc[r * 8 + v] - mx);
        for (int v = 0; v < 8; ++v) mc[r][v] = expf(Sc[r * 8 + v] - mx) / sm;

        mx = NEG_INF;
        for (int s2 = 0; s2 < 8; ++s2) mx = fmaxf(mx, Sg[s2 * 8 + r]);
        sm = 0.f;
        for (int s2 = 0; s2 < 8; ++s2) sm += expf(Sg[s2 * 8 + r] - mx);
        for (int s2 = 0; s2 < 8; ++s2) mgT[r][s2] = expf(Sg[s2 * 8 + r] - mx) / sm;
    }
    __syncthreads();
    if (tid == 0) {
        float loss = 0.f;
        for (int r = 0; r < 8; ++r) {
            float d1 = 0.f, d2 = 0.f;
            for (int v = 0; v < 8; ++v) {
                d1 += mg[r][v] * mc[r][v];
                d2 += mgT[r][v] * mc[r][v];
            }
            loss -= logf(d1) + logf(d2);
        }
        out[0] = loss / 8.f;
    }
}

extern "C" void kernel_launch(void* const* d_in, const int* in_sizes, int n_in,
                              void* d_out, int out_size, void* d_ws, size_t ws_size,
                              hipStream_t stream) {
    const float* doc   = (const float*)d_in[0];
    const float* img   = (const float*)d_in[1];
    const float* tm    = (const float*)d_in[2];
    const float* im    = (const float*)d_in[3];
    const float* se    = (const float*)d_in[4];
    const float* cont  = (const float*)d_in[5];
    const int*   width = (const int*)d_in[6];
    const float* m1    = (const float*)d_in[7];
    const float* aw1   = (const float*)d_in[8];
    const float* ab1   = (const float*)d_in[9];
    const float* aw2   = (const float*)d_in[10];
    const float* ab2   = (const float*)d_in[11];
    const float* wemb  = (const float*)d_in[12];
    const float* pw_w1 = (const float*)d_in[13];
    const float* pw_b1 = (const float*)d_in[14];
    const float* pw_w2 = (const float*)d_in[15];
    const float* pw_b2 = (const float*)d_in[16];
    const float* pw_w3 = (const float*)d_in[17];
    const float* pw_b3 = (const float*)d_in[18];
    float* out = (float*)d_out;

    char* ws = (char*)d_ws;
    float* scores           = (float*)(ws + 0);                 // 1280 f32
    float* a                = (float*)(ws + 8192);              // 128*1024 f32
    float* b                = (float*)(ws + 532480);            // 128*1024 f32
    float* Sg               = (float*)(ws + 1056768);           // 64 f32
    float* ts               = (float*)(ws + 1057024);           // 16384 f32
    unsigned short* sb      = (unsigned short*)(ws + 1122560);  // 128*2368 bf16
    unsigned short* w1cT    = (unsigned short*)(ws + 1728768);  // 1024*2368 bf16
    unsigned short* w2T     = (unsigned short*)(ws + 6578432);  // 1024*1024 bf16
    unsigned short* h       = (unsigned short*)(ws + 8675584);  // 16384*1024 bf16 (33.5 MB)
    unsigned short* P       = (unsigned short*)(ws + 42230016); // 16384*2368 bf16 (77.6 MB)
    const size_t NEED_P = 42230016ull + 16384ull * 2368ull * 2ull;
    // Overlays inside the h region (all dead before k5 writes h):
    unsigned short* contb   = (unsigned short*)(ws + 8675584);  // 1280*768 bf16
    unsigned short* aw1T    = (unsigned short*)(ws + 10641664); // 1024*768 bf16
    unsigned short* w1aT    = (unsigned short*)(ws + 12214528); // 1024*2368 bf16
    unsigned short* w1bT    = (unsigned short*)(ws + 17064192); // 1024*2368 bf16
    float* attall           = (float*)(ws + 21913856);          // 512*288 f32

    int doP = (ws_size >= NEED_P) ? 1 : 0;

    kprep<<<8880, 256, 0, stream>>>(pw_w1, pw_w2, aw1, cont, w1cT, w1aT, w1bT,
                                    w2T, aw1T, contb, ts, scores, attall, a, b);
    kmidA<<<176, 256, 0, stream>>>(contb, aw1T, ab1, aw2, scores, doc, img, attall);
    k2_assemble<<<128, 256, 0, stream>>>(se, cont, width, scores, ab2, wemb, sb);
    kmidB<<<16576, 256, 0, stream>>>(sb, P, doP, w1aT, w1bT, a, b, attall, tm, im, Sg);
    if (doP) {
        k5_sym<<<576, 256, 0, stream>>>(P, w1cT, a, b, pw_b1, h);
    } else {
        k5_mfma<<<dim3(8, 128), 256, 0, stream>>>(sb, w1cT, a, b, pw_b1, h);
    }
    k6_gemm<<<1024, 256, 0, stream>>>(h, w2T, pw_b2, pw_w3, ts);
    k7_final<<<1, 256, 0, stream>>>(ts, Sg, m1, pw_b3, out);
}